// Round 1
// baseline (4412.059 us; speedup 1.0000x reference)
//
#include <hip/hip_runtime.h>
#include <hip/hip_bf16.h>
#include <math.h>

#define NN 100000   // nodes
#define EE 300000   // edges per type
#define TT 3        // edge types
#define LL 2        // layers
#define HH 128      // hidden
#define FF 5        // node feat
#define TE 64       // type embed
#define BB 64       // graphs

// ---------------------------------------------------------------- counts
__global__ void count_kernel(const int* __restrict__ ei, int* __restrict__ cnt) {
    int i = blockIdx.x * blockDim.x + threadIdx.x;
    if (i >= TT * EE) return;
    int t = i / EE, e = i - t * EE;
    int dst = ei[(t * 2 + 1) * EE + e];
    atomicAdd(&cnt[t * NN + dst], 1);
}

__global__ void invcnt_kernel(const int* __restrict__ cnt, float* __restrict__ inv) {
    int i = blockIdx.x * blockDim.x + threadIdx.x;
    if (i >= TT * NN) return;
    inv[i] = 1.0f / fmaxf((float)cnt[i], 1.0f);
}

// ---------------------------------------------------------------- input projection
// h[n,:] = concat(emb[ast[n]], x[n]) @ W_in + b_in    (69 x 128 weights in LDS)
__global__ void input_proj_kernel(const float* __restrict__ x, const int* __restrict__ ast,
                                  const float* __restrict__ emb, const float* __restrict__ W_in,
                                  const float* __restrict__ b_in, float* __restrict__ h) {
    __shared__ float Ws[(TE + FF) * HH];
    __shared__ float vin[TE + FF];
    int tid = threadIdx.x;  // 128 threads
    for (int i = tid; i < (TE + FF) * HH; i += HH) Ws[i] = W_in[i];
    float bj = b_in[tid];
    __syncthreads();
    for (int n = blockIdx.x; n < NN; n += gridDim.x) {
        if (tid < TE + FF) {
            int a = ast[n];
            vin[tid] = (tid < TE) ? emb[a * TE + tid] : x[n * FF + (tid - TE)];
        }
        __syncthreads();
        float acc = bj;
        #pragma unroll
        for (int k = 0; k < TE + FF; ++k) acc = fmaf(vin[k], Ws[k * HH + tid], acc);
        h[n * HH + tid] = acc;
        __syncthreads();
    }
}

// ---------------------------------------------------------------- f32 GEMM  C = A @ (sum of nW 128x128 mats) [+ sum biases]
// BM=64, BN=128, K=128. 512 threads, 4x4 register tile each.
__global__ __launch_bounds__(512) void gemm128_kernel(
    const float* __restrict__ A, const float* __restrict__ Wb, int nW,
    const float* __restrict__ bb, float* __restrict__ C, int rows)
{
    __shared__ float Ws[HH * HH];        // 64 KB
    __shared__ float As[64][HH + 4];     // 33.8 KB, pad 4 -> A reads 2-way (free)
    int tid = threadIdx.x;
    for (int i = tid; i < HH * HH; i += 512) {
        float w = Wb[i];
        for (int m = 1; m < nW; ++m) w += Wb[m * HH * HH + i];
        Ws[i] = w;
    }
    int row0 = blockIdx.x * 64;
    {
        int k = tid & 127, rh = tid >> 7;
        for (int r = rh; r < 64; r += 4) {
            int gr = row0 + r;
            As[r][k] = (gr < rows) ? A[gr * HH + k] : 0.0f;
        }
    }
    __syncthreads();
    int ty = tid >> 5, tx = tid & 31;   // 16 row-threads x 32 col-threads
    float acc[4][4] = {};
    #pragma unroll 8
    for (int k = 0; k < HH; ++k) {
        float a0 = As[ty * 4 + 0][k];
        float a1 = As[ty * 4 + 1][k];
        float a2 = As[ty * 4 + 2][k];
        float a3 = As[ty * 4 + 3][k];
        float4 b = *reinterpret_cast<const float4*>(&Ws[k * HH + tx * 4]);
        acc[0][0] = fmaf(a0, b.x, acc[0][0]); acc[0][1] = fmaf(a0, b.y, acc[0][1]);
        acc[0][2] = fmaf(a0, b.z, acc[0][2]); acc[0][3] = fmaf(a0, b.w, acc[0][3]);
        acc[1][0] = fmaf(a1, b.x, acc[1][0]); acc[1][1] = fmaf(a1, b.y, acc[1][1]);
        acc[1][2] = fmaf(a1, b.z, acc[1][2]); acc[1][3] = fmaf(a1, b.w, acc[1][3]);
        acc[2][0] = fmaf(a2, b.x, acc[2][0]); acc[2][1] = fmaf(a2, b.y, acc[2][1]);
        acc[2][2] = fmaf(a2, b.z, acc[2][2]); acc[2][3] = fmaf(a2, b.w, acc[2][3]);
        acc[3][0] = fmaf(a3, b.x, acc[3][0]); acc[3][1] = fmaf(a3, b.y, acc[3][1]);
        acc[3][2] = fmaf(a3, b.z, acc[3][2]); acc[3][3] = fmaf(a3, b.w, acc[3][3]);
    }
    float bj[4] = {0.f, 0.f, 0.f, 0.f};
    if (bb) {
        #pragma unroll
        for (int j = 0; j < 4; ++j) {
            float s = 0.f;
            for (int m = 0; m < nW; ++m) s += bb[m * HH + tx * 4 + j];
            bj[j] = s;
        }
    }
    #pragma unroll
    for (int i = 0; i < 4; ++i) {
        int gr = row0 + ty * 4 + i;
        if (gr < rows) {
            float4 o;
            o.x = acc[i][0] + bj[0]; o.y = acc[i][1] + bj[1];
            o.z = acc[i][2] + bj[2]; o.w = acc[i][3] + bj[3];
            *reinterpret_cast<float4*>(&C[gr * HH + tx * 4]) = o;
        }
    }
}

// ---------------------------------------------------------------- scatter: ob[dst] += g[src] * inv[dst]
__global__ void scatter_kernel(const int* __restrict__ eit, const float* __restrict__ g,
                               const float* __restrict__ invt, float* __restrict__ ob) {
    int lane = threadIdx.x & 31;            // 32 lanes x float4 = 128 dims
    int e = blockIdx.x * 8 + (threadIdx.x >> 5);
    if (e >= EE) return;
    int src = eit[e];
    int dst = eit[EE + e];
    float s = invt[dst];
    float4 v = *reinterpret_cast<const float4*>(&g[src * HH + lane * 4]);
    float* o = &ob[dst * HH + lane * 4];
    atomicAdd(o + 0, v.x * s);
    atomicAdd(o + 1, v.y * s);
    atomicAdd(o + 2, v.z * s);
    atomicAdd(o + 3, v.w * s);
}

// ---------------------------------------------------------------- layernorm (1 wave per row)
__global__ void layernorm_kernel(const float* __restrict__ in, const float* __restrict__ gamma,
                                 const float* __restrict__ beta, float* __restrict__ out, int rows) {
    int lane = threadIdx.x & 63;
    int row = blockIdx.x * 4 + (threadIdx.x >> 6);
    if (row >= rows) return;
    float2 v = *reinterpret_cast<const float2*>(&in[row * HH + lane * 2]);
    float s = v.x + v.y, sq = v.x * v.x + v.y * v.y;
    #pragma unroll
    for (int o = 32; o; o >>= 1) { s += __shfl_xor(s, o); sq += __shfl_xor(sq, o); }
    float mu = s * (1.0f / HH);
    float var = sq * (1.0f / HH) - mu * mu;
    float r = rsqrtf(var + 1e-5f);
    float2 gj = *reinterpret_cast<const float2*>(&gamma[lane * 2]);
    float2 bj = *reinterpret_cast<const float2*>(&beta[lane * 2]);
    float2 o2;
    o2.x = (v.x - mu) * r * gj.x + bj.x;
    o2.y = (v.y - mu) * r * gj.y + bj.y;
    *reinterpret_cast<float2*>(&out[row * HH + lane * 2]) = o2;
}

// ---------------------------------------------------------------- pooling: one block per graph (batch is sorted)
__global__ void pool_kernel(const float* __restrict__ h, const int* __restrict__ batch,
                            float* __restrict__ out) {
    int b = blockIdx.x;
    int start, end;
    {
        int lo = 0, hi = NN;
        while (lo < hi) { int mid = (lo + hi) >> 1; if (batch[mid] < b) lo = mid + 1; else hi = mid; }
        start = lo;
        hi = NN;
        while (lo < hi) { int mid = (lo + hi) >> 1; if (batch[mid] < b + 1) lo = mid + 1; else hi = mid; }
        end = lo;
    }
    int tid = threadIdx.x;           // 256 threads
    int d = tid & 127, half = tid >> 7;
    float s = 0.f, m = -INFINITY;
    for (int n = start + half; n < end; n += 2) {
        float v = h[n * HH + d];
        s += v; m = fmaxf(m, v);
    }
    __shared__ float ss[256], sm[256];
    ss[tid] = s; sm[tid] = m;
    __syncthreads();
    if (half == 0) {
        s += ss[tid + 128];
        m = fmaxf(m, sm[tid + 128]);
        int cg = end - start;
        float mean = s / fmaxf((float)cg, 1.0f);
        float mx = (cg > 0) ? m : 0.0f;
        out[b * 2 * HH + d] = mean;
        out[b * 2 * HH + HH + d] = mx;
    }
}

// ---------------------------------------------------------------- launch
extern "C" void kernel_launch(void* const* d_in, const int* in_sizes, int n_in,
                              void* d_out, int out_size, void* d_ws, size_t ws_size,
                              hipStream_t stream) {
    const float* x     = (const float*)d_in[0];
    const int*   ast   = (const int*)d_in[1];
    const int*   batch = (const int*)d_in[2];
    const int*   ei    = (const int*)d_in[3];   // [T,2,E]
    const float* emb   = (const float*)d_in[4];
    const float* W_in  = (const float*)d_in[5];
    const float* b_in  = (const float*)d_in[6];
    const float* W_l   = (const float*)d_in[7]; // [L,T,H,H]
    const float* b_l   = (const float*)d_in[8]; // [L,T,H]
    const float* W_r   = (const float*)d_in[9]; // [L,T,H,H]
    const float* gamma = (const float*)d_in[10];
    const float* beta  = (const float*)d_in[11];
    float* out = (float*)d_out;

    float* h   = (float*)d_ws;               // N*H
    float* ob  = h + (size_t)NN * HH;        // N*H
    float* g   = ob + (size_t)NN * HH;       // N*H
    float* inv = g + (size_t)NN * HH;        // T*N
    int*   cnt = (int*)(inv + (size_t)TT * NN);  // T*N

    hipMemsetAsync(cnt, 0, (size_t)TT * NN * sizeof(int), stream);
    count_kernel<<<(TT * EE + 255) / 256, 256, 0, stream>>>(ei, cnt);
    invcnt_kernel<<<(TT * NN + 255) / 256, 256, 0, stream>>>(cnt, inv);
    input_proj_kernel<<<1024, HH, 0, stream>>>(x, ast, emb, W_in, b_in, h);

    int gemm_grid = (NN + 63) / 64;
    for (int l = 0; l < LL; ++l) {
        // ob = h @ (sum_t W_r[l,t]) + sum_t b_l[l,t]
        gemm128_kernel<<<gemm_grid, 512, 0, stream>>>(h, W_r + (size_t)l * TT * HH * HH, TT,
                                                      b_l + (size_t)l * TT * HH, ob, NN);
        for (int t = 0; t < TT; ++t) {
            // g = h @ W_l[l,t];  ob[dst] += g[src] * inv_t[dst]
            gemm128_kernel<<<gemm_grid, 512, 0, stream>>>(h, W_l + ((size_t)l * TT + t) * HH * HH, 1,
                                                          nullptr, g, NN);
            scatter_kernel<<<(EE + 7) / 8, 256, 0, stream>>>(ei + (size_t)t * 2 * EE, g,
                                                             inv + (size_t)t * NN, ob);
        }
        // h = LN(ob)
        layernorm_kernel<<<(NN + 3) / 4, 256, 0, stream>>>(ob, gamma + (size_t)l * HH,
                                                           beta + (size_t)l * HH, h, NN);
    }
    pool_kernel<<<BB, 256, 0, stream>>>(h, batch, out);
}

// Round 2
// 1036.150 us; speedup vs baseline: 4.2581x; 4.2581x over previous
//
#include <hip/hip_runtime.h>
#include <hip/hip_bf16.h>
#include <math.h>

#define NN 100000   // nodes
#define EE 300000   // edges per type
#define TT 3        // edge types
#define LL 2        // layers
#define HH 128      // hidden
#define FF 5        // node feat
#define TE 64       // type embed
#define NT 200      // num ast types
#define BB 64       // graphs

// ================================================================ CSR build
__global__ void count_kernel(const int* __restrict__ ei, int* __restrict__ cnt) {
    int i = blockIdx.x * blockDim.x + threadIdx.x;
    if (i >= TT * EE) return;
    int t = i / EE, e = i - t * EE;
    int dst = ei[(t * 2 + 1) * EE + e];
    atomicAdd(&cnt[t * NN + dst], 1);
}

// hierarchical exclusive scan over M = T*N counts (1024 elems / block)
__global__ __launch_bounds__(256) void scan1_kernel(const int* __restrict__ cnt,
                                                    int* __restrict__ offs,
                                                    int* __restrict__ bsums, int M) {
    int tid = threadIdx.x;
    int base = blockIdx.x * 1024 + tid * 4;
    int a0 = 0, a1 = 0, a2 = 0, a3 = 0;
    if (base + 3 < M) { int4 v = *(const int4*)&cnt[base]; a0 = v.x; a1 = v.y; a2 = v.z; a3 = v.w; }
    else {
        if (base + 0 < M) a0 = cnt[base + 0];
        if (base + 1 < M) a1 = cnt[base + 1];
        if (base + 2 < M) a2 = cnt[base + 2];
        if (base + 3 < M) a3 = cnt[base + 3];
    }
    int s = a0 + a1 + a2 + a3;
    int lane = tid & 63, wv = tid >> 6;
    int x = s;
    #pragma unroll
    for (int o = 1; o < 64; o <<= 1) { int y = __shfl_up(x, o); if (lane >= o) x += y; }
    __shared__ int wsum[4];
    if (lane == 63) wsum[wv] = x;
    __syncthreads();
    int add = 0;
    for (int w = 0; w < wv; ++w) add += wsum[w];
    int incl = x + add;
    int e0 = incl - s, e1 = e0 + a0, e2 = e1 + a1, e3 = e2 + a2;
    if (base + 0 < M) offs[base + 0] = e0;
    if (base + 1 < M) offs[base + 1] = e1;
    if (base + 2 < M) offs[base + 2] = e2;
    if (base + 3 < M) offs[base + 3] = e3;
    if (tid == 255) bsums[blockIdx.x] = incl;
}

__global__ __launch_bounds__(512) void scan2_kernel(int* __restrict__ bsums, int NB) {
    int tid = threadIdx.x;
    int s = (tid < NB) ? bsums[tid] : 0;
    int lane = tid & 63, wv = tid >> 6;
    int x = s;
    #pragma unroll
    for (int o = 1; o < 64; o <<= 1) { int y = __shfl_up(x, o); if (lane >= o) x += y; }
    __shared__ int wsum[8];
    if (lane == 63) wsum[wv] = x;
    __syncthreads();
    int add = 0;
    for (int w = 0; w < wv; ++w) add += wsum[w];
    if (tid < NB) bsums[tid] = x + add - s;   // exclusive
}

__global__ void scan3_kernel(int* __restrict__ offs, const int* __restrict__ bsums,
                             int* __restrict__ cursor, int M) {
    int i = blockIdx.x * 256 + threadIdx.x;
    if (i >= M) return;
    int v = offs[i] + bsums[i >> 10];
    offs[i] = v;
    cursor[i] = v;
}

__global__ void fill_kernel(const int* __restrict__ ei, int* __restrict__ cursor,
                            int* __restrict__ csr) {
    int i = blockIdx.x * blockDim.x + threadIdx.x;
    if (i >= TT * EE) return;
    int t = i / EE, e = i - t * EE;
    int src = ei[(t * 2 + 0) * EE + e];
    int dst = ei[(t * 2 + 1) * EE + e];
    int pos = atomicAdd(&cursor[t * NN + dst], 1);
    csr[pos] = src;
}

// ================================================================ weight pre-sum
// Wrsum[l] = sum_t W_r[l,t]; blsum[l] = sum_t b_l[l,t]
__global__ void wsum_kernel(const float* __restrict__ W_r, const float* __restrict__ b_l,
                            float* __restrict__ Wrsum, float* __restrict__ blsum) {
    int i = blockIdx.x * 256 + threadIdx.x;
    if (i < LL * HH * HH) {
        int l = i >> 14, r = i & 16383;
        float s = 0.f;
        for (int t = 0; t < TT; ++t) s += W_r[(((size_t)(l * TT + t)) << 14) + r];
        Wrsum[i] = s;
    }
    if (i < LL * HH) {
        int l = i >> 7, j = i & 127;
        float s = 0.f;
        for (int t = 0; t < TT; ++t) s += b_l[(l * TT + t) * HH + j];
        blsum[i] = s;
    }
}

// ================================================================ input projection
// h[n,:] = concat(emb[ast[n]], x[n]) @ W_in + b_in.  emb table + W_in fully in LDS.
__global__ __launch_bounds__(512) void input_proj_kernel(
    const float* __restrict__ x, const int* __restrict__ ast,
    const float* __restrict__ emb, const float* __restrict__ W_in,
    const float* __restrict__ b_in, float* __restrict__ h)
{
    __shared__ float Ws[(TE + FF) * HH];   // 35.3 KB
    __shared__ float Es[NT * TE];          // 51.2 KB
    int tid = threadIdx.x;
    for (int i = tid; i < (TE + FF) * HH; i += 512) Ws[i] = W_in[i];
    for (int i = tid; i < NT * TE; i += 512) Es[i] = emb[i];
    __syncthreads();
    int col = tid & 127, nl = tid >> 7;    // 4 nodes per block-iteration
    float bj = b_in[col];
    for (int n = blockIdx.x * 4 + nl; n < NN; n += gridDim.x * 4) {
        int a = ast[n];
        float acc = bj;
        const float* ep = &Es[a * TE];
        #pragma unroll
        for (int k = 0; k < TE; ++k) acc = fmaf(ep[k], Ws[k * HH + col], acc);
        #pragma unroll
        for (int k = 0; k < FF; ++k) acc = fmaf(x[n * FF + k], Ws[(TE + k) * HH + col], acc);
        h[(size_t)n * HH + col] = acc;
    }
}

// ================================================================ fused conv layer
// One kernel per layer. Block = 64 rows x 128 cols, 512 threads, 4x4 tile each.
// acc = h@Wrsum + sum_t mean_t@W_l[t] + blsum, then in-register LayerNorm -> hout.
#define AS_LD (HH + 4)
__global__ __launch_bounds__(512) void conv_kernel(
    const float* __restrict__ h, const float* __restrict__ Wrsum_l,  // [H][H]
    const float* __restrict__ W_l_l,                                 // [T][H][H]
    const float* __restrict__ blsum_l,                               // [H]
    const float* __restrict__ gamma, const float* __restrict__ beta, // [H]
    const int* __restrict__ offs, const int* __restrict__ cnt, const int* __restrict__ csr,
    float* __restrict__ hout)
{
    __shared__ float Ws[HH * HH];      // 64 KB
    __shared__ float As[64][AS_LD];    // 33 KB
    int tid = threadIdx.x;
    int row0 = blockIdx.x * 64;
    int ty = tid >> 5, tx = tid & 31;
    float acc[4][4] = {};

    for (int m = 0; m < 4; ++m) {
        // ---- stage weights (16384 floats / 512 thr = 8 float4 each)
        const float* Wsrc = (m == 0) ? Wrsum_l : (W_l_l + (size_t)(m - 1) * HH * HH);
        #pragma unroll
        for (int s = 0; s < 8; ++s) {
            int idx = (s * 512 + tid) * 4;
            *(float4*)&Ws[idx] = *(const float4*)&Wsrc[idx];
        }
        // ---- stage A-tile
        if (m == 0) {
            #pragma unroll
            for (int s = 0; s < 4; ++s) {
                int f = s * 512 + tid;            // 0..2047
                int r = f >> 5, k0 = (f & 31) * 4;
                int gr = row0 + r;
                float4 v = {0.f, 0.f, 0.f, 0.f};
                if (gr < NN) v = *(const float4*)&h[(size_t)gr * HH + k0];
                *(float4*)&As[r][k0] = v;
            }
        } else {
            int t = m - 1;
            int r = tid >> 3, sub = tid & 7;      // 64 nodes x 8 threads; 16 cols each
            int gr = row0 + r;
            float4 s0 = {0,0,0,0}, s1 = {0,0,0,0}, s2 = {0,0,0,0}, s3 = {0,0,0,0};
            int c = 0;
            if (gr < NN) {
                int base = t * NN + gr;
                int o = offs[base];
                c = cnt[base];
                for (int j = 0; j < c; ++j) {
                    int src = csr[o + j];
                    const float4* hp = (const float4*)&h[(size_t)src * HH + sub * 16];
                    float4 v0 = hp[0], v1 = hp[1], v2 = hp[2], v3 = hp[3];
                    s0.x += v0.x; s0.y += v0.y; s0.z += v0.z; s0.w += v0.w;
                    s1.x += v1.x; s1.y += v1.y; s1.z += v1.z; s1.w += v1.w;
                    s2.x += v2.x; s2.y += v2.y; s2.z += v2.z; s2.w += v2.w;
                    s3.x += v3.x; s3.y += v3.y; s3.z += v3.z; s3.w += v3.w;
                }
            }
            float inv = (c > 0) ? 1.0f / (float)c : 0.0f;
            s0.x *= inv; s0.y *= inv; s0.z *= inv; s0.w *= inv;
            s1.x *= inv; s1.y *= inv; s1.z *= inv; s1.w *= inv;
            s2.x *= inv; s2.y *= inv; s2.z *= inv; s2.w *= inv;
            s3.x *= inv; s3.y *= inv; s3.z *= inv; s3.w *= inv;
            *(float4*)&As[r][sub * 16 + 0]  = s0;
            *(float4*)&As[r][sub * 16 + 4]  = s1;
            *(float4*)&As[r][sub * 16 + 8]  = s2;
            *(float4*)&As[r][sub * 16 + 12] = s3;
        }
        __syncthreads();
        // ---- accumulate 128 k-steps (b128 reads: A broadcast, W row-contiguous)
        #pragma unroll 2
        for (int kk = 0; kk < 32; ++kk) {
            float4 w0 = *(const float4*)&Ws[(kk * 4 + 0) * HH + tx * 4];
            float4 w1 = *(const float4*)&Ws[(kk * 4 + 1) * HH + tx * 4];
            float4 w2 = *(const float4*)&Ws[(kk * 4 + 2) * HH + tx * 4];
            float4 w3 = *(const float4*)&Ws[(kk * 4 + 3) * HH + tx * 4];
            #pragma unroll
            for (int i = 0; i < 4; ++i) {
                float4 a = *(const float4*)&As[ty * 4 + i][kk * 4];
                acc[i][0] = fmaf(a.x, w0.x, acc[i][0]);
                acc[i][1] = fmaf(a.x, w0.y, acc[i][1]);
                acc[i][2] = fmaf(a.x, w0.z, acc[i][2]);
                acc[i][3] = fmaf(a.x, w0.w, acc[i][3]);
                acc[i][0] = fmaf(a.y, w1.x, acc[i][0]);
                acc[i][1] = fmaf(a.y, w1.y, acc[i][1]);
                acc[i][2] = fmaf(a.y, w1.z, acc[i][2]);
                acc[i][3] = fmaf(a.y, w1.w, acc[i][3]);
                acc[i][0] = fmaf(a.z, w2.x, acc[i][0]);
                acc[i][1] = fmaf(a.z, w2.y, acc[i][1]);
                acc[i][2] = fmaf(a.z, w2.z, acc[i][2]);
                acc[i][3] = fmaf(a.z, w2.w, acc[i][3]);
                acc[i][0] = fmaf(a.w, w3.x, acc[i][0]);
                acc[i][1] = fmaf(a.w, w3.y, acc[i][1]);
                acc[i][2] = fmaf(a.w, w3.z, acc[i][2]);
                acc[i][3] = fmaf(a.w, w3.w, acc[i][3]);
            }
        }
        __syncthreads();   // before next m overwrites LDS
    }

    // ---- bias + in-register LayerNorm (row r = ty*4+i lives in 32 threads of one half-wave)
    float4 bj = *(const float4*)&blsum_l[tx * 4];
    float4 gj = *(const float4*)&gamma[tx * 4];
    float4 be = *(const float4*)&beta[tx * 4];
    #pragma unroll
    for (int i = 0; i < 4; ++i) {
        acc[i][0] += bj.x; acc[i][1] += bj.y; acc[i][2] += bj.z; acc[i][3] += bj.w;
    }
    float s[4], q[4];
    #pragma unroll
    for (int i = 0; i < 4; ++i) {
        s[i] = acc[i][0] + acc[i][1] + acc[i][2] + acc[i][3];
        q[i] = acc[i][0]*acc[i][0] + acc[i][1]*acc[i][1] + acc[i][2]*acc[i][2] + acc[i][3]*acc[i][3];
    }
    #pragma unroll
    for (int o = 1; o < 32; o <<= 1) {
        #pragma unroll
        for (int i = 0; i < 4; ++i) {
            s[i] += __shfl_xor(s[i], o);
            q[i] += __shfl_xor(q[i], o);
        }
    }
    #pragma unroll
    for (int i = 0; i < 4; ++i) {
        int gr = row0 + ty * 4 + i;
        if (gr < NN) {
            float mu = s[i] * (1.0f / HH);
            float var = q[i] * (1.0f / HH) - mu * mu;
            float rs = rsqrtf(var + 1e-5f);
            float4 o4;
            o4.x = (acc[i][0] - mu) * rs * gj.x + be.x;
            o4.y = (acc[i][1] - mu) * rs * gj.y + be.y;
            o4.z = (acc[i][2] - mu) * rs * gj.z + be.z;
            o4.w = (acc[i][3] - mu) * rs * gj.w + be.w;
            *(float4*)&hout[(size_t)gr * HH + tx * 4] = o4;
        }
    }
}

// ================================================================ pooling
__global__ void pool_kernel(const float* __restrict__ h, const int* __restrict__ batch,
                            float* __restrict__ out) {
    int b = blockIdx.x;
    int start, end;
    {
        int lo = 0, hi = NN;
        while (lo < hi) { int mid = (lo + hi) >> 1; if (batch[mid] < b) lo = mid + 1; else hi = mid; }
        start = lo;
        hi = NN;
        while (lo < hi) { int mid = (lo + hi) >> 1; if (batch[mid] < b + 1) lo = mid + 1; else hi = mid; }
        end = lo;
    }
    int tid = threadIdx.x;           // 256 threads
    int d = tid & 127, half = tid >> 7;
    float s = 0.f, m = -INFINITY;
    for (int n = start + half; n < end; n += 2) {
        float v = h[(size_t)n * HH + d];
        s += v; m = fmaxf(m, v);
    }
    __shared__ float ss[256], sm[256];
    ss[tid] = s; sm[tid] = m;
    __syncthreads();
    if (half == 0) {
        s += ss[tid + 128];
        m = fmaxf(m, sm[tid + 128]);
        int cg = end - start;
        float mean = s / fmaxf((float)cg, 1.0f);
        float mx = (cg > 0) ? m : 0.0f;
        out[b * 2 * HH + d] = mean;
        out[b * 2 * HH + HH + d] = mx;
    }
}

// ================================================================ launch
extern "C" void kernel_launch(void* const* d_in, const int* in_sizes, int n_in,
                              void* d_out, int out_size, void* d_ws, size_t ws_size,
                              hipStream_t stream) {
    const float* x     = (const float*)d_in[0];
    const int*   ast   = (const int*)d_in[1];
    const int*   batch = (const int*)d_in[2];
    const int*   ei    = (const int*)d_in[3];   // [T,2,E]
    const float* emb   = (const float*)d_in[4];
    const float* W_in  = (const float*)d_in[5];
    const float* b_in  = (const float*)d_in[6];
    const float* W_l   = (const float*)d_in[7]; // [L,T,H,H]
    const float* b_l   = (const float*)d_in[8]; // [L,T,H]
    const float* W_r   = (const float*)d_in[9]; // [L,T,H,H]
    const float* gamma = (const float*)d_in[10];
    const float* beta  = (const float*)d_in[11];
    float* out = (float*)d_out;

    const int M  = TT * NN;                  // 300000
    const int NB = (M + 1023) / 1024;        // 293

    float* h     = (float*)d_ws;             // N*H
    float* h2    = h + (size_t)NN * HH;      // N*H
    float* Wrsum = h2 + (size_t)NN * HH;     // L*H*H
    float* blsum = Wrsum + LL * HH * HH;     // L*H
    int* cnt     = (int*)(blsum + LL * HH);  // T*N
    int* offs    = cnt + M;                  // T*N
    int* cursor  = offs + M;                 // T*N
    int* csr     = cursor + M;               // T*E
    int* bsums   = csr + TT * EE;            // NB (<512)

    hipMemsetAsync(cnt, 0, (size_t)M * sizeof(int), stream);
    count_kernel<<<(TT * EE + 255) / 256, 256, 0, stream>>>(ei, cnt);
    scan1_kernel<<<NB, 256, 0, stream>>>(cnt, offs, bsums, M);
    scan2_kernel<<<1, 512, 0, stream>>>(bsums, NB);
    scan3_kernel<<<(M + 255) / 256, 256, 0, stream>>>(offs, bsums, cursor, M);
    fill_kernel<<<(TT * EE + 255) / 256, 256, 0, stream>>>(ei, cursor, csr);
    wsum_kernel<<<(LL * HH * HH + 255) / 256, 256, 0, stream>>>(W_r, b_l, Wrsum, blsum);
    input_proj_kernel<<<512, 512, 0, stream>>>(x, ast, emb, W_in, b_in, h);

    int conv_grid = (NN + 63) / 64;
    const float* src = h;
    float* dst = h2;
    for (int l = 0; l < LL; ++l) {
        conv_kernel<<<conv_grid, 512, 0, stream>>>(
            src, Wrsum + (size_t)l * HH * HH, W_l + (size_t)l * TT * HH * HH,
            blsum + (size_t)l * HH, gamma + (size_t)l * HH, beta + (size_t)l * HH,
            offs, cnt, csr, dst);
        const float* tmp = dst; dst = (float*)src; src = tmp;
    }
    pool_kernel<<<BB, 256, 0, stream>>>(src, batch, out);
}

// Round 5
// 704.213 us; speedup vs baseline: 6.2652x; 1.4714x over previous
//
#include <hip/hip_runtime.h>
#include <hip/hip_bf16.h>
#include <math.h>

#define NN 100000   // nodes
#define EE 300000   // edges per type
#define TT 3        // edge types
#define LL 2        // layers
#define HH 128      // hidden
#define FF 5        // node feat
#define TE 64       // type embed
#define NT 200      // num ast types
#define BB 64       // graphs

typedef short bf16x8 __attribute__((ext_vector_type(8)));
typedef float f32x4  __attribute__((ext_vector_type(4)));

__device__ __forceinline__ float bf2f(unsigned short u) {
    union { unsigned i; float f; } v; v.i = ((unsigned)u) << 16; return v.f;
}
__device__ __forceinline__ unsigned short f2bf(float f) {
    union { float f; unsigned i; } v; v.f = f;
    unsigned b = v.i + (0x7FFFu + ((v.i >> 16) & 1u));   // RNE
    return (unsigned short)(b >> 16);
}
// split x ~= hi + lo (two bf16); hi+lo reproduces x to ~2^-16 rel
__device__ __forceinline__ void split_bf(float x, unsigned short& hi, unsigned short& lo) {
    hi = f2bf(x);
    lo = f2bf(x - bf2f(hi));
}

// ================================================================ CSR build (validated R2)
__global__ void count_kernel(const int* __restrict__ ei, int* __restrict__ cnt) {
    int i = blockIdx.x * blockDim.x + threadIdx.x;
    if (i >= TT * EE) return;
    int t = i / EE, e = i - t * EE;
    int dst = ei[(t * 2 + 1) * EE + e];
    atomicAdd(&cnt[t * NN + dst], 1);
}

__global__ __launch_bounds__(256) void scan1_kernel(const int* __restrict__ cnt,
                                                    int* __restrict__ offs,
                                                    int* __restrict__ bsums, int M) {
    int tid = threadIdx.x;
    int base = blockIdx.x * 1024 + tid * 4;
    int a0 = 0, a1 = 0, a2 = 0, a3 = 0;
    if (base + 3 < M) { int4 v = *(const int4*)&cnt[base]; a0 = v.x; a1 = v.y; a2 = v.z; a3 = v.w; }
    else {
        if (base + 0 < M) a0 = cnt[base + 0];
        if (base + 1 < M) a1 = cnt[base + 1];
        if (base + 2 < M) a2 = cnt[base + 2];
        if (base + 3 < M) a3 = cnt[base + 3];
    }
    int s = a0 + a1 + a2 + a3;
    int lane = tid & 63, wv = tid >> 6;
    int x = s;
    #pragma unroll
    for (int o = 1; o < 64; o <<= 1) { int y = __shfl_up(x, o); if (lane >= o) x += y; }
    __shared__ int wsum[4];
    if (lane == 63) wsum[wv] = x;
    __syncthreads();
    int add = 0;
    for (int w = 0; w < wv; ++w) add += wsum[w];
    int incl = x + add;
    int e0 = incl - s, e1 = e0 + a0, e2 = e1 + a1, e3 = e2 + a2;
    if (base + 0 < M) offs[base + 0] = e0;
    if (base + 1 < M) offs[base + 1] = e1;
    if (base + 2 < M) offs[base + 2] = e2;
    if (base + 3 < M) offs[base + 3] = e3;
    if (tid == 255) bsums[blockIdx.x] = incl;
}

__global__ __launch_bounds__(512) void scan2_kernel(int* __restrict__ bsums, int NB) {
    int tid = threadIdx.x;
    int s = (tid < NB) ? bsums[tid] : 0;
    int lane = tid & 63, wv = tid >> 6;
    int x = s;
    #pragma unroll
    for (int o = 1; o < 64; o <<= 1) { int y = __shfl_up(x, o); if (lane >= o) x += y; }
    __shared__ int wsum[8];
    if (lane == 63) wsum[wv] = x;
    __syncthreads();
    int add = 0;
    for (int w = 0; w < wv; ++w) add += wsum[w];
    if (tid < NB) bsums[tid] = x + add - s;
}

__global__ void scan3_kernel(int* __restrict__ offs, const int* __restrict__ bsums,
                             int* __restrict__ cursor, int M) {
    int i = blockIdx.x * 256 + threadIdx.x;
    if (i >= M) return;
    int v = offs[i] + bsums[i >> 10];
    offs[i] = v;
    cursor[i] = v;
}

__global__ void fill_kernel(const int* __restrict__ ei, int* __restrict__ cursor,
                            int* __restrict__ csr) {
    int i = blockIdx.x * blockDim.x + threadIdx.x;
    if (i >= TT * EE) return;
    int t = i / EE, e = i - t * EE;
    int src = ei[(t * 2 + 0) * EE + e];
    int dst = ei[(t * 2 + 1) * EE + e];
    int pos = atomicAdd(&cursor[t * NN + dst], 1);
    csr[pos] = src;
}

// ================================================================ weight prep
// Wt16 layout: [l][m][plane][col][k], plane 0 = hi, 1 = lo. m=0 -> sum_t W_r^T, m=1..3 -> W_l[t]^T.
__global__ void wprep_kernel(const float* __restrict__ W_l, const float* __restrict__ W_r,
                             const float* __restrict__ b_l,
                             unsigned short* __restrict__ Wt16, float* __restrict__ blsum) {
    int i = blockIdx.x * 256 + threadIdx.x;
    if (i < LL * 4 * HH * HH) {
        int lm = i >> 14;          // l*4 + m
        int ck = i & 16383;
        int col = ck >> 7, k = ck & 127;
        int l = lm >> 2, m = lm & 3;
        float v;
        if (m == 0) {
            v = 0.f;
            for (int t = 0; t < TT; ++t)
                v += W_r[(((size_t)(l * TT + t)) << 14) + k * HH + col];
        } else {
            v = W_l[(((size_t)(l * TT + (m - 1))) << 14) + k * HH + col];
        }
        unsigned short hi, lo;
        split_bf(v, hi, lo);
        Wt16[((size_t)lm << 15) + ck]         = hi;
        Wt16[((size_t)lm << 15) + 16384 + ck] = lo;
    }
    if (i < LL * HH) {
        int l = i >> 7, j = i & 127;
        float s = 0.f;
        for (int t = 0; t < TT; ++t) s += b_l[(l * TT + t) * HH + j];
        blsum[i] = s;
    }
}

// ================================================================ input projection (validated R2, verbatim)
__global__ __launch_bounds__(512) void input_proj_kernel(
    const float* __restrict__ x, const int* __restrict__ ast,
    const float* __restrict__ emb, const float* __restrict__ W_in,
    const float* __restrict__ b_in, float* __restrict__ h)
{
    __shared__ float Ws[(TE + FF) * HH];   // 35.3 KB
    __shared__ float Es[NT * TE];          // 51.2 KB
    int tid = threadIdx.x;
    for (int i = tid; i < (TE + FF) * HH; i += 512) Ws[i] = W_in[i];
    for (int i = tid; i < NT * TE; i += 512) Es[i] = emb[i];
    __syncthreads();
    int col = tid & 127, nl = tid >> 7;    // 4 nodes per block-iteration
    float bj = b_in[col];
    for (int n = blockIdx.x * 4 + nl; n < NN; n += gridDim.x * 4) {
        int a = ast[n];
        float acc = bj;
        const float* ep = &Es[a * TE];
        #pragma unroll
        for (int k = 0; k < TE; ++k) acc = fmaf(ep[k], Ws[k * HH + col], acc);
        #pragma unroll
        for (int k = 0; k < FF; ++k) acc = fmaf(x[n * FF + k], Ws[(TE + k) * HH + col], acc);
        h[(size_t)n * HH + col] = acc;
    }
}

// ================================================================ conv layer (split-bf16 MFMA, padded-linear LDS)
// Block: 64 rows x 128 cols, 512 threads (8 waves: 4 row-groups x 2 col-groups).
// acc = h@Wrsum + sum_t mean_t@W_l[t]; writes acc+bias raw to ob (LN is separate).
#define ALD 136   // padded LDS stride (shorts): 272 B -> 2-way bank aliasing (free)

__global__ __launch_bounds__(512) void conv_kernel(
    const float* __restrict__ h,                 // [N][128] f32
    const unsigned short* __restrict__ Wt_l,     // [4][2][128][128] bf16 (hi/lo planes, W^T)
    const float* __restrict__ blsum_l,
    const int* __restrict__ offs, const int* __restrict__ cnt, const int* __restrict__ csr,
    float* __restrict__ ob)
{
    __shared__ unsigned short Wl[128 * ALD];     // 34.8 KB
    __shared__ unsigned short Ahi[64 * ALD];     // 17.4 KB
    __shared__ unsigned short Alo[64 * ALD];     // 17.4 KB

    int tid = threadIdx.x;
    int row0 = blockIdx.x * 64;
    int w = tid >> 6, l = tid & 63;
    int R0 = (w >> 1) * 16, C0 = (w & 1) * 64;
    int l15 = l & 15, koff = (l >> 4) * 8;
    f32x4 acc[4] = {};

    for (int m = 0; m < 4; ++m) {
        // ---- stage A-tile (hi/lo split), padded linear layout
        if (m == 0) {
            #pragma unroll
            for (int s2 = 0; s2 < 2; ++s2) {
                int c16 = s2 * 512 + tid;
                int r = c16 >> 4, k0 = (c16 & 15) * 8;
                int gr = row0 + r;
                float v[8] = {0.f,0.f,0.f,0.f,0.f,0.f,0.f,0.f};
                if (gr < NN) {
                    float4 va = *(const float4*)&h[(size_t)gr * 128 + k0];
                    float4 vb = *(const float4*)&h[(size_t)gr * 128 + k0 + 4];
                    v[0]=va.x; v[1]=va.y; v[2]=va.z; v[3]=va.w;
                    v[4]=vb.x; v[5]=vb.y; v[6]=vb.z; v[7]=vb.w;
                }
                unsigned short hs[8], ls[8];
                #pragma unroll
                for (int j = 0; j < 8; ++j) split_bf(v[j], hs[j], ls[j]);
                uint4 hv, lv;
                hv.x = (unsigned)hs[0] | ((unsigned)hs[1] << 16);
                hv.y = (unsigned)hs[2] | ((unsigned)hs[3] << 16);
                hv.z = (unsigned)hs[4] | ((unsigned)hs[5] << 16);
                hv.w = (unsigned)hs[6] | ((unsigned)hs[7] << 16);
                lv.x = (unsigned)ls[0] | ((unsigned)ls[1] << 16);
                lv.y = (unsigned)ls[2] | ((unsigned)ls[3] << 16);
                lv.z = (unsigned)ls[4] | ((unsigned)ls[5] << 16);
                lv.w = (unsigned)ls[6] | ((unsigned)ls[7] << 16);
                *(uint4*)&Ahi[r * ALD + k0] = hv;
                *(uint4*)&Alo[r * ALD + k0] = lv;
            }
        } else {
            int t = m - 1;
            int r = tid >> 3, sub = tid & 7;
            int gr = row0 + r;
            float s[16];
            #pragma unroll
            for (int j = 0; j < 16; ++j) s[j] = 0.f;
            int c = 0;
            if (gr < NN) {
                int base = t * NN + gr;
                int o = offs[base];
                c = cnt[base];
                for (int j = 0; j < c; ++j) {
                    int src = csr[o + j];
                    const float4* hp = (const float4*)&h[(size_t)src * 128 + sub * 16];
                    float4 v0 = hp[0], v1 = hp[1], v2 = hp[2], v3 = hp[3];
                    s[0]  += v0.x; s[1]  += v0.y; s[2]  += v0.z; s[3]  += v0.w;
                    s[4]  += v1.x; s[5]  += v1.y; s[6]  += v1.z; s[7]  += v1.w;
                    s[8]  += v2.x; s[9]  += v2.y; s[10] += v2.z; s[11] += v2.w;
                    s[12] += v3.x; s[13] += v3.y; s[14] += v3.z; s[15] += v3.w;
                }
            }
            float inv = (c > 0) ? 1.0f / (float)c : 0.0f;
            unsigned short hs[16], ls[16];
            #pragma unroll
            for (int j = 0; j < 16; ++j) split_bf(s[j] * inv, hs[j], ls[j]);
            uint4 hv0, hv1, lv0, lv1;
            hv0.x = (unsigned)hs[0]  | ((unsigned)hs[1]  << 16);
            hv0.y = (unsigned)hs[2]  | ((unsigned)hs[3]  << 16);
            hv0.z = (unsigned)hs[4]  | ((unsigned)hs[5]  << 16);
            hv0.w = (unsigned)hs[6]  | ((unsigned)hs[7]  << 16);
            hv1.x = (unsigned)hs[8]  | ((unsigned)hs[9]  << 16);
            hv1.y = (unsigned)hs[10] | ((unsigned)hs[11] << 16);
            hv1.z = (unsigned)hs[12] | ((unsigned)hs[13] << 16);
            hv1.w = (unsigned)hs[14] | ((unsigned)hs[15] << 16);
            lv0.x = (unsigned)ls[0]  | ((unsigned)ls[1]  << 16);
            lv0.y = (unsigned)ls[2]  | ((unsigned)ls[3]  << 16);
            lv0.z = (unsigned)ls[4]  | ((unsigned)ls[5]  << 16);
            lv0.w = (unsigned)ls[6]  | ((unsigned)ls[7]  << 16);
            lv1.x = (unsigned)ls[8]  | ((unsigned)ls[9]  << 16);
            lv1.y = (unsigned)ls[10] | ((unsigned)ls[11] << 16);
            lv1.z = (unsigned)ls[12] | ((unsigned)ls[13] << 16);
            lv1.w = (unsigned)ls[14] | ((unsigned)ls[15] << 16);
            *(uint4*)&Ahi[r * ALD + sub * 16]     = hv0;
            *(uint4*)&Ahi[r * ALD + sub * 16 + 8] = hv1;
            *(uint4*)&Alo[r * ALD + sub * 16]     = lv0;
            *(uint4*)&Alo[r * ALD + sub * 16 + 8] = lv1;
        }
        // ---- stage W hi plane (linear)
        const unsigned short* Whi = Wt_l + ((size_t)m << 15);
        #pragma unroll
        for (int s2 = 0; s2 < 4; ++s2) {
            int c16 = s2 * 512 + tid;
            int col = c16 >> 4, k0 = (c16 & 15) * 8;
            *(uint4*)&Wl[col * ALD + k0] = *(const uint4*)&Whi[col * 128 + k0];
        }
        __syncthreads();
        // ---- hi pass: (a_hi + a_lo) * w_hi
        #pragma unroll
        for (int ks = 0; ks < 4; ++ks) {
            int k0 = ks * 32 + koff;
            bf16x8 ah = *(const bf16x8*)&Ahi[(R0 + l15) * ALD + k0];
            bf16x8 al = *(const bf16x8*)&Alo[(R0 + l15) * ALD + k0];
            #pragma unroll
            for (int n = 0; n < 4; ++n) {
                bf16x8 b = *(const bf16x8*)&Wl[(C0 + n * 16 + l15) * ALD + k0];
                acc[n] = __builtin_amdgcn_mfma_f32_16x16x32_bf16(ah, b, acc[n], 0, 0, 0);
                acc[n] = __builtin_amdgcn_mfma_f32_16x16x32_bf16(al, b, acc[n], 0, 0, 0);
            }
        }
        __syncthreads();
        // ---- stage W lo plane
        const unsigned short* Wlo = Whi + 16384;
        #pragma unroll
        for (int s2 = 0; s2 < 4; ++s2) {
            int c16 = s2 * 512 + tid;
            int col = c16 >> 4, k0 = (c16 & 15) * 8;
            *(uint4*)&Wl[col * ALD + k0] = *(const uint4*)&Wlo[col * 128 + k0];
        }
        __syncthreads();
        // ---- lo pass: (a_hi + a_lo) * w_lo  -> full (ahi+alo)(whi+wlo)
        #pragma unroll
        for (int ks = 0; ks < 4; ++ks) {
            int k0 = ks * 32 + koff;
            bf16x8 ah = *(const bf16x8*)&Ahi[(R0 + l15) * ALD + k0];
            bf16x8 al = *(const bf16x8*)&Alo[(R0 + l15) * ALD + k0];
            #pragma unroll
            for (int n = 0; n < 4; ++n) {
                bf16x8 b = *(const bf16x8*)&Wl[(C0 + n * 16 + l15) * ALD + k0];
                acc[n] = __builtin_amdgcn_mfma_f32_16x16x32_bf16(ah, b, acc[n], 0, 0, 0);
                acc[n] = __builtin_amdgcn_mfma_f32_16x16x32_bf16(al, b, acc[n], 0, 0, 0);
            }
        }
        __syncthreads();   // before next m overwrites LDS
    }

    // ---- bias + raw global store (m89 C/D layout: col=lane&15, row=(lane>>4)*4+reg)
    #pragma unroll
    for (int n = 0; n < 4; ++n) {
        int cc = C0 + n * 16 + l15;
        float bv = blsum_l[cc];
        #pragma unroll
        for (int i = 0; i < 4; ++i) {
            int gr = row0 + R0 + (l >> 4) * 4 + i;
            if (gr < NN) ob[(size_t)gr * HH + cc] = acc[n][i] + bv;
        }
    }
}

// ================================================================ layernorm (validated R1, in-place safe)
__global__ void layernorm_kernel(const float* __restrict__ in, const float* __restrict__ gamma,
                                 const float* __restrict__ beta, float* __restrict__ out, int rows) {
    int lane = threadIdx.x & 63;
    int row = blockIdx.x * 4 + (threadIdx.x >> 6);
    if (row >= rows) return;
    float2 v = *reinterpret_cast<const float2*>(&in[(size_t)row * HH + lane * 2]);
    float s = v.x + v.y, sq = v.x * v.x + v.y * v.y;
    #pragma unroll
    for (int o = 32; o; o >>= 1) { s += __shfl_xor(s, o); sq += __shfl_xor(sq, o); }
    float mu = s * (1.0f / HH);
    float var = sq * (1.0f / HH) - mu * mu;
    float r = rsqrtf(var + 1e-5f);
    float2 gj = *reinterpret_cast<const float2*>(&gamma[lane * 2]);
    float2 bj = *reinterpret_cast<const float2*>(&beta[lane * 2]);
    float2 o2;
    o2.x = (v.x - mu) * r * gj.x + bj.x;
    o2.y = (v.y - mu) * r * gj.y + bj.y;
    *reinterpret_cast<float2*>(&out[(size_t)row * HH + lane * 2]) = o2;
}

// ================================================================ pooling (validated R1)
__global__ void pool_kernel(const float* __restrict__ h, const int* __restrict__ batch,
                            float* __restrict__ out) {
    int b = blockIdx.x;
    int start, end;
    {
        int lo = 0, hi = NN;
        while (lo < hi) { int mid = (lo + hi) >> 1; if (batch[mid] < b) lo = mid + 1; else hi = mid; }
        start = lo;
        hi = NN;
        while (lo < hi) { int mid = (lo + hi) >> 1; if (batch[mid] < b + 1) lo = mid + 1; else hi = mid; }
        end = lo;
    }
    int tid = threadIdx.x;
    int d = tid & 127, half = tid >> 7;
    float s = 0.f, m = -INFINITY;
    for (int n = start + half; n < end; n += 2) {
        float v = h[(size_t)n * HH + d];
        s += v; m = fmaxf(m, v);
    }
    __shared__ float ss[256], sm[256];
    ss[tid] = s; sm[tid] = m;
    __syncthreads();
    if (half == 0) {
        s += ss[tid + 128];
        m = fmaxf(m, sm[tid + 128]);
        int cg = end - start;
        float mean = s / fmaxf((float)cg, 1.0f);
        float mx = (cg > 0) ? m : 0.0f;
        out[b * 2 * HH + d] = mean;
        out[b * 2 * HH + HH + d] = mx;
    }
}

// ================================================================ launch
extern "C" void kernel_launch(void* const* d_in, const int* in_sizes, int n_in,
                              void* d_out, int out_size, void* d_ws, size_t ws_size,
                              hipStream_t stream) {
    const float* x     = (const float*)d_in[0];
    const int*   ast   = (const int*)d_in[1];
    const int*   batch = (const int*)d_in[2];
    const int*   ei    = (const int*)d_in[3];
    const float* emb   = (const float*)d_in[4];
    const float* W_in  = (const float*)d_in[5];
    const float* b_in  = (const float*)d_in[6];
    const float* W_l   = (const float*)d_in[7];
    const float* b_l   = (const float*)d_in[8];
    const float* W_r   = (const float*)d_in[9];
    const float* gamma = (const float*)d_in[10];
    const float* beta  = (const float*)d_in[11];
    float* out = (float*)d_out;

    const int M  = TT * NN;
    const int NB = (M + 1023) / 1024;

    char* p = (char*)d_ws;
    float* h32 = (float*)p;                    p += (size_t)NN * HH * 4;   // 51.2 MB
    float* ob  = (float*)p;                    p += (size_t)NN * HH * 4;   // 51.2 MB
    unsigned short* Wt16 = (unsigned short*)p; p += (size_t)LL * 4 * 2 * HH * HH * 2;
    float* blsum = (float*)p;                  p += LL * HH * 4;
    int* cnt    = (int*)p;                     p += (size_t)M * 4;
    int* offs   = (int*)p;                     p += (size_t)M * 4;
    int* cursor = (int*)p;                     p += (size_t)M * 4;
    int* csr    = (int*)p;                     p += (size_t)TT * EE * 4;
    int* bsums  = (int*)p;

    hipMemsetAsync(cnt, 0, (size_t)M * sizeof(int), stream);
    count_kernel<<<(TT * EE + 255) / 256, 256, 0, stream>>>(ei, cnt);
    scan1_kernel<<<NB, 256, 0, stream>>>(cnt, offs, bsums, M);
    scan2_kernel<<<1, 512, 0, stream>>>(bsums, NB);
    scan3_kernel<<<(M + 255) / 256, 256, 0, stream>>>(offs, bsums, cursor, M);
    fill_kernel<<<(TT * EE + 255) / 256, 256, 0, stream>>>(ei, cursor, csr);
    wprep_kernel<<<(LL * 4 * HH * HH + 255) / 256, 256, 0, stream>>>(W_l, W_r, b_l, Wt16, blsum);
    input_proj_kernel<<<512, 512, 0, stream>>>(x, ast, emb, W_in, b_in, h32);

    int conv_grid = (NN + 63) / 64;
    int ln_grid = (NN + 3) / 4;
    // layer 0: h32 -> ob, LN in-place on ob
    conv_kernel<<<conv_grid, 512, 0, stream>>>(h32, Wt16, blsum, offs, cnt, csr, ob);
    layernorm_kernel<<<ln_grid, 256, 0, stream>>>(ob, gamma, beta, ob, NN);
    // layer 1: ob -> h32, LN in-place on h32
    conv_kernel<<<conv_grid, 512, 0, stream>>>(ob, Wt16 + (size_t)4 * 2 * HH * HH,
                                               blsum + HH, offs, cnt, csr, h32);
    layernorm_kernel<<<ln_grid, 256, 0, stream>>>(h32, gamma + HH, beta + HH, h32, NN);
    pool_kernel<<<BB, 256, 0, stream>>>(h32, batch, out);
}

// Round 6
// 516.607 us; speedup vs baseline: 8.5405x; 1.3632x over previous
//
#include <hip/hip_runtime.h>
#include <hip/hip_bf16.h>
#include <math.h>

#define NN 100000   // nodes
#define EE 300000   // edges per type
#define TT 3        // edge types
#define LL 2        // layers
#define HH 128      // hidden
#define FF 5        // node feat
#define TE 64       // type embed
#define NT 200      // num ast types
#define BB 64       // graphs
#define NC 16       // pooling chunks per graph

typedef short bf16x8 __attribute__((ext_vector_type(8)));
typedef float f32x4  __attribute__((ext_vector_type(4)));

__device__ __forceinline__ float bf2f(unsigned short u) {
    union { unsigned i; float f; } v; v.i = ((unsigned)u) << 16; return v.f;
}
__device__ __forceinline__ unsigned short f2bf(float f) {
    union { float f; unsigned i; } v; v.f = f;
    unsigned b = v.i + (0x7FFFu + ((v.i >> 16) & 1u));   // RNE
    return (unsigned short)(b >> 16);
}
// split x ~= hi + lo (two bf16); hi+lo reproduces x to ~2^-16 rel
__device__ __forceinline__ void split_bf(float x, unsigned short& hi, unsigned short& lo) {
    hi = f2bf(x);
    lo = f2bf(x - bf2f(hi));
}

// ================================================================ CSR build (validated R2)
__global__ void count_kernel(const int* __restrict__ ei, int* __restrict__ cnt) {
    int i = blockIdx.x * blockDim.x + threadIdx.x;
    if (i >= TT * EE) return;
    int t = i / EE, e = i - t * EE;
    int dst = ei[(t * 2 + 1) * EE + e];
    atomicAdd(&cnt[t * NN + dst], 1);
}

__global__ __launch_bounds__(256) void scan1_kernel(const int* __restrict__ cnt,
                                                    int* __restrict__ offs,
                                                    int* __restrict__ bsums, int M) {
    int tid = threadIdx.x;
    int base = blockIdx.x * 1024 + tid * 4;
    int a0 = 0, a1 = 0, a2 = 0, a3 = 0;
    if (base + 3 < M) { int4 v = *(const int4*)&cnt[base]; a0 = v.x; a1 = v.y; a2 = v.z; a3 = v.w; }
    else {
        if (base + 0 < M) a0 = cnt[base + 0];
        if (base + 1 < M) a1 = cnt[base + 1];
        if (base + 2 < M) a2 = cnt[base + 2];
        if (base + 3 < M) a3 = cnt[base + 3];
    }
    int s = a0 + a1 + a2 + a3;
    int lane = tid & 63, wv = tid >> 6;
    int x = s;
    #pragma unroll
    for (int o = 1; o < 64; o <<= 1) { int y = __shfl_up(x, o); if (lane >= o) x += y; }
    __shared__ int wsum[4];
    if (lane == 63) wsum[wv] = x;
    __syncthreads();
    int add = 0;
    for (int w = 0; w < wv; ++w) add += wsum[w];
    int incl = x + add;
    int e0 = incl - s, e1 = e0 + a0, e2 = e1 + a1, e3 = e2 + a2;
    if (base + 0 < M) offs[base + 0] = e0;
    if (base + 1 < M) offs[base + 1] = e1;
    if (base + 2 < M) offs[base + 2] = e2;
    if (base + 3 < M) offs[base + 3] = e3;
    if (tid == 255) bsums[blockIdx.x] = incl;
}

__global__ __launch_bounds__(512) void scan2_kernel(int* __restrict__ bsums, int NB) {
    int tid = threadIdx.x;
    int s = (tid < NB) ? bsums[tid] : 0;
    int lane = tid & 63, wv = tid >> 6;
    int x = s;
    #pragma unroll
    for (int o = 1; o < 64; o <<= 1) { int y = __shfl_up(x, o); if (lane >= o) x += y; }
    __shared__ int wsum[8];
    if (lane == 63) wsum[wv] = x;
    __syncthreads();
    int add = 0;
    for (int w = 0; w < wv; ++w) add += wsum[w];
    if (tid < NB) bsums[tid] = x + add - s;
}

__global__ void scan3_kernel(int* __restrict__ offs, const int* __restrict__ bsums,
                             int* __restrict__ cursor, int M) {
    int i = blockIdx.x * 256 + threadIdx.x;
    if (i >= M) return;
    int v = offs[i] + bsums[i >> 10];
    offs[i] = v;
    cursor[i] = v;
}

__global__ void fill_kernel(const int* __restrict__ ei, int* __restrict__ cursor,
                            int* __restrict__ csr) {
    int i = blockIdx.x * blockDim.x + threadIdx.x;
    if (i >= TT * EE) return;
    int t = i / EE, e = i - t * EE;
    int src = ei[(t * 2 + 0) * EE + e];
    int dst = ei[(t * 2 + 1) * EE + e];
    int pos = atomicAdd(&cursor[t * NN + dst], 1);
    csr[pos] = src;
}

// ================================================================ weight prep
// Wt16 layout: [l][m][plane][col][k], plane 0 = hi, 1 = lo. m=0 -> sum_t W_r^T, m=1..3 -> W_l[t]^T.
__global__ void wprep_kernel(const float* __restrict__ W_l, const float* __restrict__ W_r,
                             const float* __restrict__ b_l,
                             unsigned short* __restrict__ Wt16, float* __restrict__ blsum) {
    int i = blockIdx.x * 256 + threadIdx.x;
    if (i < LL * 4 * HH * HH) {
        int lm = i >> 14;          // l*4 + m
        int ck = i & 16383;
        int col = ck >> 7, k = ck & 127;
        int l = lm >> 2, m = lm & 3;
        float v;
        if (m == 0) {
            v = 0.f;
            for (int t = 0; t < TT; ++t)
                v += W_r[(((size_t)(l * TT + t)) << 14) + k * HH + col];
        } else {
            v = W_l[(((size_t)(l * TT + (m - 1))) << 14) + k * HH + col];
        }
        unsigned short hi, lo;
        split_bf(v, hi, lo);
        Wt16[((size_t)lm << 15) + ck]         = hi;
        Wt16[((size_t)lm << 15) + 16384 + ck] = lo;
    }
    if (i < LL * HH) {
        int l = i >> 7, j = i & 127;
        float s = 0.f;
        for (int t = 0; t < TT; ++t) s += b_l[(l * TT + t) * HH + j];
        blsum[i] = s;
    }
}

// ================================================================ input projection (validated R2, verbatim)
__global__ __launch_bounds__(512) void input_proj_kernel(
    const float* __restrict__ x, const int* __restrict__ ast,
    const float* __restrict__ emb, const float* __restrict__ W_in,
    const float* __restrict__ b_in, float* __restrict__ h)
{
    __shared__ float Ws[(TE + FF) * HH];   // 35.3 KB
    __shared__ float Es[NT * TE];          // 51.2 KB
    int tid = threadIdx.x;
    for (int i = tid; i < (TE + FF) * HH; i += 512) Ws[i] = W_in[i];
    for (int i = tid; i < NT * TE; i += 512) Es[i] = emb[i];
    __syncthreads();
    int col = tid & 127, nl = tid >> 7;    // 4 nodes per block-iteration
    float bj = b_in[col];
    for (int n = blockIdx.x * 4 + nl; n < NN; n += gridDim.x * 4) {
        int a = ast[n];
        float acc = bj;
        const float* ep = &Es[a * TE];
        #pragma unroll
        for (int k = 0; k < TE; ++k) acc = fmaf(ep[k], Ws[k * HH + col], acc);
        #pragma unroll
        for (int k = 0; k < FF; ++k) acc = fmaf(x[n * FF + k], Ws[(TE + k) * HH + col], acc);
        h[(size_t)n * HH + col] = acc;
    }
}

// ================================================================ conv layer (split-bf16 MFMA, padded-linear LDS) — validated R5, verbatim
#define ALD 136   // padded LDS stride (shorts): 272 B -> 2-way bank aliasing (free)

__global__ __launch_bounds__(512) void conv_kernel(
    const float* __restrict__ h,                 // [N][128] f32
    const unsigned short* __restrict__ Wt_l,     // [4][2][128][128] bf16 (hi/lo planes, W^T)
    const float* __restrict__ blsum_l,
    const int* __restrict__ offs, const int* __restrict__ cnt, const int* __restrict__ csr,
    float* __restrict__ ob)
{
    __shared__ unsigned short Wl[128 * ALD];     // 34.8 KB
    __shared__ unsigned short Ahi[64 * ALD];     // 17.4 KB
    __shared__ unsigned short Alo[64 * ALD];     // 17.4 KB

    int tid = threadIdx.x;
    int row0 = blockIdx.x * 64;
    int w = tid >> 6, l = tid & 63;
    int R0 = (w >> 1) * 16, C0 = (w & 1) * 64;
    int l15 = l & 15, koff = (l >> 4) * 8;
    f32x4 acc[4] = {};

    for (int m = 0; m < 4; ++m) {
        // ---- stage A-tile (hi/lo split), padded linear layout
        if (m == 0) {
            #pragma unroll
            for (int s2 = 0; s2 < 2; ++s2) {
                int c16 = s2 * 512 + tid;
                int r = c16 >> 4, k0 = (c16 & 15) * 8;
                int gr = row0 + r;
                float v[8] = {0.f,0.f,0.f,0.f,0.f,0.f,0.f,0.f};
                if (gr < NN) {
                    float4 va = *(const float4*)&h[(size_t)gr * 128 + k0];
                    float4 vb = *(const float4*)&h[(size_t)gr * 128 + k0 + 4];
                    v[0]=va.x; v[1]=va.y; v[2]=va.z; v[3]=va.w;
                    v[4]=vb.x; v[5]=vb.y; v[6]=vb.z; v[7]=vb.w;
                }
                unsigned short hs[8], ls[8];
                #pragma unroll
                for (int j = 0; j < 8; ++j) split_bf(v[j], hs[j], ls[j]);
                uint4 hv, lv;
                hv.x = (unsigned)hs[0] | ((unsigned)hs[1] << 16);
                hv.y = (unsigned)hs[2] | ((unsigned)hs[3] << 16);
                hv.z = (unsigned)hs[4] | ((unsigned)hs[5] << 16);
                hv.w = (unsigned)hs[6] | ((unsigned)hs[7] << 16);
                lv.x = (unsigned)ls[0] | ((unsigned)ls[1] << 16);
                lv.y = (unsigned)ls[2] | ((unsigned)ls[3] << 16);
                lv.z = (unsigned)ls[4] | ((unsigned)ls[5] << 16);
                lv.w = (unsigned)ls[6] | ((unsigned)ls[7] << 16);
                *(uint4*)&Ahi[r * ALD + k0] = hv;
                *(uint4*)&Alo[r * ALD + k0] = lv;
            }
        } else {
            int t = m - 1;
            int r = tid >> 3, sub = tid & 7;
            int gr = row0 + r;
            float s[16];
            #pragma unroll
            for (int j = 0; j < 16; ++j) s[j] = 0.f;
            int c = 0;
            if (gr < NN) {
                int base = t * NN + gr;
                int o = offs[base];
                c = cnt[base];
                for (int j = 0; j < c; ++j) {
                    int src = csr[o + j];
                    const float4* hp = (const float4*)&h[(size_t)src * 128 + sub * 16];
                    float4 v0 = hp[0], v1 = hp[1], v2 = hp[2], v3 = hp[3];
                    s[0]  += v0.x; s[1]  += v0.y; s[2]  += v0.z; s[3]  += v0.w;
                    s[4]  += v1.x; s[5]  += v1.y; s[6]  += v1.z; s[7]  += v1.w;
                    s[8]  += v2.x; s[9]  += v2.y; s[10] += v2.z; s[11] += v2.w;
                    s[12] += v3.x; s[13] += v3.y; s[14] += v3.z; s[15] += v3.w;
                }
            }
            float inv = (c > 0) ? 1.0f / (float)c : 0.0f;
            unsigned short hs[16], ls[16];
            #pragma unroll
            for (int j = 0; j < 16; ++j) split_bf(s[j] * inv, hs[j], ls[j]);
            uint4 hv0, hv1, lv0, lv1;
            hv0.x = (unsigned)hs[0]  | ((unsigned)hs[1]  << 16);
            hv0.y = (unsigned)hs[2]  | ((unsigned)hs[3]  << 16);
            hv0.z = (unsigned)hs[4]  | ((unsigned)hs[5]  << 16);
            hv0.w = (unsigned)hs[6]  | ((unsigned)hs[7]  << 16);
            hv1.x = (unsigned)hs[8]  | ((unsigned)hs[9]  << 16);
            hv1.y = (unsigned)hs[10] | ((unsigned)hs[11] << 16);
            hv1.z = (unsigned)hs[12] | ((unsigned)hs[13] << 16);
            hv1.w = (unsigned)hs[14] | ((unsigned)hs[15] << 16);
            lv0.x = (unsigned)ls[0]  | ((unsigned)ls[1]  << 16);
            lv0.y = (unsigned)ls[2]  | ((unsigned)ls[3]  << 16);
            lv0.z = (unsigned)ls[4]  | ((unsigned)ls[5]  << 16);
            lv0.w = (unsigned)ls[6]  | ((unsigned)ls[7]  << 16);
            lv1.x = (unsigned)ls[8]  | ((unsigned)ls[9]  << 16);
            lv1.y = (unsigned)ls[10] | ((unsigned)ls[11] << 16);
            lv1.z = (unsigned)ls[12] | ((unsigned)ls[13] << 16);
            lv1.w = (unsigned)ls[14] | ((unsigned)ls[15] << 16);
            *(uint4*)&Ahi[r * ALD + sub * 16]     = hv0;
            *(uint4*)&Ahi[r * ALD + sub * 16 + 8] = hv1;
            *(uint4*)&Alo[r * ALD + sub * 16]     = lv0;
            *(uint4*)&Alo[r * ALD + sub * 16 + 8] = lv1;
        }
        // ---- stage W hi plane (linear)
        const unsigned short* Whi = Wt_l + ((size_t)m << 15);
        #pragma unroll
        for (int s2 = 0; s2 < 4; ++s2) {
            int c16 = s2 * 512 + tid;
            int col = c16 >> 4, k0 = (c16 & 15) * 8;
            *(uint4*)&Wl[col * ALD + k0] = *(const uint4*)&Whi[col * 128 + k0];
        }
        __syncthreads();
        // ---- hi pass: (a_hi + a_lo) * w_hi
        #pragma unroll
        for (int ks = 0; ks < 4; ++ks) {
            int k0 = ks * 32 + koff;
            bf16x8 ah = *(const bf16x8*)&Ahi[(R0 + l15) * ALD + k0];
            bf16x8 al = *(const bf16x8*)&Alo[(R0 + l15) * ALD + k0];
            #pragma unroll
            for (int n = 0; n < 4; ++n) {
                bf16x8 b = *(const bf16x8*)&Wl[(C0 + n * 16 + l15) * ALD + k0];
                acc[n] = __builtin_amdgcn_mfma_f32_16x16x32_bf16(ah, b, acc[n], 0, 0, 0);
                acc[n] = __builtin_amdgcn_mfma_f32_16x16x32_bf16(al, b, acc[n], 0, 0, 0);
            }
        }
        __syncthreads();
        // ---- stage W lo plane
        const unsigned short* Wlo = Whi + 16384;
        #pragma unroll
        for (int s2 = 0; s2 < 4; ++s2) {
            int c16 = s2 * 512 + tid;
            int col = c16 >> 4, k0 = (c16 & 15) * 8;
            *(uint4*)&Wl[col * ALD + k0] = *(const uint4*)&Wlo[col * 128 + k0];
        }
        __syncthreads();
        // ---- lo pass: (a_hi + a_lo) * w_lo  -> full (ahi+alo)(whi+wlo)
        #pragma unroll
        for (int ks = 0; ks < 4; ++ks) {
            int k0 = ks * 32 + koff;
            bf16x8 ah = *(const bf16x8*)&Ahi[(R0 + l15) * ALD + k0];
            bf16x8 al = *(const bf16x8*)&Alo[(R0 + l15) * ALD + k0];
            #pragma unroll
            for (int n = 0; n < 4; ++n) {
                bf16x8 b = *(const bf16x8*)&Wl[(C0 + n * 16 + l15) * ALD + k0];
                acc[n] = __builtin_amdgcn_mfma_f32_16x16x32_bf16(ah, b, acc[n], 0, 0, 0);
                acc[n] = __builtin_amdgcn_mfma_f32_16x16x32_bf16(al, b, acc[n], 0, 0, 0);
            }
        }
        __syncthreads();   // before next m overwrites LDS
    }

    // ---- bias + raw global store (m89 C/D layout: col=lane&15, row=(lane>>4)*4+reg)
    #pragma unroll
    for (int n = 0; n < 4; ++n) {
        int cc = C0 + n * 16 + l15;
        float bv = blsum_l[cc];
        #pragma unroll
        for (int i = 0; i < 4; ++i) {
            int gr = row0 + R0 + (l >> 4) * 4 + i;
            if (gr < NN) ob[(size_t)gr * HH + cc] = acc[n][i] + bv;
        }
    }
}

// ================================================================ layernorm (validated R1, in-place safe)
__global__ void layernorm_kernel(const float* __restrict__ in, const float* __restrict__ gamma,
                                 const float* __restrict__ beta, float* __restrict__ out, int rows) {
    int lane = threadIdx.x & 63;
    int row = blockIdx.x * 4 + (threadIdx.x >> 6);
    if (row >= rows) return;
    float2 v = *reinterpret_cast<const float2*>(&in[(size_t)row * HH + lane * 2]);
    float s = v.x + v.y, sq = v.x * v.x + v.y * v.y;
    #pragma unroll
    for (int o = 32; o; o >>= 1) { s += __shfl_xor(s, o); sq += __shfl_xor(sq, o); }
    float mu = s * (1.0f / HH);
    float var = sq * (1.0f / HH) - mu * mu;
    float r = rsqrtf(var + 1e-5f);
    float2 gj = *reinterpret_cast<const float2*>(&gamma[lane * 2]);
    float2 bj = *reinterpret_cast<const float2*>(&beta[lane * 2]);
    float2 o2;
    o2.x = (v.x - mu) * r * gj.x + bj.x;
    o2.y = (v.y - mu) * r * gj.y + bj.y;
    *reinterpret_cast<float2*>(&out[(size_t)row * HH + lane * 2]) = o2;
}

// ================================================================ two-stage pooling
// stage 1: 64 graphs x NC chunks; partial sum/max per (chunk, dim)
__global__ void pool1_kernel(const float* __restrict__ h, const int* __restrict__ batch,
                             float* __restrict__ psum, float* __restrict__ pmax) {
    int g = blockIdx.x >> 4, c = blockIdx.x & (NC - 1);
    int start, end;
    {
        int lo = 0, hi = NN;
        while (lo < hi) { int mid = (lo + hi) >> 1; if (batch[mid] < g) lo = mid + 1; else hi = mid; }
        start = lo;
        hi = NN;
        while (lo < hi) { int mid = (lo + hi) >> 1; if (batch[mid] < g + 1) lo = mid + 1; else hi = mid; }
        end = lo;
    }
    int len = end - start;
    int chunk = (len + NC - 1) / NC;
    int clo = start + c * chunk;
    int chi = min(clo + chunk, end);
    int tid = threadIdx.x;
    int d = tid & 127, half = tid >> 7;
    float s = 0.f, m = -INFINITY;
    for (int n = clo + half; n < chi; n += 2) {
        float v = h[(size_t)n * HH + d];
        s += v; m = fmaxf(m, v);
    }
    __shared__ float ss[256], sm[256];
    ss[tid] = s; sm[tid] = m;
    __syncthreads();
    if (half == 0) {
        s += ss[tid + 128];
        m = fmaxf(m, sm[tid + 128]);
        psum[(size_t)blockIdx.x * HH + d] = s;
        pmax[(size_t)blockIdx.x * HH + d] = m;
    }
}

// stage 2: fold NC partials per graph, finalize mean/max
__global__ void pool2_kernel(const float* __restrict__ psum, const float* __restrict__ pmax,
                             const int* __restrict__ batch, float* __restrict__ out) {
    int g = blockIdx.x;
    int d = threadIdx.x;   // 128 threads
    int start, end;
    {
        int lo = 0, hi = NN;
        while (lo < hi) { int mid = (lo + hi) >> 1; if (batch[mid] < g) lo = mid + 1; else hi = mid; }
        start = lo;
        hi = NN;
        while (lo < hi) { int mid = (lo + hi) >> 1; if (batch[mid] < g + 1) lo = mid + 1; else hi = mid; }
        end = lo;
    }
    float s = 0.f, m = -INFINITY;
    #pragma unroll
    for (int c = 0; c < NC; ++c) {
        s += psum[(size_t)(g * NC + c) * HH + d];
        m = fmaxf(m, pmax[(size_t)(g * NC + c) * HH + d]);
    }
    int cg = end - start;
    out[g * 2 * HH + d] = s / fmaxf((float)cg, 1.0f);
    out[g * 2 * HH + HH + d] = (cg > 0) ? m : 0.0f;
}

// ================================================================ launch
extern "C" void kernel_launch(void* const* d_in, const int* in_sizes, int n_in,
                              void* d_out, int out_size, void* d_ws, size_t ws_size,
                              hipStream_t stream) {
    const float* x     = (const float*)d_in[0];
    const int*   ast   = (const int*)d_in[1];
    const int*   batch = (const int*)d_in[2];
    const int*   ei    = (const int*)d_in[3];
    const float* emb   = (const float*)d_in[4];
    const float* W_in  = (const float*)d_in[5];
    const float* b_in  = (const float*)d_in[6];
    const float* W_l   = (const float*)d_in[7];
    const float* b_l   = (const float*)d_in[8];
    const float* W_r   = (const float*)d_in[9];
    const float* gamma = (const float*)d_in[10];
    const float* beta  = (const float*)d_in[11];
    float* out = (float*)d_out;

    const int M  = TT * NN;
    const int NB = (M + 1023) / 1024;

    char* p = (char*)d_ws;
    float* h32 = (float*)p;                    p += (size_t)NN * HH * 4;   // 51.2 MB
    float* ob  = (float*)p;                    p += (size_t)NN * HH * 4;   // 51.2 MB
    unsigned short* Wt16 = (unsigned short*)p; p += (size_t)LL * 4 * 2 * HH * HH * 2;
    float* blsum = (float*)p;                  p += LL * HH * 4;
    float* psum = (float*)p;                   p += (size_t)BB * NC * HH * 4;
    float* pmax = (float*)p;                   p += (size_t)BB * NC * HH * 4;
    int* cnt    = (int*)p;                     p += (size_t)M * 4;
    int* offs   = (int*)p;                     p += (size_t)M * 4;
    int* cursor = (int*)p;                     p += (size_t)M * 4;
    int* csr    = (int*)p;                     p += (size_t)TT * EE * 4;
    int* bsums  = (int*)p;

    hipMemsetAsync(cnt, 0, (size_t)M * sizeof(int), stream);
    count_kernel<<<(TT * EE + 255) / 256, 256, 0, stream>>>(ei, cnt);
    scan1_kernel<<<NB, 256, 0, stream>>>(cnt, offs, bsums, M);
    scan2_kernel<<<1, 512, 0, stream>>>(bsums, NB);
    scan3_kernel<<<(M + 255) / 256, 256, 0, stream>>>(offs, bsums, cursor, M);
    fill_kernel<<<(TT * EE + 255) / 256, 256, 0, stream>>>(ei, cursor, csr);
    wprep_kernel<<<(LL * 4 * HH * HH + 255) / 256, 256, 0, stream>>>(W_l, W_r, b_l, Wt16, blsum);
    input_proj_kernel<<<512, 512, 0, stream>>>(x, ast, emb, W_in, b_in, h32);

    int conv_grid = (NN + 63) / 64;
    int ln_grid = (NN + 3) / 4;
    // layer 0: h32 -> ob, LN in-place on ob
    conv_kernel<<<conv_grid, 512, 0, stream>>>(h32, Wt16, blsum, offs, cnt, csr, ob);
    layernorm_kernel<<<ln_grid, 256, 0, stream>>>(ob, gamma, beta, ob, NN);
    // layer 1: ob -> h32, LN in-place on h32
    conv_kernel<<<conv_grid, 512, 0, stream>>>(ob, Wt16 + (size_t)4 * 2 * HH * HH,
                                               blsum + HH, offs, cnt, csr, h32);
    layernorm_kernel<<<ln_grid, 256, 0, stream>>>(h32, gamma + HH, beta + HH, h32, NN);
    // two-stage pooling
    pool1_kernel<<<BB * NC, 256, 0, stream>>>(h32, batch, psum, pmax);
    pool2_kernel<<<BB, HH, 0, stream>>>(psum, pmax, batch, out);
}

// Round 7
// 503.726 us; speedup vs baseline: 8.7589x; 1.0256x over previous
//
#include <hip/hip_runtime.h>
#include <hip/hip_bf16.h>
#include <math.h>

#define NN 100000   // nodes
#define EE 300000   // edges per type
#define TT 3        // edge types
#define LL 2        // layers
#define HH 128      // hidden
#define FF 5        // node feat
#define TE 64       // type embed
#define NT 200      // num ast types
#define BB 64       // graphs
#define NC 16       // pooling chunks per graph
#define CSRCAP 512  // per-type per-block LDS index cap (mean ~192, 23 sigma)

typedef short bf16x8 __attribute__((ext_vector_type(8)));
typedef float f32x4  __attribute__((ext_vector_type(4)));

__device__ __forceinline__ float bf2f(unsigned short u) {
    union { unsigned i; float f; } v; v.i = ((unsigned)u) << 16; return v.f;
}
__device__ __forceinline__ unsigned short f2bf(float f) {
    union { float f; unsigned i; } v; v.f = f;
    unsigned b = v.i + (0x7FFFu + ((v.i >> 16) & 1u));   // RNE
    return (unsigned short)(b >> 16);
}
// split x ~= hi + lo (two bf16); hi+lo reproduces x to ~2^-16 rel
__device__ __forceinline__ void split_bf(float x, unsigned short& hi, unsigned short& lo) {
    hi = f2bf(x);
    lo = f2bf(x - bf2f(hi));
}

// ================================================================ CSR build (validated R2)
__global__ void count_kernel(const int* __restrict__ ei, int* __restrict__ cnt) {
    int i = blockIdx.x * blockDim.x + threadIdx.x;
    if (i >= TT * EE) return;
    int t = i / EE, e = i - t * EE;
    int dst = ei[(t * 2 + 1) * EE + e];
    atomicAdd(&cnt[t * NN + dst], 1);
}

__global__ __launch_bounds__(256) void scan1_kernel(const int* __restrict__ cnt,
                                                    int* __restrict__ offs,
                                                    int* __restrict__ bsums, int M) {
    int tid = threadIdx.x;
    int base = blockIdx.x * 1024 + tid * 4;
    int a0 = 0, a1 = 0, a2 = 0, a3 = 0;
    if (base + 3 < M) { int4 v = *(const int4*)&cnt[base]; a0 = v.x; a1 = v.y; a2 = v.z; a3 = v.w; }
    else {
        if (base + 0 < M) a0 = cnt[base + 0];
        if (base + 1 < M) a1 = cnt[base + 1];
        if (base + 2 < M) a2 = cnt[base + 2];
        if (base + 3 < M) a3 = cnt[base + 3];
    }
    int s = a0 + a1 + a2 + a3;
    int lane = tid & 63, wv = tid >> 6;
    int x = s;
    #pragma unroll
    for (int o = 1; o < 64; o <<= 1) { int y = __shfl_up(x, o); if (lane >= o) x += y; }
    __shared__ int wsum[4];
    if (lane == 63) wsum[wv] = x;
    __syncthreads();
    int add = 0;
    for (int w = 0; w < wv; ++w) add += wsum[w];
    int incl = x + add;
    int e0 = incl - s, e1 = e0 + a0, e2 = e1 + a1, e3 = e2 + a2;
    if (base + 0 < M) offs[base + 0] = e0;
    if (base + 1 < M) offs[base + 1] = e1;
    if (base + 2 < M) offs[base + 2] = e2;
    if (base + 3 < M) offs[base + 3] = e3;
    if (tid == 255) bsums[blockIdx.x] = incl;
}

__global__ __launch_bounds__(512) void scan2_kernel(int* __restrict__ bsums, int NB) {
    int tid = threadIdx.x;
    int s = (tid < NB) ? bsums[tid] : 0;
    int lane = tid & 63, wv = tid >> 6;
    int x = s;
    #pragma unroll
    for (int o = 1; o < 64; o <<= 1) { int y = __shfl_up(x, o); if (lane >= o) x += y; }
    __shared__ int wsum[8];
    if (lane == 63) wsum[wv] = x;
    __syncthreads();
    int add = 0;
    for (int w = 0; w < wv; ++w) add += wsum[w];
    if (tid < NB) bsums[tid] = x + add - s;
}

__global__ void scan3_kernel(int* __restrict__ offs, const int* __restrict__ bsums,
                             int* __restrict__ cursor, int M) {
    int i = blockIdx.x * 256 + threadIdx.x;
    if (i >= M) return;
    int v = offs[i] + bsums[i >> 10];
    offs[i] = v;
    cursor[i] = v;
}

__global__ void fill_kernel(const int* __restrict__ ei, int* __restrict__ cursor,
                            int* __restrict__ csr) {
    int i = blockIdx.x * blockDim.x + threadIdx.x;
    if (i >= TT * EE) return;
    int t = i / EE, e = i - t * EE;
    int src = ei[(t * 2 + 0) * EE + e];
    int dst = ei[(t * 2 + 1) * EE + e];
    int pos = atomicAdd(&cursor[t * NN + dst], 1);
    csr[pos] = src;
}

// ================================================================ weight prep
// Wt16 layout: [l][m][plane][col][k], plane 0 = hi, 1 = lo. m=0 -> sum_t W_r^T, m=1..3 -> W_l[t]^T.
__global__ void wprep_kernel(const float* __restrict__ W_l, const float* __restrict__ W_r,
                             const float* __restrict__ b_l,
                             unsigned short* __restrict__ Wt16, float* __restrict__ blsum) {
    int i = blockIdx.x * 256 + threadIdx.x;
    if (i < LL * 4 * HH * HH) {
        int lm = i >> 14;          // l*4 + m
        int ck = i & 16383;
        int col = ck >> 7, k = ck & 127;
        int l = lm >> 2, m = lm & 3;
        float v;
        if (m == 0) {
            v = 0.f;
            for (int t = 0; t < TT; ++t)
                v += W_r[(((size_t)(l * TT + t)) << 14) + k * HH + col];
        } else {
            v = W_l[(((size_t)(l * TT + (m - 1))) << 14) + k * HH + col];
        }
        unsigned short hi, lo;
        split_bf(v, hi, lo);
        Wt16[((size_t)lm << 15) + ck]         = hi;
        Wt16[((size_t)lm << 15) + 16384 + ck] = lo;
    }
    if (i < LL * HH) {
        int l = i >> 7, j = i & 127;
        float s = 0.f;
        for (int t = 0; t < TT; ++t) s += b_l[(l * TT + t) * HH + j];
        blsum[i] = s;
    }
}

// ================================================================ input projection (validated R2, verbatim)
__global__ __launch_bounds__(512) void input_proj_kernel(
    const float* __restrict__ x, const int* __restrict__ ast,
    const float* __restrict__ emb, const float* __restrict__ W_in,
    const float* __restrict__ b_in, float* __restrict__ h)
{
    __shared__ float Ws[(TE + FF) * HH];   // 35.3 KB
    __shared__ float Es[NT * TE];          // 51.2 KB
    int tid = threadIdx.x;
    for (int i = tid; i < (TE + FF) * HH; i += 512) Ws[i] = W_in[i];
    for (int i = tid; i < NT * TE; i += 512) Es[i] = emb[i];
    __syncthreads();
    int col = tid & 127, nl = tid >> 7;    // 4 nodes per block-iteration
    float bj = b_in[col];
    for (int n = blockIdx.x * 4 + nl; n < NN; n += gridDim.x * 4) {
        int a = ast[n];
        float acc = bj;
        const float* ep = &Es[a * TE];
        #pragma unroll
        for (int k = 0; k < TE; ++k) acc = fmaf(ep[k], Ws[k * HH + col], acc);
        #pragma unroll
        for (int k = 0; k < FF; ++k) acc = fmaf(x[n * FF + k], Ws[(TE + k) * HH + col], acc);
        h[(size_t)n * HH + col] = acc;
    }
}

// ================================================================ conv layer (split-bf16 MFMA)
// R7: CSR indices bulk-staged in LDS; all 3 gathers hoisted to registers before
// the m-loop (one latency exposure). MFMA math bit-identical to validated R5.
#define ALD 136   // padded LDS stride (shorts): 272 B -> 2-way bank aliasing (free)

__global__ __launch_bounds__(512) void conv_kernel(
    const float* __restrict__ h,                 // [N][128] f32
    const unsigned short* __restrict__ Wt_l,     // [4][2][128][128] bf16 (hi/lo planes, W^T)
    const float* __restrict__ blsum_l,
    const int* __restrict__ offs, const int* __restrict__ cnt, const int* __restrict__ csr,
    float* __restrict__ ob)
{
    __shared__ unsigned short Wl[128 * ALD];     // 34.8 KB
    __shared__ unsigned short Ahi[64 * ALD];     // 17.4 KB
    __shared__ unsigned short Alo[64 * ALD];     // 17.4 KB
    __shared__ int csr_lds[TT][CSRCAP];          // 6 KB
    __shared__ int base_lds[TT], len_lds[TT], flag_lds[TT];

    int tid = threadIdx.x;
    int row0 = blockIdx.x * 64;
    int nrow = min(64, NN - row0);
    int w = tid >> 6, l = tid & 63;
    int R0 = (w >> 1) * 16, C0 = (w & 1) * 64;
    int l15 = l & 15, koff = (l >> 4) * 8;

    // ---- stage CSR ranges (rows are consecutive -> each type's slice is contiguous)
    if (tid < TT) {
        int t = tid;
        int last = row0 + nrow - 1;
        int b = offs[t * NN + row0];
        int e = offs[t * NN + last] + cnt[t * NN + last];
        base_lds[t] = b;
        len_lds[t] = e - b;
        flag_lds[t] = (e - b) <= CSRCAP;
    }
    __syncthreads();
    #pragma unroll
    for (int t = 0; t < TT; ++t) {
        if (flag_lds[t]) {
            int b = base_lds[t], len = len_lds[t];
            for (int i = tid; i < len; i += 512) csr_lds[t][i] = csr[b + i];
        }
    }
    __syncthreads();

    // ---- gather all 3 types into registers (max MLP, no barriers in between)
    int r = tid >> 3, sub = tid & 7;
    int gr = row0 + r;
    float ms[TT][16];
    float invc[TT];
    #pragma unroll
    for (int t = 0; t < TT; ++t) {
        invc[t] = 0.f;
        #pragma unroll
        for (int j = 0; j < 16; ++j) ms[t][j] = 0.f;
    }
    if (gr < NN) {
        #pragma unroll
        for (int t = 0; t < TT; ++t) {
            int o = offs[t * NN + gr];
            int c = cnt[t * NN + gr];
            invc[t] = (c > 0) ? 1.0f / (float)c : 0.0f;
            bool inl = flag_lds[t] != 0;
            int rel = o - base_lds[t];
            for (int j = 0; j < c; ++j) {
                int src = inl ? csr_lds[t][rel + j] : csr[o + j];
                const float4* hp = (const float4*)&h[(size_t)src * 128 + sub * 16];
                float4 v0 = hp[0], v1 = hp[1], v2 = hp[2], v3 = hp[3];
                ms[t][0]  += v0.x; ms[t][1]  += v0.y; ms[t][2]  += v0.z; ms[t][3]  += v0.w;
                ms[t][4]  += v1.x; ms[t][5]  += v1.y; ms[t][6]  += v1.z; ms[t][7]  += v1.w;
                ms[t][8]  += v2.x; ms[t][9]  += v2.y; ms[t][10] += v2.z; ms[t][11] += v2.w;
                ms[t][12] += v3.x; ms[t][13] += v3.y; ms[t][14] += v3.z; ms[t][15] += v3.w;
            }
        }
    }

    f32x4 acc[4] = {};

    #pragma unroll
    for (int m = 0; m < 4; ++m) {
        // ---- stage A-tile (hi/lo split), padded linear layout
        if (m == 0) {
            #pragma unroll
            for (int s2 = 0; s2 < 2; ++s2) {
                int c16 = s2 * 512 + tid;
                int rr = c16 >> 4, k0 = (c16 & 15) * 8;
                int grr = row0 + rr;
                float v[8] = {0.f,0.f,0.f,0.f,0.f,0.f,0.f,0.f};
                if (grr < NN) {
                    float4 va = *(const float4*)&h[(size_t)grr * 128 + k0];
                    float4 vb = *(const float4*)&h[(size_t)grr * 128 + k0 + 4];
                    v[0]=va.x; v[1]=va.y; v[2]=va.z; v[3]=va.w;
                    v[4]=vb.x; v[5]=vb.y; v[6]=vb.z; v[7]=vb.w;
                }
                unsigned short hs[8], ls[8];
                #pragma unroll
                for (int j = 0; j < 8; ++j) split_bf(v[j], hs[j], ls[j]);
                uint4 hv, lv;
                hv.x = (unsigned)hs[0] | ((unsigned)hs[1] << 16);
                hv.y = (unsigned)hs[2] | ((unsigned)hs[3] << 16);
                hv.z = (unsigned)hs[4] | ((unsigned)hs[5] << 16);
                hv.w = (unsigned)hs[6] | ((unsigned)hs[7] << 16);
                lv.x = (unsigned)ls[0] | ((unsigned)ls[1] << 16);
                lv.y = (unsigned)ls[2] | ((unsigned)ls[3] << 16);
                lv.z = (unsigned)ls[4] | ((unsigned)ls[5] << 16);
                lv.w = (unsigned)ls[6] | ((unsigned)ls[7] << 16);
                *(uint4*)&Ahi[rr * ALD + k0] = hv;
                *(uint4*)&Alo[rr * ALD + k0] = lv;
            }
        } else {
            int t = m - 1;   // static under #pragma unroll
            float inv = invc[t];
            unsigned short hs[16], ls[16];
            #pragma unroll
            for (int j = 0; j < 16; ++j) split_bf(ms[t][j] * inv, hs[j], ls[j]);
            uint4 hv0, hv1, lv0, lv1;
            hv0.x = (unsigned)hs[0]  | ((unsigned)hs[1]  << 16);
            hv0.y = (unsigned)hs[2]  | ((unsigned)hs[3]  << 16);
            hv0.z = (unsigned)hs[4]  | ((unsigned)hs[5]  << 16);
            hv0.w = (unsigned)hs[6]  | ((unsigned)hs[7]  << 16);
            hv1.x = (unsigned)hs[8]  | ((unsigned)hs[9]  << 16);
            hv1.y = (unsigned)hs[10] | ((unsigned)hs[11] << 16);
            hv1.z = (unsigned)hs[12] | ((unsigned)hs[13] << 16);
            hv1.w = (unsigned)hs[14] | ((unsigned)hs[15] << 16);
            lv0.x = (unsigned)ls[0]  | ((unsigned)ls[1]  << 16);
            lv0.y = (unsigned)ls[2]  | ((unsigned)ls[3]  << 16);
            lv0.z = (unsigned)ls[4]  | ((unsigned)ls[5]  << 16);
            lv0.w = (unsigned)ls[6]  | ((unsigned)ls[7]  << 16);
            lv1.x = (unsigned)ls[8]  | ((unsigned)ls[9]  << 16);
            lv1.y = (unsigned)ls[10] | ((unsigned)ls[11] << 16);
            lv1.z = (unsigned)ls[12] | ((unsigned)ls[13] << 16);
            lv1.w = (unsigned)ls[14] | ((unsigned)ls[15] << 16);
            *(uint4*)&Ahi[r * ALD + sub * 16]     = hv0;
            *(uint4*)&Ahi[r * ALD + sub * 16 + 8] = hv1;
            *(uint4*)&Alo[r * ALD + sub * 16]     = lv0;
            *(uint4*)&Alo[r * ALD + sub * 16 + 8] = lv1;
        }
        // ---- stage W hi plane (linear)
        const unsigned short* Whi = Wt_l + ((size_t)m << 15);
        #pragma unroll
        for (int s2 = 0; s2 < 4; ++s2) {
            int c16 = s2 * 512 + tid;
            int col = c16 >> 4, k0 = (c16 & 15) * 8;
            *(uint4*)&Wl[col * ALD + k0] = *(const uint4*)&Whi[col * 128 + k0];
        }
        __syncthreads();
        // ---- hi pass: (a_hi + a_lo) * w_hi
        #pragma unroll
        for (int ks = 0; ks < 4; ++ks) {
            int k0 = ks * 32 + koff;
            bf16x8 ah = *(const bf16x8*)&Ahi[(R0 + l15) * ALD + k0];
            bf16x8 al = *(const bf16x8*)&Alo[(R0 + l15) * ALD + k0];
            #pragma unroll
            for (int n = 0; n < 4; ++n) {
                bf16x8 b = *(const bf16x8*)&Wl[(C0 + n * 16 + l15) * ALD + k0];
                acc[n] = __builtin_amdgcn_mfma_f32_16x16x32_bf16(ah, b, acc[n], 0, 0, 0);
                acc[n] = __builtin_amdgcn_mfma_f32_16x16x32_bf16(al, b, acc[n], 0, 0, 0);
            }
        }
        __syncthreads();
        // ---- stage W lo plane
        const unsigned short* Wlo = Whi + 16384;
        #pragma unroll
        for (int s2 = 0; s2 < 4; ++s2) {
            int c16 = s2 * 512 + tid;
            int col = c16 >> 4, k0 = (c16 & 15) * 8;
            *(uint4*)&Wl[col * ALD + k0] = *(const uint4*)&Wlo[col * 128 + k0];
        }
        __syncthreads();
        // ---- lo pass: (a_hi + a_lo) * w_lo
        #pragma unroll
        for (int ks = 0; ks < 4; ++ks) {
            int k0 = ks * 32 + koff;
            bf16x8 ah = *(const bf16x8*)&Ahi[(R0 + l15) * ALD + k0];
            bf16x8 al = *(const bf16x8*)&Alo[(R0 + l15) * ALD + k0];
            #pragma unroll
            for (int n = 0; n < 4; ++n) {
                bf16x8 b = *(const bf16x8*)&Wl[(C0 + n * 16 + l15) * ALD + k0];
                acc[n] = __builtin_amdgcn_mfma_f32_16x16x32_bf16(ah, b, acc[n], 0, 0, 0);
                acc[n] = __builtin_amdgcn_mfma_f32_16x16x32_bf16(al, b, acc[n], 0, 0, 0);
            }
        }
        __syncthreads();   // before next m overwrites LDS
    }

    // ---- bias + raw global store (m89 C/D layout: col=lane&15, row=(lane>>4)*4+reg)
    #pragma unroll
    for (int n = 0; n < 4; ++n) {
        int cc = C0 + n * 16 + l15;
        float bv = blsum_l[cc];
        #pragma unroll
        for (int i = 0; i < 4; ++i) {
            int grr = row0 + R0 + (l >> 4) * 4 + i;
            if (grr < NN) ob[(size_t)grr * HH + cc] = acc[n][i] + bv;
        }
    }
}

// ================================================================ layernorm (validated R1, in-place safe)
__global__ void layernorm_kernel(const float* __restrict__ in, const float* __restrict__ gamma,
                                 const float* __restrict__ beta, float* __restrict__ out, int rows) {
    int lane = threadIdx.x & 63;
    int row = blockIdx.x * 4 + (threadIdx.x >> 6);
    if (row >= rows) return;
    float2 v = *reinterpret_cast<const float2*>(&in[(size_t)row * HH + lane * 2]);
    float s = v.x + v.y, sq = v.x * v.x + v.y * v.y;
    #pragma unroll
    for (int o = 32; o; o >>= 1) { s += __shfl_xor(s, o); sq += __shfl_xor(sq, o); }
    float mu = s * (1.0f / HH);
    float var = sq * (1.0f / HH) - mu * mu;
    float r = rsqrtf(var + 1e-5f);
    float2 gj = *reinterpret_cast<const float2*>(&gamma[lane * 2]);
    float2 bj = *reinterpret_cast<const float2*>(&beta[lane * 2]);
    float2 o2;
    o2.x = (v.x - mu) * r * gj.x + bj.x;
    o2.y = (v.y - mu) * r * gj.y + bj.y;
    *reinterpret_cast<float2*>(&out[(size_t)row * HH + lane * 2]) = o2;
}

// ================================================================ two-stage pooling (validated R6)
__global__ void pool1_kernel(const float* __restrict__ h, const int* __restrict__ batch,
                             float* __restrict__ psum, float* __restrict__ pmax) {
    int g = blockIdx.x >> 4, c = blockIdx.x & (NC - 1);
    int start, end;
    {
        int lo = 0, hi = NN;
        while (lo < hi) { int mid = (lo + hi) >> 1; if (batch[mid] < g) lo = mid + 1; else hi = mid; }
        start = lo;
        hi = NN;
        while (lo < hi) { int mid = (lo + hi) >> 1; if (batch[mid] < g + 1) lo = mid + 1; else hi = mid; }
        end = lo;
    }
    int len = end - start;
    int chunk = (len + NC - 1) / NC;
    int clo = start + c * chunk;
    int chi = min(clo + chunk, end);
    int tid = threadIdx.x;
    int d = tid & 127, half = tid >> 7;
    float s = 0.f, m = -INFINITY;
    for (int n = clo + half; n < chi; n += 2) {
        float v = h[(size_t)n * HH + d];
        s += v; m = fmaxf(m, v);
    }
    __shared__ float ss[256], sm[256];
    ss[tid] = s; sm[tid] = m;
    __syncthreads();
    if (half == 0) {
        s += ss[tid + 128];
        m = fmaxf(m, sm[tid + 128]);
        psum[(size_t)blockIdx.x * HH + d] = s;
        pmax[(size_t)blockIdx.x * HH + d] = m;
    }
}

__global__ void pool2_kernel(const float* __restrict__ psum, const float* __restrict__ pmax,
                             const int* __restrict__ batch, float* __restrict__ out) {
    int g = blockIdx.x;
    int d = threadIdx.x;   // 128 threads
    int start, end;
    {
        int lo = 0, hi = NN;
        while (lo < hi) { int mid = (lo + hi) >> 1; if (batch[mid] < g) lo = mid + 1; else hi = mid; }
        start = lo;
        hi = NN;
        while (lo < hi) { int mid = (lo + hi) >> 1; if (batch[mid] < g + 1) lo = mid + 1; else hi = mid; }
        end = lo;
    }
    float s = 0.f, m = -INFINITY;
    #pragma unroll
    for (int c = 0; c < NC; ++c) {
        s += psum[(size_t)(g * NC + c) * HH + d];
        m = fmaxf(m, pmax[(size_t)(g * NC + c) * HH + d]);
    }
    int cg = end - start;
    out[g * 2 * HH + d] = s / fmaxf((float)cg, 1.0f);
    out[g * 2 * HH + HH + d] = (cg > 0) ? m : 0.0f;
}

// ================================================================ launch
extern "C" void kernel_launch(void* const* d_in, const int* in_sizes, int n_in,
                              void* d_out, int out_size, void* d_ws, size_t ws_size,
                              hipStream_t stream) {
    const float* x     = (const float*)d_in[0];
    const int*   ast   = (const int*)d_in[1];
    const int*   batch = (const int*)d_in[2];
    const int*   ei    = (const int*)d_in[3];
    const float* emb   = (const float*)d_in[4];
    const float* W_in  = (const float*)d_in[5];
    const float* b_in  = (const float*)d_in[6];
    const float* W_l   = (const float*)d_in[7];
    const float* b_l   = (const float*)d_in[8];
    const float* W_r   = (const float*)d_in[9];
    const float* gamma = (const float*)d_in[10];
    const float* beta  = (const float*)d_in[11];
    float* out = (float*)d_out;

    const int M  = TT * NN;
    const int NB = (M + 1023) / 1024;

    char* p = (char*)d_ws;
    float* h32 = (float*)p;                    p += (size_t)NN * HH * 4;   // 51.2 MB
    float* ob  = (float*)p;                    p += (size_t)NN * HH * 4;   // 51.2 MB
    unsigned short* Wt16 = (unsigned short*)p; p += (size_t)LL * 4 * 2 * HH * HH * 2;
    float* blsum = (float*)p;                  p += LL * HH * 4;
    float* psum = (float*)p;                   p += (size_t)BB * NC * HH * 4;
    float* pmax = (float*)p;                   p += (size_t)BB * NC * HH * 4;
    int* cnt    = (int*)p;                     p += (size_t)M * 4;
    int* offs   = (int*)p;                     p += (size_t)M * 4;
    int* cursor = (int*)p;                     p += (size_t)M * 4;
    int* csr    = (int*)p;                     p += (size_t)TT * EE * 4;
    int* bsums  = (int*)p;

    hipMemsetAsync(cnt, 0, (size_t)M * sizeof(int), stream);
    count_kernel<<<(TT * EE + 255) / 256, 256, 0, stream>>>(ei, cnt);
    scan1_kernel<<<NB, 256, 0, stream>>>(cnt, offs, bsums, M);
    scan2_kernel<<<1, 512, 0, stream>>>(bsums, NB);
    scan3_kernel<<<(M + 255) / 256, 256, 0, stream>>>(offs, bsums, cursor, M);
    fill_kernel<<<(TT * EE + 255) / 256, 256, 0, stream>>>(ei, cursor, csr);
    wprep_kernel<<<(LL * 4 * HH * HH + 255) / 256, 256, 0, stream>>>(W_l, W_r, b_l, Wt16, blsum);
    input_proj_kernel<<<512, 512, 0, stream>>>(x, ast, emb, W_in, b_in, h32);

    int conv_grid = (NN + 63) / 64;
    int ln_grid = (NN + 3) / 4;
    // layer 0: h32 -> ob, LN in-place on ob
    conv_kernel<<<conv_grid, 512, 0, stream>>>(h32, Wt16, blsum, offs, cnt, csr, ob);
    layernorm_kernel<<<ln_grid, 256, 0, stream>>>(ob, gamma, beta, ob, NN);
    // layer 1: ob -> h32, LN in-place on h32
    conv_kernel<<<conv_grid, 512, 0, stream>>>(ob, Wt16 + (size_t)4 * 2 * HH * HH,
                                               blsum + HH, offs, cnt, csr, h32);
    layernorm_kernel<<<ln_grid, 256, 0, stream>>>(h32, gamma + HH, beta + HH, h32, NN);
    // two-stage pooling
    pool1_kernel<<<BB * NC, 256, 0, stream>>>(h32, batch, psum, pmax);
    pool2_kernel<<<BB, HH, 0, stream>>>(psum, pmax, batch, out);
}

// Round 8
// 491.503 us; speedup vs baseline: 8.9767x; 1.0249x over previous
//
#include <hip/hip_runtime.h>
#include <hip/hip_bf16.h>
#include <math.h>

#define NN 100000   // nodes
#define EE 300000   // edges per type
#define TT 3        // edge types
#define LL 2        // layers
#define HH 128      // hidden
#define FF 5        // node feat
#define TE 64       // type embed
#define NT 200      // num ast types
#define BB 64       // graphs
#define NC 16       // pooling chunks per graph
#define CSRCAP 512  // per-type per-block LDS index cap (mean ~192)
#define WLSZ 131072 // per-layer fragment-packed weight size (shorts)

typedef short bf16x8 __attribute__((ext_vector_type(8)));
typedef float f32x4  __attribute__((ext_vector_type(4)));

__device__ __forceinline__ float bf2f(unsigned short u) {
    union { unsigned i; float f; } v; v.i = ((unsigned)u) << 16; return v.f;
}
__device__ __forceinline__ unsigned short f2bf(float f) {
    union { float f; unsigned i; } v; v.f = f;
    unsigned b = v.i + (0x7FFFu + ((v.i >> 16) & 1u));   // RNE
    return (unsigned short)(b >> 16);
}
// split x ~= hi + lo (two bf16); hi+lo reproduces x to ~2^-16 rel
__device__ __forceinline__ void split_bf(float x, unsigned short& hi, unsigned short& lo) {
    hi = f2bf(x);
    lo = f2bf(x - bf2f(hi));
}

// ================================================================ CSR build (validated R2)
__global__ void count_kernel(const int* __restrict__ ei, int* __restrict__ cnt) {
    int i = blockIdx.x * blockDim.x + threadIdx.x;
    if (i >= TT * EE) return;
    int t = i / EE, e = i - t * EE;
    int dst = ei[(t * 2 + 1) * EE + e];
    atomicAdd(&cnt[t * NN + dst], 1);
}

__global__ __launch_bounds__(256) void scan1_kernel(const int* __restrict__ cnt,
                                                    int* __restrict__ offs,
                                                    int* __restrict__ bsums, int M) {
    int tid = threadIdx.x;
    int base = blockIdx.x * 1024 + tid * 4;
    int a0 = 0, a1 = 0, a2 = 0, a3 = 0;
    if (base + 3 < M) { int4 v = *(const int4*)&cnt[base]; a0 = v.x; a1 = v.y; a2 = v.z; a3 = v.w; }
    else {
        if (base + 0 < M) a0 = cnt[base + 0];
        if (base + 1 < M) a1 = cnt[base + 1];
        if (base + 2 < M) a2 = cnt[base + 2];
        if (base + 3 < M) a3 = cnt[base + 3];
    }
    int s = a0 + a1 + a2 + a3;
    int lane = tid & 63, wv = tid >> 6;
    int x = s;
    #pragma unroll
    for (int o = 1; o < 64; o <<= 1) { int y = __shfl_up(x, o); if (lane >= o) x += y; }
    __shared__ int wsum[4];
    if (lane == 63) wsum[wv] = x;
    __syncthreads();
    int add = 0;
    for (int w = 0; w < wv; ++w) add += wsum[w];
    int incl = x + add;
    int e0 = incl - s, e1 = e0 + a0, e2 = e1 + a1, e3 = e2 + a2;
    if (base + 0 < M) offs[base + 0] = e0;
    if (base + 1 < M) offs[base + 1] = e1;
    if (base + 2 < M) offs[base + 2] = e2;
    if (base + 3 < M) offs[base + 3] = e3;
    if (tid == 255) bsums[blockIdx.x] = incl;
}

__global__ __launch_bounds__(512) void scan2_kernel(int* __restrict__ bsums, int NB) {
    int tid = threadIdx.x;
    int s = (tid < NB) ? bsums[tid] : 0;
    int lane = tid & 63, wv = tid >> 6;
    int x = s;
    #pragma unroll
    for (int o = 1; o < 64; o <<= 1) { int y = __shfl_up(x, o); if (lane >= o) x += y; }
    __shared__ int wsum[8];
    if (lane == 63) wsum[wv] = x;
    __syncthreads();
    int add = 0;
    for (int w = 0; w < wv; ++w) add += wsum[w];
    if (tid < NB) bsums[tid] = x + add - s;
}

__global__ void scan3_kernel(int* __restrict__ offs, const int* __restrict__ bsums,
                             int* __restrict__ cursor, int M) {
    int i = blockIdx.x * 256 + threadIdx.x;
    if (i >= M) return;
    int v = offs[i] + bsums[i >> 10];
    offs[i] = v;
    cursor[i] = v;
}

__global__ void fill_kernel(const int* __restrict__ ei, int* __restrict__ cursor,
                            int* __restrict__ csr) {
    int i = blockIdx.x * blockDim.x + threadIdx.x;
    if (i >= TT * EE) return;
    int t = i / EE, e = i - t * EE;
    int src = ei[(t * 2 + 0) * EE + e];
    int dst = ei[(t * 2 + 1) * EE + e];
    int pos = atomicAdd(&cursor[t * NN + dst], 1);
    csr[pos] = src;
}

// ================================================================ weight prep (fragment-major pack)
// Wt16[l] layout: idx = P*4096 + cg*512 + lane*8 + j, P = (m*2+plane)*4 + ks.
// col = cg*16 + (lane&15), k = ks*32 + (lane>>4)*8 + j; value = W^T[col][k] split hi/lo.
__global__ void wprep_kernel(const float* __restrict__ W_l, const float* __restrict__ W_r,
                             const float* __restrict__ b_l,
                             unsigned short* __restrict__ Wt16, float* __restrict__ blsum) {
    int i = blockIdx.x * 256 + threadIdx.x;
    if (i < LL * 4 * HH * HH) {
        int lm = i >> 14;          // l*4 + m
        int ck = i & 16383;
        int col = ck >> 7, k = ck & 127;
        int l = lm >> 2, m = lm & 3;
        float v;
        if (m == 0) {
            v = 0.f;
            for (int t = 0; t < TT; ++t)
                v += W_r[(((size_t)(l * TT + t)) << 14) + k * HH + col];
        } else {
            v = W_l[(((size_t)(l * TT + (m - 1))) << 14) + k * HH + col];
        }
        unsigned short hi, lo;
        split_bf(v, hi, lo);
        int cg = col >> 4, l15 = col & 15;
        int ks = k >> 5, lh = (k >> 3) & 3, j = k & 7;
        int lane = lh * 16 + l15;
        size_t base = (size_t)l * WLSZ;
        int Phi = (m * 2 + 0) * 4 + ks;
        int Plo = Phi + 4;
        Wt16[base + (size_t)Phi * 4096 + cg * 512 + lane * 8 + j] = hi;
        Wt16[base + (size_t)Plo * 4096 + cg * 512 + lane * 8 + j] = lo;
    }
    if (i < LL * HH) {
        int l = i >> 7, j = i & 127;
        float s = 0.f;
        for (int t = 0; t < TT; ++t) s += b_l[(l * TT + t) * HH + j];
        blsum[i] = s;
    }
}

// ================================================================ input projection (validated R2, verbatim)
__global__ __launch_bounds__(512) void input_proj_kernel(
    const float* __restrict__ x, const int* __restrict__ ast,
    const float* __restrict__ emb, const float* __restrict__ W_in,
    const float* __restrict__ b_in, float* __restrict__ h)
{
    __shared__ float Ws[(TE + FF) * HH];   // 35.3 KB
    __shared__ float Es[NT * TE];          // 51.2 KB
    int tid = threadIdx.x;
    for (int i = tid; i < (TE + FF) * HH; i += 512) Ws[i] = W_in[i];
    for (int i = tid; i < NT * TE; i += 512) Es[i] = emb[i];
    __syncthreads();
    int col = tid & 127, nl = tid >> 7;    // 4 nodes per block-iteration
    float bj = b_in[col];
    for (int n = blockIdx.x * 4 + nl; n < NN; n += gridDim.x * 4) {
        int a = ast[n];
        float acc = bj;
        const float* ep = &Es[a * TE];
        #pragma unroll
        for (int k = 0; k < TE; ++k) acc = fmaf(ep[k], Ws[k * HH + col], acc);
        #pragma unroll
        for (int k = 0; k < FF; ++k) acc = fmaf(x[n * FF + k], Ws[(TE + k) * HH + col], acc);
        h[(size_t)n * HH + col] = acc;
    }
}

// ================================================================ conv layer (split-bf16 MFMA, W direct-to-VGPR)
// R8: W fragments load straight from L2-hot packed global -> no W LDS staging,
// 2 barriers per m instead of 4. Wave = 64 rows x 16 cols (8 col-groups, no
// cross-wave W duplication). A-path/gather/CSR verbatim from validated R7.
#define ALD 136   // padded LDS stride (shorts): 272 B -> 2-way bank aliasing (free)

__global__ __launch_bounds__(512) void conv_kernel(
    const float* __restrict__ h,                 // [N][128] f32
    const unsigned short* __restrict__ Wt_l,     // fragment-packed, per-layer base
    const float* __restrict__ blsum_l,
    const int* __restrict__ offs, const int* __restrict__ cnt, const int* __restrict__ csr,
    float* __restrict__ ob)
{
    __shared__ unsigned short Ahi[64 * ALD];     // 17.4 KB
    __shared__ unsigned short Alo[64 * ALD];     // 17.4 KB
    __shared__ int csr_lds[TT][CSRCAP];          // 6 KB
    __shared__ int base_lds[TT], len_lds[TT], flag_lds[TT];

    int tid = threadIdx.x;
    int row0 = blockIdx.x * 64;
    int nrow = min(64, NN - row0);
    int w = tid >> 6, l = tid & 63;
    int l15 = l & 15, koff = (l >> 4) * 8;

    // ---- stage CSR ranges (rows consecutive -> contiguous csr slice per type)
    if (tid < TT) {
        int t = tid;
        int last = row0 + nrow - 1;
        int b = offs[t * NN + row0];
        int e = offs[t * NN + last] + cnt[t * NN + last];
        base_lds[t] = b;
        len_lds[t] = e - b;
        flag_lds[t] = (e - b) <= CSRCAP;
    }
    __syncthreads();
    #pragma unroll
    for (int t = 0; t < TT; ++t) {
        if (flag_lds[t]) {
            int b = base_lds[t], len = len_lds[t];
            for (int i = tid; i < len; i += 512) csr_lds[t][i] = csr[b + i];
        }
    }
    __syncthreads();

    // ---- gather all 3 types into registers (one latency exposure)
    int r = tid >> 3, sub = tid & 7;
    int gr = row0 + r;
    float ms[TT][16];
    float invc[TT];
    #pragma unroll
    for (int t = 0; t < TT; ++t) {
        invc[t] = 0.f;
        #pragma unroll
        for (int j = 0; j < 16; ++j) ms[t][j] = 0.f;
    }
    if (gr < NN) {
        #pragma unroll
        for (int t = 0; t < TT; ++t) {
            int o = offs[t * NN + gr];
            int c = cnt[t * NN + gr];
            invc[t] = (c > 0) ? 1.0f / (float)c : 0.0f;
            bool inl = flag_lds[t] != 0;
            int rel = o - base_lds[t];
            for (int j = 0; j < c; ++j) {
                int src = inl ? csr_lds[t][rel + j] : csr[o + j];
                const float4* hp = (const float4*)&h[(size_t)src * 128 + sub * 16];
                float4 v0 = hp[0], v1 = hp[1], v2 = hp[2], v3 = hp[3];
                ms[t][0]  += v0.x; ms[t][1]  += v0.y; ms[t][2]  += v0.z; ms[t][3]  += v0.w;
                ms[t][4]  += v1.x; ms[t][5]  += v1.y; ms[t][6]  += v1.z; ms[t][7]  += v1.w;
                ms[t][8]  += v2.x; ms[t][9]  += v2.y; ms[t][10] += v2.z; ms[t][11] += v2.w;
                ms[t][12] += v3.x; ms[t][13] += v3.y; ms[t][14] += v3.z; ms[t][15] += v3.w;
            }
        }
    }

    f32x4 acc[4] = {};

    #pragma unroll
    for (int m = 0; m < 4; ++m) {
        // ---- stage A-tile (hi/lo split), padded linear layout (R7 verbatim)
        if (m == 0) {
            #pragma unroll
            for (int s2 = 0; s2 < 2; ++s2) {
                int c16 = s2 * 512 + tid;
                int rr = c16 >> 4, k0 = (c16 & 15) * 8;
                int grr = row0 + rr;
                float v[8] = {0.f,0.f,0.f,0.f,0.f,0.f,0.f,0.f};
                if (grr < NN) {
                    float4 va = *(const float4*)&h[(size_t)grr * 128 + k0];
                    float4 vb = *(const float4*)&h[(size_t)grr * 128 + k0 + 4];
                    v[0]=va.x; v[1]=va.y; v[2]=va.z; v[3]=va.w;
                    v[4]=vb.x; v[5]=vb.y; v[6]=vb.z; v[7]=vb.w;
                }
                unsigned short hs[8], ls[8];
                #pragma unroll
                for (int j = 0; j < 8; ++j) split_bf(v[j], hs[j], ls[j]);
                uint4 hv, lv;
                hv.x = (unsigned)hs[0] | ((unsigned)hs[1] << 16);
                hv.y = (unsigned)hs[2] | ((unsigned)hs[3] << 16);
                hv.z = (unsigned)hs[4] | ((unsigned)hs[5] << 16);
                hv.w = (unsigned)hs[6] | ((unsigned)hs[7] << 16);
                lv.x = (unsigned)ls[0] | ((unsigned)ls[1] << 16);
                lv.y = (unsigned)ls[2] | ((unsigned)ls[3] << 16);
                lv.z = (unsigned)ls[4] | ((unsigned)ls[5] << 16);
                lv.w = (unsigned)ls[6] | ((unsigned)ls[7] << 16);
                *(uint4*)&Ahi[rr * ALD + k0] = hv;
                *(uint4*)&Alo[rr * ALD + k0] = lv;
            }
        } else {
            int t = m - 1;   // static under #pragma unroll
            float inv = invc[t];
            unsigned short hs[16], ls[16];
            #pragma unroll
            for (int j = 0; j < 16; ++j) split_bf(ms[t][j] * inv, hs[j], ls[j]);
            uint4 hv0, hv1, lv0, lv1;
            hv0.x = (unsigned)hs[0]  | ((unsigned)hs[1]  << 16);
            hv0.y = (unsigned)hs[2]  | ((unsigned)hs[3]  << 16);
            hv0.z = (unsigned)hs[4]  | ((unsigned)hs[5]  << 16);
            hv0.w = (unsigned)hs[6]  | ((unsigned)hs[7]  << 16);
            hv1.x = (unsigned)hs[8]  | ((unsigned)hs[9]  << 16);
            hv1.y = (unsigned)hs[10] | ((unsigned)hs[11] << 16);
            hv1.z = (unsigned)hs[12] | ((unsigned)hs[13] << 16);
            hv1.w = (unsigned)hs[14] | ((unsigned)hs[15] << 16);
            lv0.x = (unsigned)ls[0]  | ((unsigned)ls[1]  << 16);
            lv0.y = (unsigned)ls[2]  | ((unsigned)ls[3]  << 16);
            lv0.z = (unsigned)ls[4]  | ((unsigned)ls[5]  << 16);
            lv0.w = (unsigned)ls[6]  | ((unsigned)ls[7]  << 16);
            lv1.x = (unsigned)ls[8]  | ((unsigned)ls[9]  << 16);
            lv1.y = (unsigned)ls[10] | ((unsigned)ls[11] << 16);
            lv1.z = (unsigned)ls[12] | ((unsigned)ls[13] << 16);
            lv1.w = (unsigned)ls[14] | ((unsigned)ls[15] << 16);
            *(uint4*)&Ahi[r * ALD + sub * 16]     = hv0;
            *(uint4*)&Ahi[r * ALD + sub * 16 + 8] = hv1;
            *(uint4*)&Alo[r * ALD + sub * 16]     = lv0;
            *(uint4*)&Alo[r * ALD + sub * 16 + 8] = lv1;
        }
        __syncthreads();
        // ---- MFMA: W fragments direct from global (coalesced 16B/lane, L2-hot)
        #pragma unroll
        for (int ks = 0; ks < 4; ++ks) {
            bf16x8 wh = *(const bf16x8*)&Wt_l[(size_t)(8 * m + ks) * 4096 + w * 512 + l * 8];
            bf16x8 wl = *(const bf16x8*)&Wt_l[(size_t)(8 * m + 4 + ks) * 4096 + w * 512 + l * 8];
            int k0 = ks * 32 + koff;
            #pragma unroll
            for (int rt = 0; rt < 4; ++rt) {
                bf16x8 ah = *(const bf16x8*)&Ahi[(rt * 16 + l15) * ALD + k0];
                bf16x8 al = *(const bf16x8*)&Alo[(rt * 16 + l15) * ALD + k0];
                acc[rt] = __builtin_amdgcn_mfma_f32_16x16x32_bf16(ah, wh, acc[rt], 0, 0, 0);
                acc[rt] = __builtin_amdgcn_mfma_f32_16x16x32_bf16(al, wh, acc[rt], 0, 0, 0);
                acc[rt] = __builtin_amdgcn_mfma_f32_16x16x32_bf16(ah, wl, acc[rt], 0, 0, 0);
            }
        }
        __syncthreads();   // before next m overwrites A
    }

    // ---- bias + raw global store (m89 C/D layout: col=lane&15, row=(lane>>4)*4+reg)
    {
        int col = w * 16 + l15;
        float bv = blsum_l[col];
        int rbase = row0 + (l >> 4) * 4;
        #pragma unroll
        for (int rt = 0; rt < 4; ++rt) {
            #pragma unroll
            for (int i = 0; i < 4; ++i) {
                int grr = rbase + rt * 16 + i;
                if (grr < NN) ob[(size_t)grr * HH + col] = acc[rt][i] + bv;
            }
        }
    }
}

// ================================================================ layernorm (validated R1, in-place safe)
__global__ void layernorm_kernel(const float* __restrict__ in, const float* __restrict__ gamma,
                                 const float* __restrict__ beta, float* __restrict__ out, int rows) {
    int lane = threadIdx.x & 63;
    int row = blockIdx.x * 4 + (threadIdx.x >> 6);
    if (row >= rows) return;
    float2 v = *reinterpret_cast<const float2*>(&in[(size_t)row * HH + lane * 2]);
    float s = v.x + v.y, sq = v.x * v.x + v.y * v.y;
    #pragma unroll
    for (int o = 32; o; o >>= 1) { s += __shfl_xor(s, o); sq += __shfl_xor(sq, o); }
    float mu = s * (1.0f / HH);
    float var = sq * (1.0f / HH) - mu * mu;
    float r = rsqrtf(var + 1e-5f);
    float2 gj = *reinterpret_cast<const float2*>(&gamma[lane * 2]);
    float2 bj = *reinterpret_cast<const float2*>(&beta[lane * 2]);
    float2 o2;
    o2.x = (v.x - mu) * r * gj.x + bj.x;
    o2.y = (v.y - mu) * r * gj.y + bj.y;
    *reinterpret_cast<float2*>(&out[(size_t)row * HH + lane * 2]) = o2;
}

// ================================================================ two-stage pooling (validated R6)
__global__ void pool1_kernel(const float* __restrict__ h, const int* __restrict__ batch,
                             float* __restrict__ psum, float* __restrict__ pmax) {
    int g = blockIdx.x >> 4, c = blockIdx.x & (NC - 1);
    int start, end;
    {
        int lo = 0, hi = NN;
        while (lo < hi) { int mid = (lo + hi) >> 1; if (batch[mid] < g) lo = mid + 1; else hi = mid; }
        start = lo;
        hi = NN;
        while (lo < hi) { int mid = (lo + hi) >> 1; if (batch[mid] < g + 1) lo = mid + 1; else hi = mid; }
        end = lo;
    }
    int len = end - start;
    int chunk = (len + NC - 1) / NC;
    int clo = start + c * chunk;
    int chi = min(clo + chunk, end);
    int tid = threadIdx.x;
    int d = tid & 127, half = tid >> 7;
    float s = 0.f, m = -INFINITY;
    for (int n = clo + half; n < chi; n += 2) {
        float v = h[(size_t)n * HH + d];
        s += v; m = fmaxf(m, v);
    }
    __shared__ float ss[256], sm[256];
    ss[tid] = s; sm[tid] = m;
    __syncthreads();
    if (half == 0) {
        s += ss[tid + 128];
        m = fmaxf(m, sm[tid + 128]);
        psum[(size_t)blockIdx.x * HH + d] = s;
        pmax[(size_t)blockIdx.x * HH + d] = m;
    }
}

__global__ void pool2_kernel(const float* __restrict__ psum, const float* __restrict__ pmax,
                             const int* __restrict__ batch, float* __restrict__ out) {
    int g = blockIdx.x;
    int d = threadIdx.x;   // 128 threads
    int start, end;
    {
        int lo = 0, hi = NN;
        while (lo < hi) { int mid = (lo + hi) >> 1; if (batch[mid] < g) lo = mid + 1; else hi = mid; }
        start = lo;
        hi = NN;
        while (lo < hi) { int mid = (lo + hi) >> 1; if (batch[mid] < g + 1) lo = mid + 1; else hi = mid; }
        end = lo;
    }
    float s = 0.f, m = -INFINITY;
    #pragma unroll
    for (int c = 0; c < NC; ++c) {
        s += psum[(size_t)(g * NC + c) * HH + d];
        m = fmaxf(m, pmax[(size_t)(g * NC + c) * HH + d]);
    }
    int cg = end - start;
    out[g * 2 * HH + d] = s / fmaxf((float)cg, 1.0f);
    out[g * 2 * HH + HH + d] = (cg > 0) ? m : 0.0f;
}

// ================================================================ launch
extern "C" void kernel_launch(void* const* d_in, const int* in_sizes, int n_in,
                              void* d_out, int out_size, void* d_ws, size_t ws_size,
                              hipStream_t stream) {
    const float* x     = (const float*)d_in[0];
    const int*   ast   = (const int*)d_in[1];
    const int*   batch = (const int*)d_in[2];
    const int*   ei    = (const int*)d_in[3];
    const float* emb   = (const float*)d_in[4];
    const float* W_in  = (const float*)d_in[5];
    const float* b_in  = (const float*)d_in[6];
    const float* W_l   = (const float*)d_in[7];
    const float* b_l   = (const float*)d_in[8];
    const float* W_r   = (const float*)d_in[9];
    const float* gamma = (const float*)d_in[10];
    const float* beta  = (const float*)d_in[11];
    float* out = (float*)d_out;

    const int M  = TT * NN;
    const int NB = (M + 1023) / 1024;

    char* p = (char*)d_ws;
    float* h32 = (float*)p;                    p += (size_t)NN * HH * 4;   // 51.2 MB
    float* ob  = (float*)p;                    p += (size_t)NN * HH * 4;   // 51.2 MB
    unsigned short* Wt16 = (unsigned short*)p; p += (size_t)LL * WLSZ * 2;
    float* blsum = (float*)p;                  p += LL * HH * 4;
    float* psum = (float*)p;                   p += (size_t)BB * NC * HH * 4;
    float* pmax = (float*)p;                   p += (size_t)BB * NC * HH * 4;
    int* cnt    = (int*)p;                     p += (size_t)M * 4;
    int* offs   = (int*)p;                     p += (size_t)M * 4;
    int* cursor = (int*)p;                     p += (size_t)M * 4;
    int* csr    = (int*)p;                     p += (size_t)TT * EE * 4;
    int* bsums  = (int*)p;

    hipMemsetAsync(cnt, 0, (size_t)M * sizeof(int), stream);
    count_kernel<<<(TT * EE + 255) / 256, 256, 0, stream>>>(ei, cnt);
    scan1_kernel<<<NB, 256, 0, stream>>>(cnt, offs, bsums, M);
    scan2_kernel<<<1, 512, 0, stream>>>(bsums, NB);
    scan3_kernel<<<(M + 255) / 256, 256, 0, stream>>>(offs, bsums, cursor, M);
    fill_kernel<<<(TT * EE + 255) / 256, 256, 0, stream>>>(ei, cursor, csr);
    wprep_kernel<<<(LL * 4 * HH * HH + 255) / 256, 256, 0, stream>>>(W_l, W_r, b_l, Wt16, blsum);
    input_proj_kernel<<<512, 512, 0, stream>>>(x, ast, emb, W_in, b_in, h32);

    int conv_grid = (NN + 63) / 64;
    int ln_grid = (NN + 3) / 4;
    // layer 0: h32 -> ob, LN in-place on ob
    conv_kernel<<<conv_grid, 512, 0, stream>>>(h32, Wt16, blsum, offs, cnt, csr, ob);
    layernorm_kernel<<<ln_grid, 256, 0, stream>>>(ob, gamma, beta, ob, NN);
    // layer 1: ob -> h32, LN in-place on h32
    conv_kernel<<<conv_grid, 512, 0, stream>>>(ob, Wt16 + (size_t)WLSZ, blsum + HH,
                                               offs, cnt, csr, h32);
    layernorm_kernel<<<ln_grid, 256, 0, stream>>>(h32, gamma + HH, beta + HH, h32, NN);
    // two-stage pooling
    pool1_kernel<<<BB * NC, 256, 0, stream>>>(h32, batch, psum, pmax);
    pool2_kernel<<<BB, HH, 0, stream>>>(psum, pmax, batch, out);
}

// Round 9
// 428.429 us; speedup vs baseline: 10.2982x; 1.1472x over previous
//
#include <hip/hip_runtime.h>
#include <hip/hip_bf16.h>
#include <math.h>

#define NN 100000   // nodes
#define EE 300000   // edges per type
#define TT 3        // edge types
#define LL 2        // layers
#define HH 128      // hidden
#define FF 5        // node feat
#define TE 64       // type embed
#define NT 200      // num ast types
#define BB 64       // graphs
#define NC 16       // pooling chunks per graph
#define CSRCAP 512  // per-type per-block LDS index cap (mean ~192)
#define WLSZ 131072 // per-layer fragment-packed weight size (shorts)

typedef short bf16x8 __attribute__((ext_vector_type(8)));
typedef float f32x4  __attribute__((ext_vector_type(4)));

__device__ __forceinline__ float bf2f(unsigned short u) {
    union { unsigned i; float f; } v; v.i = ((unsigned)u) << 16; return v.f;
}
__device__ __forceinline__ float bflo(unsigned u) {
    union { unsigned i; float f; } v; v.i = u << 16; return v.f;
}
__device__ __forceinline__ float bfhi(unsigned u) {
    union { unsigned i; float f; } v; v.i = u & 0xFFFF0000u; return v.f;
}
__device__ __forceinline__ unsigned short f2bf(float f) {
    union { float f; unsigned i; } v; v.f = f;
    unsigned b = v.i + (0x7FFFu + ((v.i >> 16) & 1u));   // RNE
    return (unsigned short)(b >> 16);
}
__device__ __forceinline__ unsigned pk2(float a, float b) {
    return (unsigned)f2bf(a) | ((unsigned)f2bf(b) << 16);
}
// split x ~= hi + lo (two bf16); hi+lo reproduces x to ~2^-16 rel
__device__ __forceinline__ void split_bf(float x, unsigned short& hi, unsigned short& lo) {
    hi = f2bf(x);
    lo = f2bf(x - bf2f(hi));
}

// ================================================================ CSR build (validated R2)
__global__ void count_kernel(const int* __restrict__ ei, int* __restrict__ cnt) {
    int i = blockIdx.x * blockDim.x + threadIdx.x;
    if (i >= TT * EE) return;
    int t = i / EE, e = i - t * EE;
    int dst = ei[(t * 2 + 1) * EE + e];
    atomicAdd(&cnt[t * NN + dst], 1);
}

__global__ __launch_bounds__(256) void scan1_kernel(const int* __restrict__ cnt,
                                                    int* __restrict__ offs,
                                                    int* __restrict__ bsums, int M) {
    int tid = threadIdx.x;
    int base = blockIdx.x * 1024 + tid * 4;
    int a0 = 0, a1 = 0, a2 = 0, a3 = 0;
    if (base + 3 < M) { int4 v = *(const int4*)&cnt[base]; a0 = v.x; a1 = v.y; a2 = v.z; a3 = v.w; }
    else {
        if (base + 0 < M) a0 = cnt[base + 0];
        if (base + 1 < M) a1 = cnt[base + 1];
        if (base + 2 < M) a2 = cnt[base + 2];
        if (base + 3 < M) a3 = cnt[base + 3];
    }
    int s = a0 + a1 + a2 + a3;
    int lane = tid & 63, wv = tid >> 6;
    int x = s;
    #pragma unroll
    for (int o = 1; o < 64; o <<= 1) { int y = __shfl_up(x, o); if (lane >= o) x += y; }
    __shared__ int wsum[4];
    if (lane == 63) wsum[wv] = x;
    __syncthreads();
    int add = 0;
    for (int w = 0; w < wv; ++w) add += wsum[w];
    int incl = x + add;
    int e0 = incl - s, e1 = e0 + a0, e2 = e1 + a1, e3 = e2 + a2;
    if (base + 0 < M) offs[base + 0] = e0;
    if (base + 1 < M) offs[base + 1] = e1;
    if (base + 2 < M) offs[base + 2] = e2;
    if (base + 3 < M) offs[base + 3] = e3;
    if (tid == 255) bsums[blockIdx.x] = incl;
}

__global__ __launch_bounds__(512) void scan2_kernel(int* __restrict__ bsums, int NB) {
    int tid = threadIdx.x;
    int s = (tid < NB) ? bsums[tid] : 0;
    int lane = tid & 63, wv = tid >> 6;
    int x = s;
    #pragma unroll
    for (int o = 1; o < 64; o <<= 1) { int y = __shfl_up(x, o); if (lane >= o) x += y; }
    __shared__ int wsum[8];
    if (lane == 63) wsum[wv] = x;
    __syncthreads();
    int add = 0;
    for (int w = 0; w < wv; ++w) add += wsum[w];
    if (tid < NB) bsums[tid] = x + add - s;
}

__global__ void scan3_kernel(int* __restrict__ offs, const int* __restrict__ bsums,
                             int* __restrict__ cursor, int M) {
    int i = blockIdx.x * 256 + threadIdx.x;
    if (i >= M) return;
    int v = offs[i] + bsums[i >> 10];
    offs[i] = v;
    cursor[i] = v;
}

__global__ void fill_kernel(const int* __restrict__ ei, int* __restrict__ cursor,
                            int* __restrict__ csr) {
    int i = blockIdx.x * blockDim.x + threadIdx.x;
    if (i >= TT * EE) return;
    int t = i / EE, e = i - t * EE;
    int src = ei[(t * 2 + 0) * EE + e];
    int dst = ei[(t * 2 + 1) * EE + e];
    int pos = atomicAdd(&cursor[t * NN + dst], 1);
    csr[pos] = src;
}

// ================================================================ weight prep (fragment-major pack, validated R8)
__global__ void wprep_kernel(const float* __restrict__ W_l, const float* __restrict__ W_r,
                             const float* __restrict__ b_l,
                             unsigned short* __restrict__ Wt16, float* __restrict__ blsum) {
    int i = blockIdx.x * 256 + threadIdx.x;
    if (i < LL * 4 * HH * HH) {
        int lm = i >> 14;          // l*4 + m
        int ck = i & 16383;
        int col = ck >> 7, k = ck & 127;
        int l = lm >> 2, m = lm & 3;
        float v;
        if (m == 0) {
            v = 0.f;
            for (int t = 0; t < TT; ++t)
                v += W_r[(((size_t)(l * TT + t)) << 14) + k * HH + col];
        } else {
            v = W_l[(((size_t)(l * TT + (m - 1))) << 14) + k * HH + col];
        }
        unsigned short hi, lo;
        split_bf(v, hi, lo);
        int cg = col >> 4, l15 = col & 15;
        int ks = k >> 5, lh = (k >> 3) & 3, j = k & 7;
        int lane = lh * 16 + l15;
        size_t base = (size_t)l * WLSZ;
        int Phi = (m * 2 + 0) * 4 + ks;
        int Plo = Phi + 4;
        Wt16[base + (size_t)Phi * 4096 + cg * 512 + lane * 8 + j] = hi;
        Wt16[base + (size_t)Plo * 4096 + cg * 512 + lane * 8 + j] = lo;
    }
    if (i < LL * HH) {
        int l = i >> 7, j = i & 127;
        float s = 0.f;
        for (int t = 0; t < TT; ++t) s += b_l[(l * TT + t) * HH + j];
        blsum[i] = s;
    }
}

// ================================================================ input projection (R2 + h16 shadow write)
__global__ __launch_bounds__(512) void input_proj_kernel(
    const float* __restrict__ x, const int* __restrict__ ast,
    const float* __restrict__ emb, const float* __restrict__ W_in,
    const float* __restrict__ b_in, float* __restrict__ h,
    unsigned short* __restrict__ h16)
{
    __shared__ float Ws[(TE + FF) * HH];   // 35.3 KB
    __shared__ float Es[NT * TE];          // 51.2 KB
    int tid = threadIdx.x;
    for (int i = tid; i < (TE + FF) * HH; i += 512) Ws[i] = W_in[i];
    for (int i = tid; i < NT * TE; i += 512) Es[i] = emb[i];
    __syncthreads();
    int col = tid & 127, nl = tid >> 7;    // 4 nodes per block-iteration
    float bj = b_in[col];
    for (int n = blockIdx.x * 4 + nl; n < NN; n += gridDim.x * 4) {
        int a = ast[n];
        float acc = bj;
        const float* ep = &Es[a * TE];
        #pragma unroll
        for (int k = 0; k < TE; ++k) acc = fmaf(ep[k], Ws[k * HH + col], acc);
        #pragma unroll
        for (int k = 0; k < FF; ++k) acc = fmaf(x[n * FF + k], Ws[(TE + k) * HH + col], acc);
        h[(size_t)n * HH + col] = acc;
        h16[(size_t)n * HH + col] = f2bf(acc);
    }
}

// ================================================================ conv layer (split-bf16 MFMA, bf16 gather payload)
// R9: gather reads the bf16 shadow h16 (256B/edge, halved traffic); gather
// un-hoisted back into m-loop (frees ~32 VGPR). Everything else R8 verbatim.
#define ALD 136   // padded LDS stride (shorts): 272 B -> 2-way bank aliasing (free)

__global__ __launch_bounds__(512) void conv_kernel(
    const float* __restrict__ h,                 // [N][128] f32 (dense A path)
    const unsigned* __restrict__ h16u,           // [N][64] packed bf16 pairs (gather path)
    const unsigned short* __restrict__ Wt_l,     // fragment-packed, per-layer base
    const float* __restrict__ blsum_l,
    const int* __restrict__ offs, const int* __restrict__ cnt, const int* __restrict__ csr,
    float* __restrict__ ob)
{
    __shared__ unsigned short Ahi[64 * ALD];     // 17.4 KB
    __shared__ unsigned short Alo[64 * ALD];     // 17.4 KB
    __shared__ int csr_lds[TT][CSRCAP];          // 6 KB
    __shared__ int base_lds[TT], len_lds[TT], flag_lds[TT];

    int tid = threadIdx.x;
    int row0 = blockIdx.x * 64;
    int nrow = min(64, NN - row0);
    int w = tid >> 6, l = tid & 63;
    int l15 = l & 15, koff = (l >> 4) * 8;

    // ---- stage CSR ranges (rows consecutive -> contiguous csr slice per type)
    if (tid < TT) {
        int t = tid;
        int last = row0 + nrow - 1;
        int b = offs[t * NN + row0];
        int e = offs[t * NN + last] + cnt[t * NN + last];
        base_lds[t] = b;
        len_lds[t] = e - b;
        flag_lds[t] = (e - b) <= CSRCAP;
    }
    __syncthreads();
    #pragma unroll
    for (int t = 0; t < TT; ++t) {
        if (flag_lds[t]) {
            int b = base_lds[t], len = len_lds[t];
            for (int i = tid; i < len; i += 512) csr_lds[t][i] = csr[b + i];
        }
    }
    __syncthreads();

    int r = tid >> 3, sub = tid & 7;
    int gr = row0 + r;

    f32x4 acc[4] = {};

    #pragma unroll
    for (int m = 0; m < 4; ++m) {
        // ---- stage A-tile (hi/lo split), padded linear layout
        if (m == 0) {
            #pragma unroll
            for (int s2 = 0; s2 < 2; ++s2) {
                int c16 = s2 * 512 + tid;
                int rr = c16 >> 4, k0 = (c16 & 15) * 8;
                int grr = row0 + rr;
                float v[8] = {0.f,0.f,0.f,0.f,0.f,0.f,0.f,0.f};
                if (grr < NN) {
                    float4 va = *(const float4*)&h[(size_t)grr * 128 + k0];
                    float4 vb = *(const float4*)&h[(size_t)grr * 128 + k0 + 4];
                    v[0]=va.x; v[1]=va.y; v[2]=va.z; v[3]=va.w;
                    v[4]=vb.x; v[5]=vb.y; v[6]=vb.z; v[7]=vb.w;
                }
                unsigned short hs[8], ls[8];
                #pragma unroll
                for (int j = 0; j < 8; ++j) split_bf(v[j], hs[j], ls[j]);
                uint4 hv, lv;
                hv.x = (unsigned)hs[0] | ((unsigned)hs[1] << 16);
                hv.y = (unsigned)hs[2] | ((unsigned)hs[3] << 16);
                hv.z = (unsigned)hs[4] | ((unsigned)hs[5] << 16);
                hv.w = (unsigned)hs[6] | ((unsigned)hs[7] << 16);
                lv.x = (unsigned)ls[0] | ((unsigned)ls[1] << 16);
                lv.y = (unsigned)ls[2] | ((unsigned)ls[3] << 16);
                lv.z = (unsigned)ls[4] | ((unsigned)ls[5] << 16);
                lv.w = (unsigned)ls[6] | ((unsigned)ls[7] << 16);
                *(uint4*)&Ahi[rr * ALD + k0] = hv;
                *(uint4*)&Alo[rr * ALD + k0] = lv;
            }
        } else {
            int t = m - 1;   // static under #pragma unroll
            // ---- gather mean_t for this block's rows from bf16 shadow (32B/edge/thread)
            float ms[16];
            #pragma unroll
            for (int j = 0; j < 16; ++j) ms[j] = 0.f;
            float inv = 0.f;
            if (gr < NN) {
                int o = offs[t * NN + gr];
                int c = cnt[t * NN + gr];
                inv = (c > 0) ? 1.0f / (float)c : 0.0f;
                bool inl = flag_lds[t] != 0;
                int rel = o - base_lds[t];
                for (int j = 0; j < c; ++j) {
                    int src = inl ? csr_lds[t][rel + j] : csr[o + j];
                    const uint4* hp = (const uint4*)&h16u[(size_t)src * 64 + sub * 8];
                    uint4 v0 = hp[0], v1 = hp[1];
                    ms[0]  += bflo(v0.x); ms[1]  += bfhi(v0.x);
                    ms[2]  += bflo(v0.y); ms[3]  += bfhi(v0.y);
                    ms[4]  += bflo(v0.z); ms[5]  += bfhi(v0.z);
                    ms[6]  += bflo(v0.w); ms[7]  += bfhi(v0.w);
                    ms[8]  += bflo(v1.x); ms[9]  += bfhi(v1.x);
                    ms[10] += bflo(v1.y); ms[11] += bfhi(v1.y);
                    ms[12] += bflo(v1.z); ms[13] += bfhi(v1.z);
                    ms[14] += bflo(v1.w); ms[15] += bfhi(v1.w);
                }
            }
            unsigned short hs[16], ls[16];
            #pragma unroll
            for (int j = 0; j < 16; ++j) split_bf(ms[j] * inv, hs[j], ls[j]);
            uint4 hv0, hv1, lv0, lv1;
            hv0.x = (unsigned)hs[0]  | ((unsigned)hs[1]  << 16);
            hv0.y = (unsigned)hs[2]  | ((unsigned)hs[3]  << 16);
            hv0.z = (unsigned)hs[4]  | ((unsigned)hs[5]  << 16);
            hv0.w = (unsigned)hs[6]  | ((unsigned)hs[7]  << 16);
            hv1.x = (unsigned)hs[8]  | ((unsigned)hs[9]  << 16);
            hv1.y = (unsigned)hs[10] | ((unsigned)hs[11] << 16);
            hv1.z = (unsigned)hs[12] | ((unsigned)hs[13] << 16);
            hv1.w = (unsigned)hs[14] | ((unsigned)hs[15] << 16);
            lv0.x = (unsigned)ls[0]  | ((unsigned)ls[1]  << 16);
            lv0.y = (unsigned)ls[2]  | ((unsigned)ls[3]  << 16);
            lv0.z = (unsigned)ls[4]  | ((unsigned)ls[5]  << 16);
            lv0.w = (unsigned)ls[6]  | ((unsigned)ls[7]  << 16);
            lv1.x = (unsigned)ls[8]  | ((unsigned)ls[9]  << 16);
            lv1.y = (unsigned)ls[10] | ((unsigned)ls[11] << 16);
            lv1.z = (unsigned)ls[12] | ((unsigned)ls[13] << 16);
            lv1.w = (unsigned)ls[14] | ((unsigned)ls[15] << 16);
            *(uint4*)&Ahi[r * ALD + sub * 16]     = hv0;
            *(uint4*)&Ahi[r * ALD + sub * 16 + 8] = hv1;
            *(uint4*)&Alo[r * ALD + sub * 16]     = lv0;
            *(uint4*)&Alo[r * ALD + sub * 16 + 8] = lv1;
        }
        __syncthreads();
        // ---- MFMA: W fragments direct from global (coalesced 16B/lane, L2-hot)
        #pragma unroll
        for (int ks = 0; ks < 4; ++ks) {
            bf16x8 wh = *(const bf16x8*)&Wt_l[(size_t)(8 * m + ks) * 4096 + w * 512 + l * 8];
            bf16x8 wl = *(const bf16x8*)&Wt_l[(size_t)(8 * m + 4 + ks) * 4096 + w * 512 + l * 8];
            int k0 = ks * 32 + koff;
            #pragma unroll
            for (int rt = 0; rt < 4; ++rt) {
                bf16x8 ah = *(const bf16x8*)&Ahi[(rt * 16 + l15) * ALD + k0];
                bf16x8 al = *(const bf16x8*)&Alo[(rt * 16 + l15) * ALD + k0];
                acc[rt] = __builtin_amdgcn_mfma_f32_16x16x32_bf16(ah, wh, acc[rt], 0, 0, 0);
                acc[rt] = __builtin_amdgcn_mfma_f32_16x16x32_bf16(al, wh, acc[rt], 0, 0, 0);
                acc[rt] = __builtin_amdgcn_mfma_f32_16x16x32_bf16(ah, wl, acc[rt], 0, 0, 0);
            }
        }
        __syncthreads();   // before next m overwrites A
    }

    // ---- bias + raw global store (m89 C/D layout: col=lane&15, row=(lane>>4)*4+reg)
    {
        int col = w * 16 + l15;
        float bv = blsum_l[col];
        int rbase = row0 + (l >> 4) * 4;
        #pragma unroll
        for (int rt = 0; rt < 4; ++rt) {
            #pragma unroll
            for (int i = 0; i < 4; ++i) {
                int grr = rbase + rt * 16 + i;
                if (grr < NN) ob[(size_t)grr * HH + col] = acc[rt][i] + bv;
            }
        }
    }
}

// ================================================================ layernorm (R1 + h16 shadow write)
__global__ void layernorm_kernel(const float* __restrict__ in, const float* __restrict__ gamma,
                                 const float* __restrict__ beta, float* __restrict__ out,
                                 unsigned* __restrict__ h16u, int rows) {
    int lane = threadIdx.x & 63;
    int row = blockIdx.x * 4 + (threadIdx.x >> 6);
    if (row >= rows) return;
    float2 v = *reinterpret_cast<const float2*>(&in[(size_t)row * HH + lane * 2]);
    float s = v.x + v.y, sq = v.x * v.x + v.y * v.y;
    #pragma unroll
    for (int o = 32; o; o >>= 1) { s += __shfl_xor(s, o); sq += __shfl_xor(sq, o); }
    float mu = s * (1.0f / HH);
    float var = sq * (1.0f / HH) - mu * mu;
    float r = rsqrtf(var + 1e-5f);
    float2 gj = *reinterpret_cast<const float2*>(&gamma[lane * 2]);
    float2 bj = *reinterpret_cast<const float2*>(&beta[lane * 2]);
    float2 o2;
    o2.x = (v.x - mu) * r * gj.x + bj.x;
    o2.y = (v.y - mu) * r * gj.y + bj.y;
    *reinterpret_cast<float2*>(&out[(size_t)row * HH + lane * 2]) = o2;
    h16u[(size_t)row * 64 + lane] = pk2(o2.x, o2.y);
}

// ================================================================ two-stage pooling (validated R6)
__global__ void pool1_kernel(const float* __restrict__ h, const int* __restrict__ batch,
                             float* __restrict__ psum, float* __restrict__ pmax) {
    int g = blockIdx.x >> 4, c = blockIdx.x & (NC - 1);
    int start, end;
    {
        int lo = 0, hi = NN;
        while (lo < hi) { int mid = (lo + hi) >> 1; if (batch[mid] < g) lo = mid + 1; else hi = mid; }
        start = lo;
        hi = NN;
        while (lo < hi) { int mid = (lo + hi) >> 1; if (batch[mid] < g + 1) lo = mid + 1; else hi = mid; }
        end = lo;
    }
    int len = end - start;
    int chunk = (len + NC - 1) / NC;
    int clo = start + c * chunk;
    int chi = min(clo + chunk, end);
    int tid = threadIdx.x;
    int d = tid & 127, half = tid >> 7;
    float s = 0.f, m = -INFINITY;
    for (int n = clo + half; n < chi; n += 2) {
        float v = h[(size_t)n * HH + d];
        s += v; m = fmaxf(m, v);
    }
    __shared__ float ss[256], sm[256];
    ss[tid] = s; sm[tid] = m;
    __syncthreads();
    if (half == 0) {
        s += ss[tid + 128];
        m = fmaxf(m, sm[tid + 128]);
        psum[(size_t)blockIdx.x * HH + d] = s;
        pmax[(size_t)blockIdx.x * HH + d] = m;
    }
}

__global__ void pool2_kernel(const float* __restrict__ psum, const float* __restrict__ pmax,
                             const int* __restrict__ batch, float* __restrict__ out) {
    int g = blockIdx.x;
    int d = threadIdx.x;   // 128 threads
    int start, end;
    {
        int lo = 0, hi = NN;
        while (lo < hi) { int mid = (lo + hi) >> 1; if (batch[mid] < g) lo = mid + 1; else hi = mid; }
        start = lo;
        hi = NN;
        while (lo < hi) { int mid = (lo + hi) >> 1; if (batch[mid] < g + 1) lo = mid + 1; else hi = mid; }
        end = lo;
    }
    float s = 0.f, m = -INFINITY;
    #pragma unroll
    for (int c = 0; c < NC; ++c) {
        s += psum[(size_t)(g * NC + c) * HH + d];
        m = fmaxf(m, pmax[(size_t)(g * NC + c) * HH + d]);
    }
    int cg = end - start;
    out[g * 2 * HH + d] = s / fmaxf((float)cg, 1.0f);
    out[g * 2 * HH + HH + d] = (cg > 0) ? m : 0.0f;
}

// ================================================================ launch
extern "C" void kernel_launch(void* const* d_in, const int* in_sizes, int n_in,
                              void* d_out, int out_size, void* d_ws, size_t ws_size,
                              hipStream_t stream) {
    const float* x     = (const float*)d_in[0];
    const int*   ast   = (const int*)d_in[1];
    const int*   batch = (const int*)d_in[2];
    const int*   ei    = (const int*)d_in[3];
    const float* emb   = (const float*)d_in[4];
    const float* W_in  = (const float*)d_in[5];
    const float* b_in  = (const float*)d_in[6];
    const float* W_l   = (const float*)d_in[7];
    const float* b_l   = (const float*)d_in[8];
    const float* W_r   = (const float*)d_in[9];
    const float* gamma = (const float*)d_in[10];
    const float* beta  = (const float*)d_in[11];
    float* out = (float*)d_out;

    const int M  = TT * NN;
    const int NB = (M + 1023) / 1024;

    char* p = (char*)d_ws;
    float* h32 = (float*)p;                    p += (size_t)NN * HH * 4;   // 51.2 MB
    float* ob  = (float*)p;                    p += (size_t)NN * HH * 4;   // 51.2 MB
    unsigned* h16u = (unsigned*)p;             p += (size_t)NN * HH * 2;   // 25.6 MB
    unsigned short* Wt16 = (unsigned short*)p; p += (size_t)LL * WLSZ * 2;
    float* blsum = (float*)p;                  p += LL * HH * 4;
    float* psum = (float*)p;                   p += (size_t)BB * NC * HH * 4;
    float* pmax = (float*)p;                   p += (size_t)BB * NC * HH * 4;
    int* cnt    = (int*)p;                     p += (size_t)M * 4;
    int* offs   = (int*)p;                     p += (size_t)M * 4;
    int* cursor = (int*)p;                     p += (size_t)M * 4;
    int* csr    = (int*)p;                     p += (size_t)TT * EE * 4;
    int* bsums  = (int*)p;

    hipMemsetAsync(cnt, 0, (size_t)M * sizeof(int), stream);
    count_kernel<<<(TT * EE + 255) / 256, 256, 0, stream>>>(ei, cnt);
    scan1_kernel<<<NB, 256, 0, stream>>>(cnt, offs, bsums, M);
    scan2_kernel<<<1, 512, 0, stream>>>(bsums, NB);
    scan3_kernel<<<(M + 255) / 256, 256, 0, stream>>>(offs, bsums, cursor, M);
    fill_kernel<<<(TT * EE + 255) / 256, 256, 0, stream>>>(ei, cursor, csr);
    wprep_kernel<<<(LL * 4 * HH * HH + 255) / 256, 256, 0, stream>>>(W_l, W_r, b_l, Wt16, blsum);
    input_proj_kernel<<<512, 512, 0, stream>>>(x, ast, emb, W_in, b_in, h32,
                                               (unsigned short*)h16u);

    int conv_grid = (NN + 63) / 64;
    int ln_grid = (NN + 3) / 4;
    // layer 0: h32 -> ob (gather from h16 shadow of h32), LN in-place + refresh h16
    conv_kernel<<<conv_grid, 512, 0, stream>>>(h32, h16u, Wt16, blsum, offs, cnt, csr, ob);
    layernorm_kernel<<<ln_grid, 256, 0, stream>>>(ob, gamma, beta, ob, h16u, NN);
    // layer 1: ob -> h32 (gather from h16 shadow of LN0 output), LN in-place
    conv_kernel<<<conv_grid, 512, 0, stream>>>(ob, h16u, Wt16 + (size_t)WLSZ, blsum + HH,
                                               offs, cnt, csr, h32);
    layernorm_kernel<<<ln_grid, 256, 0, stream>>>(h32, gamma + HH, beta + HH, h32, h16u, NN);
    // two-stage pooling
    pool1_kernel<<<BB * NC, 256, 0, stream>>>(h32, batch, psum, pmax);
    pool2_kernel<<<BB, HH, 0, stream>>>(psum, pmax, batch, out);
}

// Round 10
// 406.228 us; speedup vs baseline: 10.8610x; 1.0547x over previous
//
#include <hip/hip_runtime.h>
#include <hip/hip_bf16.h>
#include <math.h>

#define NN 100000   // nodes
#define EE 300000   // edges per type
#define TT 3        // edge types
#define LL 2        // layers
#define HH 128      // hidden
#define FF 5        // node feat
#define TE 64       // type embed
#define NT 200      // num ast types
#define BB 64       // graphs
#define NC 16       // pooling chunks per graph
#define CSRCAP 512  // per-type per-block LDS index cap (mean ~192)
#define WLSZ 131072 // per-layer fragment-packed weight size (shorts)

typedef short bf16x8 __attribute__((ext_vector_type(8)));
typedef float f32x4  __attribute__((ext_vector_type(4)));

__device__ __forceinline__ float bf2f(unsigned short u) {
    union { unsigned i; float f; } v; v.i = ((unsigned)u) << 16; return v.f;
}
__device__ __forceinline__ float bflo(unsigned u) {
    union { unsigned i; float f; } v; v.i = u << 16; return v.f;
}
__device__ __forceinline__ float bfhi(unsigned u) {
    union { unsigned i; float f; } v; v.i = u & 0xFFFF0000u; return v.f;
}
__device__ __forceinline__ unsigned short f2bf(float f) {
    union { float f; unsigned i; } v; v.f = f;
    unsigned b = v.i + (0x7FFFu + ((v.i >> 16) & 1u));   // RNE
    return (unsigned short)(b >> 16);
}
__device__ __forceinline__ unsigned pk2(float a, float b) {
    return (unsigned)f2bf(a) | ((unsigned)f2bf(b) << 16);
}
// split x ~= hi + lo (two bf16); hi+lo reproduces x to ~2^-16 rel
__device__ __forceinline__ void split_bf(float x, unsigned short& hi, unsigned short& lo) {
    hi = f2bf(x);
    lo = f2bf(x - bf2f(hi));
}

// ================================================================ CSR build (validated R2)
__global__ void count_kernel(const int* __restrict__ ei, int* __restrict__ cnt) {
    int i = blockIdx.x * blockDim.x + threadIdx.x;
    if (i >= TT * EE) return;
    int t = i / EE, e = i - t * EE;
    int dst = ei[(t * 2 + 1) * EE + e];
    atomicAdd(&cnt[t * NN + dst], 1);
}

__global__ __launch_bounds__(256) void scan1_kernel(const int* __restrict__ cnt,
                                                    int* __restrict__ offs,
                                                    int* __restrict__ bsums, int M) {
    int tid = threadIdx.x;
    int base = blockIdx.x * 1024 + tid * 4;
    int a0 = 0, a1 = 0, a2 = 0, a3 = 0;
    if (base + 3 < M) { int4 v = *(const int4*)&cnt[base]; a0 = v.x; a1 = v.y; a2 = v.z; a3 = v.w; }
    else {
        if (base + 0 < M) a0 = cnt[base + 0];
        if (base + 1 < M) a1 = cnt[base + 1];
        if (base + 2 < M) a2 = cnt[base + 2];
        if (base + 3 < M) a3 = cnt[base + 3];
    }
    int s = a0 + a1 + a2 + a3;
    int lane = tid & 63, wv = tid >> 6;
    int x = s;
    #pragma unroll
    for (int o = 1; o < 64; o <<= 1) { int y = __shfl_up(x, o); if (lane >= o) x += y; }
    __shared__ int wsum[4];
    if (lane == 63) wsum[wv] = x;
    __syncthreads();
    int add = 0;
    for (int w = 0; w < wv; ++w) add += wsum[w];
    int incl = x + add;
    int e0 = incl - s, e1 = e0 + a0, e2 = e1 + a1, e3 = e2 + a2;
    if (base + 0 < M) offs[base + 0] = e0;
    if (base + 1 < M) offs[base + 1] = e1;
    if (base + 2 < M) offs[base + 2] = e2;
    if (base + 3 < M) offs[base + 3] = e3;
    if (tid == 255) bsums[blockIdx.x] = incl;
}

__global__ __launch_bounds__(512) void scan2_kernel(int* __restrict__ bsums, int NB) {
    int tid = threadIdx.x;
    int s = (tid < NB) ? bsums[tid] : 0;
    int lane = tid & 63, wv = tid >> 6;
    int x = s;
    #pragma unroll
    for (int o = 1; o < 64; o <<= 1) { int y = __shfl_up(x, o); if (lane >= o) x += y; }
    __shared__ int wsum[8];
    if (lane == 63) wsum[wv] = x;
    __syncthreads();
    int add = 0;
    for (int w = 0; w < wv; ++w) add += wsum[w];
    if (tid < NB) bsums[tid] = x + add - s;
}

__global__ void scan3_kernel(int* __restrict__ offs, const int* __restrict__ bsums,
                             int* __restrict__ cursor, int M) {
    int i = blockIdx.x * 256 + threadIdx.x;
    if (i >= M) return;
    int v = offs[i] + bsums[i >> 10];
    offs[i] = v;
    cursor[i] = v;
}

__global__ void fill_kernel(const int* __restrict__ ei, int* __restrict__ cursor,
                            int* __restrict__ csr) {
    int i = blockIdx.x * blockDim.x + threadIdx.x;
    if (i >= TT * EE) return;
    int t = i / EE, e = i - t * EE;
    int src = ei[(t * 2 + 0) * EE + e];
    int dst = ei[(t * 2 + 1) * EE + e];
    int pos = atomicAdd(&cursor[t * NN + dst], 1);
    csr[pos] = src;
}

// ================================================================ weight prep (fragment-major pack, validated R8)
__global__ void wprep_kernel(const float* __restrict__ W_l, const float* __restrict__ W_r,
                             const float* __restrict__ b_l,
                             unsigned short* __restrict__ Wt16, float* __restrict__ blsum) {
    int i = blockIdx.x * 256 + threadIdx.x;
    if (i < LL * 4 * HH * HH) {
        int lm = i >> 14;          // l*4 + m
        int ck = i & 16383;
        int col = ck >> 7, k = ck & 127;
        int l = lm >> 2, m = lm & 3;
        float v;
        if (m == 0) {
            v = 0.f;
            for (int t = 0; t < TT; ++t)
                v += W_r[(((size_t)(l * TT + t)) << 14) + k * HH + col];
        } else {
            v = W_l[(((size_t)(l * TT + (m - 1))) << 14) + k * HH + col];
        }
        unsigned short hi, lo;
        split_bf(v, hi, lo);
        int cg = col >> 4, l15 = col & 15;
        int ks = k >> 5, lh = (k >> 3) & 3, j = k & 7;
        int lane = lh * 16 + l15;
        size_t base = (size_t)l * WLSZ;
        int Phi = (m * 2 + 0) * 4 + ks;
        int Plo = Phi + 4;
        Wt16[base + (size_t)Phi * 4096 + cg * 512 + lane * 8 + j] = hi;
        Wt16[base + (size_t)Plo * 4096 + cg * 512 + lane * 8 + j] = lo;
    }
    if (i < LL * HH) {
        int l = i >> 7, j = i & 127;
        float s = 0.f;
        for (int t = 0; t < TT; ++t) s += b_l[(l * TT + t) * HH + j];
        blsum[i] = s;
    }
}

// ================================================================ input projection (R2 body, bf16-only output)
__global__ __launch_bounds__(512) void input_proj_kernel(
    const float* __restrict__ x, const int* __restrict__ ast,
    const float* __restrict__ emb, const float* __restrict__ W_in,
    const float* __restrict__ b_in, unsigned short* __restrict__ h16)
{
    __shared__ float Ws[(TE + FF) * HH];   // 35.3 KB
    __shared__ float Es[NT * TE];          // 51.2 KB
    int tid = threadIdx.x;
    for (int i = tid; i < (TE + FF) * HH; i += 512) Ws[i] = W_in[i];
    for (int i = tid; i < NT * TE; i += 512) Es[i] = emb[i];
    __syncthreads();
    int col = tid & 127, nl = tid >> 7;    // 4 nodes per block-iteration
    float bj = b_in[col];
    for (int n = blockIdx.x * 4 + nl; n < NN; n += gridDim.x * 4) {
        int a = ast[n];
        float acc = bj;
        const float* ep = &Es[a * TE];
        #pragma unroll
        for (int k = 0; k < TE; ++k) acc = fmaf(ep[k], Ws[k * HH + col], acc);
        #pragma unroll
        for (int k = 0; k < FF; ++k) acc = fmaf(x[n * FF + k], Ws[(TE + k) * HH + col], acc);
        h16[(size_t)n * HH + col] = f2bf(acc);
    }
}

// ================================================================ conv layer (split-bf16 MFMA, all-bf16 h)
// R10: h lives only as bf16. m=0 A-path reads h16 (a_lo=0 -> 2 MFMAs);
// means stay f32-summed + split (3 MFMAs). Output written bf16.
#define ALD 136   // padded LDS stride (shorts): 272 B -> 2-way bank aliasing (free)

__global__ __launch_bounds__(512) void conv_kernel(
    const unsigned short* __restrict__ h16,      // [N][128] bf16 (dense A + gather)
    const unsigned short* __restrict__ Wt_l,     // fragment-packed, per-layer base
    const float* __restrict__ blsum_l,
    const int* __restrict__ offs, const int* __restrict__ cnt, const int* __restrict__ csr,
    unsigned short* __restrict__ ob16)
{
    __shared__ unsigned short Ahi[64 * ALD];     // 17.4 KB
    __shared__ unsigned short Alo[64 * ALD];     // 17.4 KB
    __shared__ int csr_lds[TT][CSRCAP];          // 6 KB
    __shared__ int base_lds[TT], len_lds[TT], flag_lds[TT];

    int tid = threadIdx.x;
    int row0 = blockIdx.x * 64;
    int nrow = min(64, NN - row0);
    int w = tid >> 6, l = tid & 63;
    int l15 = l & 15, koff = (l >> 4) * 8;

    // ---- stage CSR ranges (rows consecutive -> contiguous csr slice per type)
    if (tid < TT) {
        int t = tid;
        int last = row0 + nrow - 1;
        int b = offs[t * NN + row0];
        int e = offs[t * NN + last] + cnt[t * NN + last];
        base_lds[t] = b;
        len_lds[t] = e - b;
        flag_lds[t] = (e - b) <= CSRCAP;
    }
    __syncthreads();
    #pragma unroll
    for (int t = 0; t < TT; ++t) {
        if (flag_lds[t]) {
            int b = base_lds[t], len = len_lds[t];
            for (int i = tid; i < len; i += 512) csr_lds[t][i] = csr[b + i];
        }
    }
    __syncthreads();

    int r = tid >> 3, sub = tid & 7;
    int gr = row0 + r;

    f32x4 acc[4] = {};

    #pragma unroll
    for (int m = 0; m < 4; ++m) {
        // ---- stage A-tile
        if (m == 0) {
            // dense rows, bf16 direct copy into Ahi (a_lo = 0)
            #pragma unroll
            for (int s2 = 0; s2 < 2; ++s2) {
                int c16 = s2 * 512 + tid;
                int rr = c16 >> 4, k0 = (c16 & 15) * 8;
                int grr = row0 + rr;
                uint4 hv = {0u, 0u, 0u, 0u};
                if (grr < NN) hv = *(const uint4*)&h16[(size_t)grr * 128 + k0];
                *(uint4*)&Ahi[rr * ALD + k0] = hv;
            }
        } else {
            int t = m - 1;   // static under #pragma unroll
            // ---- gather mean_t from bf16 h (32B/edge/thread), f32 sums, split hi/lo
            float ms[16];
            #pragma unroll
            for (int j = 0; j < 16; ++j) ms[j] = 0.f;
            float inv = 0.f;
            if (gr < NN) {
                int o = offs[t * NN + gr];
                int c = cnt[t * NN + gr];
                inv = (c > 0) ? 1.0f / (float)c : 0.0f;
                bool inl = flag_lds[t] != 0;
                int rel = o - base_lds[t];
                const unsigned* h16u = (const unsigned*)h16;
                for (int j = 0; j < c; ++j) {
                    int src = inl ? csr_lds[t][rel + j] : csr[o + j];
                    const uint4* hp = (const uint4*)&h16u[(size_t)src * 64 + sub * 8];
                    uint4 v0 = hp[0], v1 = hp[1];
                    ms[0]  += bflo(v0.x); ms[1]  += bfhi(v0.x);
                    ms[2]  += bflo(v0.y); ms[3]  += bfhi(v0.y);
                    ms[4]  += bflo(v0.z); ms[5]  += bfhi(v0.z);
                    ms[6]  += bflo(v0.w); ms[7]  += bfhi(v0.w);
                    ms[8]  += bflo(v1.x); ms[9]  += bfhi(v1.x);
                    ms[10] += bflo(v1.y); ms[11] += bfhi(v1.y);
                    ms[12] += bflo(v1.z); ms[13] += bfhi(v1.z);
                    ms[14] += bflo(v1.w); ms[15] += bfhi(v1.w);
                }
            }
            unsigned short hs[16], ls[16];
            #pragma unroll
            for (int j = 0; j < 16; ++j) split_bf(ms[j] * inv, hs[j], ls[j]);
            uint4 hv0, hv1, lv0, lv1;
            hv0.x = (unsigned)hs[0]  | ((unsigned)hs[1]  << 16);
            hv0.y = (unsigned)hs[2]  | ((unsigned)hs[3]  << 16);
            hv0.z = (unsigned)hs[4]  | ((unsigned)hs[5]  << 16);
            hv0.w = (unsigned)hs[6]  | ((unsigned)hs[7]  << 16);
            hv1.x = (unsigned)hs[8]  | ((unsigned)hs[9]  << 16);
            hv1.y = (unsigned)hs[10] | ((unsigned)hs[11] << 16);
            hv1.z = (unsigned)hs[12] | ((unsigned)hs[13] << 16);
            hv1.w = (unsigned)hs[14] | ((unsigned)hs[15] << 16);
            lv0.x = (unsigned)ls[0]  | ((unsigned)ls[1]  << 16);
            lv0.y = (unsigned)ls[2]  | ((unsigned)ls[3]  << 16);
            lv0.z = (unsigned)ls[4]  | ((unsigned)ls[5]  << 16);
            lv0.w = (unsigned)ls[6]  | ((unsigned)ls[7]  << 16);
            lv1.x = (unsigned)ls[8]  | ((unsigned)ls[9]  << 16);
            lv1.y = (unsigned)ls[10] | ((unsigned)ls[11] << 16);
            lv1.z = (unsigned)ls[12] | ((unsigned)ls[13] << 16);
            lv1.w = (unsigned)ls[14] | ((unsigned)ls[15] << 16);
            *(uint4*)&Ahi[r * ALD + sub * 16]     = hv0;
            *(uint4*)&Ahi[r * ALD + sub * 16 + 8] = hv1;
            *(uint4*)&Alo[r * ALD + sub * 16]     = lv0;
            *(uint4*)&Alo[r * ALD + sub * 16 + 8] = lv1;
        }
        __syncthreads();
        // ---- MFMA: W fragments direct from global (coalesced 16B/lane, L2-hot)
        #pragma unroll
        for (int ks = 0; ks < 4; ++ks) {
            bf16x8 wh = *(const bf16x8*)&Wt_l[(size_t)(8 * m + ks) * 4096 + w * 512 + l * 8];
            bf16x8 wl = *(const bf16x8*)&Wt_l[(size_t)(8 * m + 4 + ks) * 4096 + w * 512 + l * 8];
            int k0 = ks * 32 + koff;
            #pragma unroll
            for (int rt = 0; rt < 4; ++rt) {
                bf16x8 ah = *(const bf16x8*)&Ahi[(rt * 16 + l15) * ALD + k0];
                acc[rt] = __builtin_amdgcn_mfma_f32_16x16x32_bf16(ah, wh, acc[rt], 0, 0, 0);
                acc[rt] = __builtin_amdgcn_mfma_f32_16x16x32_bf16(ah, wl, acc[rt], 0, 0, 0);
                if (m > 0) {   // static: a_lo only exists for gathered means
                    bf16x8 al = *(const bf16x8*)&Alo[(rt * 16 + l15) * ALD + k0];
                    acc[rt] = __builtin_amdgcn_mfma_f32_16x16x32_bf16(al, wh, acc[rt], 0, 0, 0);
                }
            }
        }
        __syncthreads();   // before next m overwrites A
    }

    // ---- bias + bf16 global store (m89 C/D layout: col=lane&15, row=(lane>>4)*4+reg)
    {
        int col = w * 16 + l15;
        float bv = blsum_l[col];
        int rbase = row0 + (l >> 4) * 4;
        #pragma unroll
        for (int rt = 0; rt < 4; ++rt) {
            #pragma unroll
            for (int i = 0; i < 4; ++i) {
                int grr = rbase + rt * 16 + i;
                if (grr < NN) ob16[(size_t)grr * HH + col] = f2bf(acc[rt][i] + bv);
            }
        }
    }
}

// ================================================================ layernorm (R1 body, bf16 in/out)
__global__ void layernorm_kernel(const unsigned* __restrict__ in16u,
                                 const float* __restrict__ gamma,
                                 const float* __restrict__ beta,
                                 unsigned* __restrict__ out16u, int rows) {
    int lane = threadIdx.x & 63;
    int row = blockIdx.x * 4 + (threadIdx.x >> 6);
    if (row >= rows) return;
    unsigned u = in16u[(size_t)row * 64 + lane];
    float vx = bflo(u), vy = bfhi(u);
    float s = vx + vy, sq = vx * vx + vy * vy;
    #pragma unroll
    for (int o = 32; o; o >>= 1) { s += __shfl_xor(s, o); sq += __shfl_xor(sq, o); }
    float mu = s * (1.0f / HH);
    float var = sq * (1.0f / HH) - mu * mu;
    float r = rsqrtf(var + 1e-5f);
    float2 gj = *reinterpret_cast<const float2*>(&gamma[lane * 2]);
    float2 bj = *reinterpret_cast<const float2*>(&beta[lane * 2]);
    float ox = (vx - mu) * r * gj.x + bj.x;
    float oy = (vy - mu) * r * gj.y + bj.y;
    out16u[(size_t)row * 64 + lane] = pk2(ox, oy);
}

// ================================================================ two-stage pooling (R6 body, bf16 input)
__global__ void pool1_kernel(const unsigned short* __restrict__ h16,
                             const int* __restrict__ batch,
                             float* __restrict__ psum, float* __restrict__ pmax) {
    int g = blockIdx.x >> 4, c = blockIdx.x & (NC - 1);
    int start, end;
    {
        int lo = 0, hi = NN;
        while (lo < hi) { int mid = (lo + hi) >> 1; if (batch[mid] < g) lo = mid + 1; else hi = mid; }
        start = lo;
        hi = NN;
        while (lo < hi) { int mid = (lo + hi) >> 1; if (batch[mid] < g + 1) lo = mid + 1; else hi = mid; }
        end = lo;
    }
    int len = end - start;
    int chunk = (len + NC - 1) / NC;
    int clo = start + c * chunk;
    int chi = min(clo + chunk, end);
    int tid = threadIdx.x;
    int d = tid & 127, half = tid >> 7;
    float s = 0.f, m = -INFINITY;
    for (int n = clo + half; n < chi; n += 2) {
        float v = bf2f(h16[(size_t)n * HH + d]);
        s += v; m = fmaxf(m, v);
    }
    __shared__ float ss[256], sm[256];
    ss[tid] = s; sm[tid] = m;
    __syncthreads();
    if (half == 0) {
        s += ss[tid + 128];
        m = fmaxf(m, sm[tid + 128]);
        psum[(size_t)blockIdx.x * HH + d] = s;
        pmax[(size_t)blockIdx.x * HH + d] = m;
    }
}

__global__ void pool2_kernel(const float* __restrict__ psum, const float* __restrict__ pmax,
                             const int* __restrict__ batch, float* __restrict__ out) {
    int g = blockIdx.x;
    int d = threadIdx.x;   // 128 threads
    int start, end;
    {
        int lo = 0, hi = NN;
        while (lo < hi) { int mid = (lo + hi) >> 1; if (batch[mid] < g) lo = mid + 1; else hi = mid; }
        start = lo;
        hi = NN;
        while (lo < hi) { int mid = (lo + hi) >> 1; if (batch[mid] < g + 1) lo = mid + 1; else hi = mid; }
        end = lo;
    }
    float s = 0.f, m = -INFINITY;
    #pragma unroll
    for (int c = 0; c < NC; ++c) {
        s += psum[(size_t)(g * NC + c) * HH + d];
        m = fmaxf(m, pmax[(size_t)(g * NC + c) * HH + d]);
    }
    int cg = end - start;
    out[g * 2 * HH + d] = s / fmaxf((float)cg, 1.0f);
    out[g * 2 * HH + HH + d] = (cg > 0) ? m : 0.0f;
}

// ================================================================ launch
extern "C" void kernel_launch(void* const* d_in, const int* in_sizes, int n_in,
                              void* d_out, int out_size, void* d_ws, size_t ws_size,
                              hipStream_t stream) {
    const float* x     = (const float*)d_in[0];
    const int*   ast   = (const int*)d_in[1];
    const int*   batch = (const int*)d_in[2];
    const int*   ei    = (const int*)d_in[3];
    const float* emb   = (const float*)d_in[4];
    const float* W_in  = (const float*)d_in[5];
    const float* b_in  = (const float*)d_in[6];
    const float* W_l   = (const float*)d_in[7];
    const float* b_l   = (const float*)d_in[8];
    const float* W_r   = (const float*)d_in[9];
    const float* gamma = (const float*)d_in[10];
    const float* beta  = (const float*)d_in[11];
    float* out = (float*)d_out;

    const int M  = TT * NN;
    const int NB = (M + 1023) / 1024;

    char* p = (char*)d_ws;
    unsigned short* h16a = (unsigned short*)p;  p += (size_t)NN * HH * 2;   // 25.6 MB
    unsigned short* ob16 = (unsigned short*)p;  p += (size_t)NN * HH * 2;   // 25.6 MB
    unsigned short* Wt16 = (unsigned short*)p;  p += (size_t)LL * WLSZ * 2;
    float* blsum = (float*)p;                   p += LL * HH * 4;
    float* psum = (float*)p;                    p += (size_t)BB * NC * HH * 4;
    float* pmax = (float*)p;                    p += (size_t)BB * NC * HH * 4;
    int* cnt    = (int*)p;                      p += (size_t)M * 4;
    int* offs   = (int*)p;                      p += (size_t)M * 4;
    int* cursor = (int*)p;                      p += (size_t)M * 4;
    int* csr    = (int*)p;                      p += (size_t)TT * EE * 4;
    int* bsums  = (int*)p;

    hipMemsetAsync(cnt, 0, (size_t)M * sizeof(int), stream);
    count_kernel<<<(TT * EE + 255) / 256, 256, 0, stream>>>(ei, cnt);
    scan1_kernel<<<NB, 256, 0, stream>>>(cnt, offs, bsums, M);
    scan2_kernel<<<1, 512, 0, stream>>>(bsums, NB);
    scan3_kernel<<<(M + 255) / 256, 256, 0, stream>>>(offs, bsums, cursor, M);
    fill_kernel<<<(TT * EE + 255) / 256, 256, 0, stream>>>(ei, cursor, csr);
    wprep_kernel<<<(LL * 4 * HH * HH + 255) / 256, 256, 0, stream>>>(W_l, W_r, b_l, Wt16, blsum);
    input_proj_kernel<<<512, 512, 0, stream>>>(x, ast, emb, W_in, b_in, h16a);

    int conv_grid = (NN + 63) / 64;
    int ln_grid = (NN + 3) / 4;
    // layer 0
    conv_kernel<<<conv_grid, 512, 0, stream>>>(h16a, Wt16, blsum, offs, cnt, csr, ob16);
    layernorm_kernel<<<ln_grid, 256, 0, stream>>>((const unsigned*)ob16, gamma, beta,
                                                  (unsigned*)h16a, NN);
    // layer 1
    conv_kernel<<<conv_grid, 512, 0, stream>>>(h16a, Wt16 + (size_t)WLSZ, blsum + HH,
                                               offs, cnt, csr, ob16);
    layernorm_kernel<<<ln_grid, 256, 0, stream>>>((const unsigned*)ob16, gamma + HH, beta + HH,
                                                  (unsigned*)h16a, NN);
    // two-stage pooling
    pool1_kernel<<<BB * NC, 256, 0, stream>>>(h16a, batch, psum, pmax);
    pool2_kernel<<<BB, HH, 0, stream>>>(psum, pmax, batch, out);
}

// Round 11
// 368.789 us; speedup vs baseline: 11.9636x; 1.1015x over previous
//
#include <hip/hip_runtime.h>
#include <hip/hip_bf16.h>
#include <math.h>

#define NN 100000   // nodes
#define EE 300000   // edges per type
#define TT 3        // edge types
#define LL 2        // layers
#define HH 128      // hidden
#define FF 5        // node feat
#define TE 64       // type embed
#define NT 200      // num ast types
#define BB 64       // graphs
#define NC 16       // pooling chunks per graph
#define CSRCAP 512  // per-type per-block LDS index cap (mean ~192)
#define WLSZ 131072 // per-layer fragment-packed weight size (shorts)
#define KIN 96      // padded K for input projection (69 -> 96)
#define IALD 104    // input-proj LDS row stride (shorts)

typedef short bf16x8 __attribute__((ext_vector_type(8)));
typedef float f32x4  __attribute__((ext_vector_type(4)));

__device__ __forceinline__ float bf2f(unsigned short u) {
    union { unsigned i; float f; } v; v.i = ((unsigned)u) << 16; return v.f;
}
__device__ __forceinline__ float bflo(unsigned u) {
    union { unsigned i; float f; } v; v.i = u << 16; return v.f;
}
__device__ __forceinline__ float bfhi(unsigned u) {
    union { unsigned i; float f; } v; v.i = u & 0xFFFF0000u; return v.f;
}
__device__ __forceinline__ unsigned short f2bf(float f) {
    union { float f; unsigned i; } v; v.f = f;
    unsigned b = v.i + (0x7FFFu + ((v.i >> 16) & 1u));   // RNE
    return (unsigned short)(b >> 16);
}
__device__ __forceinline__ unsigned pk2(float a, float b) {
    return (unsigned)f2bf(a) | ((unsigned)f2bf(b) << 16);
}
// split x ~= hi + lo (two bf16); hi+lo reproduces x to ~2^-16 rel
__device__ __forceinline__ void split_bf(float x, unsigned short& hi, unsigned short& lo) {
    hi = f2bf(x);
    lo = f2bf(x - bf2f(hi));
}

// ================================================================ CSR build (validated R2)
__global__ void count_kernel(const int* __restrict__ ei, int* __restrict__ cnt) {
    int i = blockIdx.x * blockDim.x + threadIdx.x;
    if (i >= TT * EE) return;
    int t = i / EE, e = i - t * EE;
    int dst = ei[(t * 2 + 1) * EE + e];
    atomicAdd(&cnt[t * NN + dst], 1);
}

__global__ __launch_bounds__(256) void scan1_kernel(const int* __restrict__ cnt,
                                                    int* __restrict__ offs,
                                                    int* __restrict__ bsums, int M) {
    int tid = threadIdx.x;
    int base = blockIdx.x * 1024 + tid * 4;
    int a0 = 0, a1 = 0, a2 = 0, a3 = 0;
    if (base + 3 < M) { int4 v = *(const int4*)&cnt[base]; a0 = v.x; a1 = v.y; a2 = v.z; a3 = v.w; }
    else {
        if (base + 0 < M) a0 = cnt[base + 0];
        if (base + 1 < M) a1 = cnt[base + 1];
        if (base + 2 < M) a2 = cnt[base + 2];
        if (base + 3 < M) a3 = cnt[base + 3];
    }
    int s = a0 + a1 + a2 + a3;
    int lane = tid & 63, wv = tid >> 6;
    int x = s;
    #pragma unroll
    for (int o = 1; o < 64; o <<= 1) { int y = __shfl_up(x, o); if (lane >= o) x += y; }
    __shared__ int wsum[4];
    if (lane == 63) wsum[wv] = x;
    __syncthreads();
    int add = 0;
    for (int w = 0; w < wv; ++w) add += wsum[w];
    int incl = x + add;
    int e0 = incl - s, e1 = e0 + a0, e2 = e1 + a1, e3 = e2 + a2;
    if (base + 0 < M) offs[base + 0] = e0;
    if (base + 1 < M) offs[base + 1] = e1;
    if (base + 2 < M) offs[base + 2] = e2;
    if (base + 3 < M) offs[base + 3] = e3;
    if (tid == 255) bsums[blockIdx.x] = incl;
}

__global__ __launch_bounds__(512) void scan2_kernel(int* __restrict__ bsums, int NB) {
    int tid = threadIdx.x;
    int s = (tid < NB) ? bsums[tid] : 0;
    int lane = tid & 63, wv = tid >> 6;
    int x = s;
    #pragma unroll
    for (int o = 1; o < 64; o <<= 1) { int y = __shfl_up(x, o); if (lane >= o) x += y; }
    __shared__ int wsum[8];
    if (lane == 63) wsum[wv] = x;
    __syncthreads();
    int add = 0;
    for (int w = 0; w < wv; ++w) add += wsum[w];
    if (tid < NB) bsums[tid] = x + add - s;
}

__global__ void scan3_kernel(int* __restrict__ offs, const int* __restrict__ bsums,
                             int* __restrict__ cursor, int M) {
    int i = blockIdx.x * 256 + threadIdx.x;
    if (i >= M) return;
    int v = offs[i] + bsums[i >> 10];
    offs[i] = v;
    cursor[i] = v;
}

__global__ void fill_kernel(const int* __restrict__ ei, int* __restrict__ cursor,
                            int* __restrict__ csr) {
    int i = blockIdx.x * blockDim.x + threadIdx.x;
    if (i >= TT * EE) return;
    int t = i / EE, e = i - t * EE;
    int src = ei[(t * 2 + 0) * EE + e];
    int dst = ei[(t * 2 + 1) * EE + e];
    int pos = atomicAdd(&cursor[t * NN + dst], 1);
    csr[pos] = src;
}

// ================================================================ weight prep (conv weights, validated R8)
__global__ void wprep_kernel(const float* __restrict__ W_l, const float* __restrict__ W_r,
                             const float* __restrict__ b_l,
                             unsigned short* __restrict__ Wt16, float* __restrict__ blsum) {
    int i = blockIdx.x * 256 + threadIdx.x;
    if (i < LL * 4 * HH * HH) {
        int lm = i >> 14;          // l*4 + m
        int ck = i & 16383;
        int col = ck >> 7, k = ck & 127;
        int l = lm >> 2, m = lm & 3;
        float v;
        if (m == 0) {
            v = 0.f;
            for (int t = 0; t < TT; ++t)
                v += W_r[(((size_t)(l * TT + t)) << 14) + k * HH + col];
        } else {
            v = W_l[(((size_t)(l * TT + (m - 1))) << 14) + k * HH + col];
        }
        unsigned short hi, lo;
        split_bf(v, hi, lo);
        int cg = col >> 4, l15 = col & 15;
        int ks = k >> 5, lh = (k >> 3) & 3, j = k & 7;
        int lane = lh * 16 + l15;
        size_t base = (size_t)l * WLSZ;
        int Phi = (m * 2 + 0) * 4 + ks;
        int Plo = Phi + 4;
        Wt16[base + (size_t)Phi * 4096 + cg * 512 + lane * 8 + j] = hi;
        Wt16[base + (size_t)Plo * 4096 + cg * 512 + lane * 8 + j] = lo;
    }
    if (i < LL * HH) {
        int l = i >> 7, j = i & 127;
        float s = 0.f;
        for (int t = 0; t < TT; ++t) s += b_l[(l * TT + t) * HH + j];
        blsum[i] = s;
    }
}

// ================================================================ weight prep (input proj, K padded to 96)
__global__ void wprep_in_kernel(const float* __restrict__ W_in,
                                unsigned short* __restrict__ Wp) {
    int i = blockIdx.x * 256 + threadIdx.x;
    if (i >= KIN * HH) return;
    int col = i & 127, k = i >> 7;
    float v = (k < TE + FF) ? W_in[k * HH + col] : 0.f;
    unsigned short hi, lo;
    split_bf(v, hi, lo);
    int cg = col >> 4, l15 = col & 15;
    int ks = k >> 5, lh = (k >> 3) & 3, j = k & 7;
    int lane = lh * 16 + l15;
    Wp[(size_t)ks * 4096 + cg * 512 + lane * 8 + j]       = hi;   // P = ks (0..2)
    Wp[(size_t)(4 + ks) * 4096 + cg * 512 + lane * 8 + j] = lo;   // P = 4+ks
}

// ================================================================ input projection (split-bf16 MFMA)
// h16[n,:] = concat(emb[ast[n]], x[n], 0-pad) @ W_in(+pad) + b_in, exact split math.
__global__ __launch_bounds__(512) void input_proj_kernel(
    const float* __restrict__ x, const int* __restrict__ ast,
    const float* __restrict__ emb, const unsigned short* __restrict__ Wp,
    const float* __restrict__ b_in, unsigned short* __restrict__ h16)
{
    __shared__ unsigned short Ahi[64 * IALD];   // 13.3 KB
    __shared__ unsigned short Alo[64 * IALD];   // 13.3 KB

    int tid = threadIdx.x;
    int row0 = blockIdx.x * 64;
    int w = tid >> 6, l = tid & 63;
    int l15 = l & 15, koff = (l >> 4) * 8;

    // ---- stage A-tile: 8 threads x 12 cols per row (96 cols)
    {
        int r = tid >> 3, sub = tid & 7;
        int gr = row0 + r;
        float v[12];
        #pragma unroll
        for (int j = 0; j < 12; ++j) v[j] = 0.f;
        if (gr < NN) {
            int a = ast[gr];
            #pragma unroll
            for (int j = 0; j < 12; ++j) {
                int k = sub * 12 + j;
                if (k < TE) v[j] = emb[a * TE + k];
                else if (k < TE + FF) v[j] = x[gr * FF + (k - TE)];
            }
        }
        unsigned short hs[12], ls[12];
        #pragma unroll
        for (int j = 0; j < 12; ++j) split_bf(v[j], hs[j], ls[j]);
        unsigned uh[6], ul[6];
        #pragma unroll
        for (int q = 0; q < 6; ++q) {
            uh[q] = (unsigned)hs[2 * q] | ((unsigned)hs[2 * q + 1] << 16);
            ul[q] = (unsigned)ls[2 * q] | ((unsigned)ls[2 * q + 1] << 16);
        }
        int base = r * IALD + sub * 12;
        uint2 h0; h0.x = uh[0]; h0.y = uh[1];
        uint2 h1; h1.x = uh[2]; h1.y = uh[3];
        uint2 h2; h2.x = uh[4]; h2.y = uh[5];
        uint2 l0; l0.x = ul[0]; l0.y = ul[1];
        uint2 l1; l1.x = ul[2]; l1.y = ul[3];
        uint2 l2; l2.x = ul[4]; l2.y = ul[5];
        *(uint2*)&Ahi[base + 0] = h0;
        *(uint2*)&Ahi[base + 4] = h1;
        *(uint2*)&Ahi[base + 8] = h2;
        *(uint2*)&Alo[base + 0] = l0;
        *(uint2*)&Alo[base + 4] = l1;
        *(uint2*)&Alo[base + 8] = l2;
    }
    __syncthreads();

    // ---- MFMA: 3 k-steps, W fragments direct from L2-hot pack
    f32x4 acc[4] = {};
    #pragma unroll
    for (int ks = 0; ks < 3; ++ks) {
        bf16x8 wh = *(const bf16x8*)&Wp[(size_t)ks * 4096 + w * 512 + l * 8];
        bf16x8 wl = *(const bf16x8*)&Wp[(size_t)(4 + ks) * 4096 + w * 512 + l * 8];
        int k0 = ks * 32 + koff;
        #pragma unroll
        for (int rt = 0; rt < 4; ++rt) {
            bf16x8 ah = *(const bf16x8*)&Ahi[(rt * 16 + l15) * IALD + k0];
            bf16x8 al = *(const bf16x8*)&Alo[(rt * 16 + l15) * IALD + k0];
            acc[rt] = __builtin_amdgcn_mfma_f32_16x16x32_bf16(ah, wh, acc[rt], 0, 0, 0);
            acc[rt] = __builtin_amdgcn_mfma_f32_16x16x32_bf16(al, wh, acc[rt], 0, 0, 0);
            acc[rt] = __builtin_amdgcn_mfma_f32_16x16x32_bf16(ah, wl, acc[rt], 0, 0, 0);
        }
    }

    // ---- bias + bf16 store (m89 C/D layout, validated epilogue pattern)
    {
        int col = w * 16 + l15;
        float bv = b_in[col];
        int rbase = row0 + (l >> 4) * 4;
        #pragma unroll
        for (int rt = 0; rt < 4; ++rt) {
            #pragma unroll
            for (int i = 0; i < 4; ++i) {
                int grr = rbase + rt * 16 + i;
                if (grr < NN) h16[(size_t)grr * HH + col] = f2bf(acc[rt][i] + bv);
            }
        }
    }
}

// ================================================================ conv layer (bf16 MFMA, single-plane A, W split)
// R11: means stored as single bf16 (no Alo) -> LDS ~24 KB -> 4 blocks/CU.
#define ALD 136   // padded LDS stride (shorts): 272 B -> 2-way bank aliasing (free)

__global__ __launch_bounds__(512) void conv_kernel(
    const unsigned short* __restrict__ h16,      // [N][128] bf16 (dense A + gather)
    const unsigned short* __restrict__ Wt_l,     // fragment-packed, per-layer base
    const float* __restrict__ blsum_l,
    const int* __restrict__ offs, const int* __restrict__ cnt, const int* __restrict__ csr,
    unsigned short* __restrict__ ob16)
{
    __shared__ unsigned short Ahi[64 * ALD];     // 17.4 KB
    __shared__ int csr_lds[TT][CSRCAP];          // 6 KB
    __shared__ int base_lds[TT], len_lds[TT], flag_lds[TT];

    int tid = threadIdx.x;
    int row0 = blockIdx.x * 64;
    int nrow = min(64, NN - row0);
    int w = tid >> 6, l = tid & 63;
    int l15 = l & 15, koff = (l >> 4) * 8;

    // ---- stage CSR ranges (rows consecutive -> contiguous csr slice per type)
    if (tid < TT) {
        int t = tid;
        int last = row0 + nrow - 1;
        int b = offs[t * NN + row0];
        int e = offs[t * NN + last] + cnt[t * NN + last];
        base_lds[t] = b;
        len_lds[t] = e - b;
        flag_lds[t] = (e - b) <= CSRCAP;
    }
    __syncthreads();
    #pragma unroll
    for (int t = 0; t < TT; ++t) {
        if (flag_lds[t]) {
            int b = base_lds[t], len = len_lds[t];
            for (int i = tid; i < len; i += 512) csr_lds[t][i] = csr[b + i];
        }
    }
    __syncthreads();

    int r = tid >> 3, sub = tid & 7;
    int gr = row0 + r;

    f32x4 acc[4] = {};

    #pragma unroll
    for (int m = 0; m < 4; ++m) {
        // ---- stage A-tile (single bf16 plane)
        if (m == 0) {
            #pragma unroll
            for (int s2 = 0; s2 < 2; ++s2) {
                int c16 = s2 * 512 + tid;
                int rr = c16 >> 4, k0 = (c16 & 15) * 8;
                int grr = row0 + rr;
                uint4 hv = {0u, 0u, 0u, 0u};
                if (grr < NN) hv = *(const uint4*)&h16[(size_t)grr * 128 + k0];
                *(uint4*)&Ahi[rr * ALD + k0] = hv;
            }
        } else {
            int t = m - 1;   // static under #pragma unroll
            // ---- gather mean_t from bf16 h (32B/edge/thread), f32 sums -> bf16
            float ms[16];
            #pragma unroll
            for (int j = 0; j < 16; ++j) ms[j] = 0.f;
            float inv = 0.f;
            if (gr < NN) {
                int o = offs[t * NN + gr];
                int c = cnt[t * NN + gr];
                inv = (c > 0) ? 1.0f / (float)c : 0.0f;
                bool inl = flag_lds[t] != 0;
                int rel = o - base_lds[t];
                const unsigned* h16u = (const unsigned*)h16;
                for (int j = 0; j < c; ++j) {
                    int src = inl ? csr_lds[t][rel + j] : csr[o + j];
                    const uint4* hp = (const uint4*)&h16u[(size_t)src * 64 + sub * 8];
                    uint4 v0 = hp[0], v1 = hp[1];
                    ms[0]  += bflo(v0.x); ms[1]  += bfhi(v0.x);
                    ms[2]  += bflo(v0.y); ms[3]  += bfhi(v0.y);
                    ms[4]  += bflo(v0.z); ms[5]  += bfhi(v0.z);
                    ms[6]  += bflo(v0.w); ms[7]  += bfhi(v0.w);
                    ms[8]  += bflo(v1.x); ms[9]  += bfhi(v1.x);
                    ms[10] += bflo(v1.y); ms[11] += bfhi(v1.y);
                    ms[12] += bflo(v1.z); ms[13] += bfhi(v1.z);
                    ms[14] += bflo(v1.w); ms[15] += bfhi(v1.w);
                }
            }
            uint4 hv0, hv1;
            hv0.x = pk2(ms[0] * inv,  ms[1] * inv);
            hv0.y = pk2(ms[2] * inv,  ms[3] * inv);
            hv0.z = pk2(ms[4] * inv,  ms[5] * inv);
            hv0.w = pk2(ms[6] * inv,  ms[7] * inv);
            hv1.x = pk2(ms[8] * inv,  ms[9] * inv);
            hv1.y = pk2(ms[10] * inv, ms[11] * inv);
            hv1.z = pk2(ms[12] * inv, ms[13] * inv);
            hv1.w = pk2(ms[14] * inv, ms[15] * inv);
            *(uint4*)&Ahi[r * ALD + sub * 16]     = hv0;
            *(uint4*)&Ahi[r * ALD + sub * 16 + 8] = hv1;
        }
        __syncthreads();
        // ---- MFMA: A single-plane x W split (wh + wl), W direct from L2-hot pack
        #pragma unroll
        for (int ks = 0; ks < 4; ++ks) {
            bf16x8 wh = *(const bf16x8*)&Wt_l[(size_t)(8 * m + ks) * 4096 + w * 512 + l * 8];
            bf16x8 wl = *(const bf16x8*)&Wt_l[(size_t)(8 * m + 4 + ks) * 4096 + w * 512 + l * 8];
            int k0 = ks * 32 + koff;
            #pragma unroll
            for (int rt = 0; rt < 4; ++rt) {
                bf16x8 ah = *(const bf16x8*)&Ahi[(rt * 16 + l15) * ALD + k0];
                acc[rt] = __builtin_amdgcn_mfma_f32_16x16x32_bf16(ah, wh, acc[rt], 0, 0, 0);
                acc[rt] = __builtin_amdgcn_mfma_f32_16x16x32_bf16(ah, wl, acc[rt], 0, 0, 0);
            }
        }
        __syncthreads();   // before next m overwrites A
    }

    // ---- bias + bf16 global store (m89 C/D layout)
    {
        int col = w * 16 + l15;
        float bv = blsum_l[col];
        int rbase = row0 + (l >> 4) * 4;
        #pragma unroll
        for (int rt = 0; rt < 4; ++rt) {
            #pragma unroll
            for (int i = 0; i < 4; ++i) {
                int grr = rbase + rt * 16 + i;
                if (grr < NN) ob16[(size_t)grr * HH + col] = f2bf(acc[rt][i] + bv);
            }
        }
    }
}

// ================================================================ layernorm (bf16 in/out, validated R10)
__global__ void layernorm_kernel(const unsigned* __restrict__ in16u,
                                 const float* __restrict__ gamma,
                                 const float* __restrict__ beta,
                                 unsigned* __restrict__ out16u, int rows) {
    int lane = threadIdx.x & 63;
    int row = blockIdx.x * 4 + (threadIdx.x >> 6);
    if (row >= rows) return;
    unsigned u = in16u[(size_t)row * 64 + lane];
    float vx = bflo(u), vy = bfhi(u);
    float s = vx + vy, sq = vx * vx + vy * vy;
    #pragma unroll
    for (int o = 32; o; o >>= 1) { s += __shfl_xor(s, o); sq += __shfl_xor(sq, o); }
    float mu = s * (1.0f / HH);
    float var = sq * (1.0f / HH) - mu * mu;
    float r = rsqrtf(var + 1e-5f);
    float2 gj = *reinterpret_cast<const float2*>(&gamma[lane * 2]);
    float2 bj = *reinterpret_cast<const float2*>(&beta[lane * 2]);
    float ox = (vx - mu) * r * gj.x + bj.x;
    float oy = (vy - mu) * r * gj.y + bj.y;
    out16u[(size_t)row * 64 + lane] = pk2(ox, oy);
}

// ================================================================ two-stage pooling (validated R10)
__global__ void pool1_kernel(const unsigned short* __restrict__ h16,
                             const int* __restrict__ batch,
                             float* __restrict__ psum, float* __restrict__ pmax) {
    int g = blockIdx.x >> 4, c = blockIdx.x & (NC - 1);
    int start, end;
    {
        int lo = 0, hi = NN;
        while (lo < hi) { int mid = (lo + hi) >> 1; if (batch[mid] < g) lo = mid + 1; else hi = mid; }
        start = lo;
        hi = NN;
        while (lo < hi) { int mid = (lo + hi) >> 1; if (batch[mid] < g + 1) lo = mid + 1; else hi = mid; }
        end = lo;
    }
    int len = end - start;
    int chunk = (len + NC - 1) / NC;
    int clo = start + c * chunk;
    int chi = min(clo + chunk, end);
    int tid = threadIdx.x;
    int d = tid & 127, half = tid >> 7;
    float s = 0.f, m = -INFINITY;
    for (int n = clo + half; n < chi; n += 2) {
        float v = bf2f(h16[(size_t)n * HH + d]);
        s += v; m = fmaxf(m, v);
    }
    __shared__ float ss[256], sm[256];
    ss[tid] = s; sm[tid] = m;
    __syncthreads();
    if (half == 0) {
        s += ss[tid + 128];
        m = fmaxf(m, sm[tid + 128]);
        psum[(size_t)blockIdx.x * HH + d] = s;
        pmax[(size_t)blockIdx.x * HH + d] = m;
    }
}

__global__ void pool2_kernel(const float* __restrict__ psum, const float* __restrict__ pmax,
                             const int* __restrict__ batch, float* __restrict__ out) {
    int g = blockIdx.x;
    int d = threadIdx.x;   // 128 threads
    int start, end;
    {
        int lo = 0, hi = NN;
        while (lo < hi) { int mid = (lo + hi) >> 1; if (batch[mid] < g) lo = mid + 1; else hi = mid; }
        start = lo;
        hi = NN;
        while (lo < hi) { int mid = (lo + hi) >> 1; if (batch[mid] < g + 1) lo = mid + 1; else hi = mid; }
        end = lo;
    }
    float s = 0.f, m = -INFINITY;
    #pragma unroll
    for (int c = 0; c < NC; ++c) {
        s += psum[(size_t)(g * NC + c) * HH + d];
        m = fmaxf(m, pmax[(size_t)(g * NC + c) * HH + d]);
    }
    int cg = end - start;
    out[g * 2 * HH + d] = s / fmaxf((float)cg, 1.0f);
    out[g * 2 * HH + HH + d] = (cg > 0) ? m : 0.0f;
}

// ================================================================ launch
extern "C" void kernel_launch(void* const* d_in, const int* in_sizes, int n_in,
                              void* d_out, int out_size, void* d_ws, size_t ws_size,
                              hipStream_t stream) {
    const float* x     = (const float*)d_in[0];
    const int*   ast   = (const int*)d_in[1];
    const int*   batch = (const int*)d_in[2];
    const int*   ei    = (const int*)d_in[3];
    const float* emb   = (const float*)d_in[4];
    const float* W_in  = (const float*)d_in[5];
    const float* b_in  = (const float*)d_in[6];
    const float* W_l   = (const float*)d_in[7];
    const float* b_l   = (const float*)d_in[8];
    const float* W_r   = (const float*)d_in[9];
    const float* gamma = (const float*)d_in[10];
    const float* beta  = (const float*)d_in[11];
    float* out = (float*)d_out;

    const int M  = TT * NN;
    const int NB = (M + 1023) / 1024;

    char* p = (char*)d_ws;
    unsigned short* h16a = (unsigned short*)p;  p += (size_t)NN * HH * 2;   // 25.6 MB
    unsigned short* ob16 = (unsigned short*)p;  p += (size_t)NN * HH * 2;   // 25.6 MB
    unsigned short* Wt16 = (unsigned short*)p;  p += (size_t)LL * WLSZ * 2;
    unsigned short* Wp_in = (unsigned short*)p; p += (size_t)32768 * 2;     // 64 KB
    float* blsum = (float*)p;                   p += LL * HH * 4;
    float* psum = (float*)p;                    p += (size_t)BB * NC * HH * 4;
    float* pmax = (float*)p;                    p += (size_t)BB * NC * HH * 4;
    int* cnt    = (int*)p;                      p += (size_t)M * 4;
    int* offs   = (int*)p;                      p += (size_t)M * 4;
    int* cursor = (int*)p;                      p += (size_t)M * 4;
    int* csr    = (int*)p;                      p += (size_t)TT * EE * 4;
    int* bsums  = (int*)p;

    hipMemsetAsync(cnt, 0, (size_t)M * sizeof(int), stream);
    count_kernel<<<(TT * EE + 255) / 256, 256, 0, stream>>>(ei, cnt);
    scan1_kernel<<<NB, 256, 0, stream>>>(cnt, offs, bsums, M);
    scan2_kernel<<<1, 512, 0, stream>>>(bsums, NB);
    scan3_kernel<<<(M + 255) / 256, 256, 0, stream>>>(offs, bsums, cursor, M);
    fill_kernel<<<(TT * EE + 255) / 256, 256, 0, stream>>>(ei, cursor, csr);
    wprep_kernel<<<(LL * 4 * HH * HH + 255) / 256, 256, 0, stream>>>(W_l, W_r, b_l, Wt16, blsum);
    wprep_in_kernel<<<(KIN * HH + 255) / 256, 256, 0, stream>>>(W_in, Wp_in);

    int conv_grid = (NN + 63) / 64;
    int ln_grid = (NN + 3) / 4;
    input_proj_kernel<<<conv_grid, 512, 0, stream>>>(x, ast, emb, Wp_in, b_in, h16a);
    // layer 0
    conv_kernel<<<conv_grid, 512, 0, stream>>>(h16a, Wt16, blsum, offs, cnt, csr, ob16);
    layernorm_kernel<<<ln_grid, 256, 0, stream>>>((const unsigned*)ob16, gamma, beta,
                                                  (unsigned*)h16a, NN);
    // layer 1
    conv_kernel<<<conv_grid, 512, 0, stream>>>(h16a, Wt16 + (size_t)WLSZ, blsum + HH,
                                               offs, cnt, csr, ob16);
    layernorm_kernel<<<ln_grid, 256, 0, stream>>>((const unsigned*)ob16, gamma + HH, beta + HH,
                                                  (unsigned*)h16a, NN);
    // two-stage pooling
    pool1_kernel<<<BB * NC, 256, 0, stream>>>(h16a, batch, psum, pmax);
    pool2_kernel<<<BB, HH, 0, stream>>>(psum, pmax, batch, out);
}